// Round 1
// baseline (650.071 us; speedup 1.0000x reference)
//
#include <hip/hip_runtime.h>
#include <math.h>

// Problem constants
constexpr int BATCH = 256;
constexpr int TT    = 64;
constexpr int NH    = 4;
constexpr int DH    = 64;
constexpr int HIDN  = 256;   // NH*DH
constexpr int INDIM = 170;
constexpr int ROWS  = BATCH * TT;   // 16384
constexpr float EPS = 1e-5f;

// ---------------------------------------------------------------------------
// Generic fp32 GEMM: C[M,N] = act( scale * (A @ B) + bias )
// A row-major [M,K], B row-major [K,N]. 64x64 tile, 256 threads, 4x4 micro.
// act: 0 = none, 1 = sigmoid
// ---------------------------------------------------------------------------
__global__ __launch_bounds__(256) void gemm_f32(
    const float* __restrict__ A, const float* __restrict__ Bm,
    const float* __restrict__ bias, float* __restrict__ Cm,
    int M, int N, int K, float scale, int act)
{
    __shared__ float As[64][17];
    __shared__ float Bs[16][68];
    const int tid = threadIdx.x;
    const int m0 = blockIdx.y * 64;
    const int n0 = blockIdx.x * 64;
    const int tx = tid & 15, ty = tid >> 4;
    const int ar = tid >> 2,  ac = (tid & 3) * 4;
    const int br = tid >> 4,  bc = (tid & 15) * 4;

    float acc[4][4] = {{0.f,0.f,0.f,0.f},{0.f,0.f,0.f,0.f},
                       {0.f,0.f,0.f,0.f},{0.f,0.f,0.f,0.f}};

    for (int k0 = 0; k0 < K; k0 += 16) {
        // stage A tile (scalar loads: K may be 170, misaligned for float4)
        #pragma unroll
        for (int j = 0; j < 4; j++) {
            int kk = k0 + ac + j;
            As[ar][ac + j] = (kk < K) ? A[(size_t)(m0 + ar) * K + kk] : 0.f;
        }
        // stage B tile (N is always a multiple of 64 here; float4 ok)
        if (k0 + br < K) {
            const float4 bv = *(const float4*)(Bm + (size_t)(k0 + br) * N + n0 + bc);
            *(float4*)&Bs[br][bc] = bv;
        } else {
            *(float4*)&Bs[br][bc] = make_float4(0.f, 0.f, 0.f, 0.f);
        }
        __syncthreads();
        #pragma unroll
        for (int kk = 0; kk < 16; kk++) {
            float a0 = As[ty*4+0][kk];
            float a1 = As[ty*4+1][kk];
            float a2 = As[ty*4+2][kk];
            float a3 = As[ty*4+3][kk];
            float4 bv = *(float4*)&Bs[kk][tx*4];
            acc[0][0] += a0*bv.x; acc[0][1] += a0*bv.y; acc[0][2] += a0*bv.z; acc[0][3] += a0*bv.w;
            acc[1][0] += a1*bv.x; acc[1][1] += a1*bv.y; acc[1][2] += a1*bv.z; acc[1][3] += a1*bv.w;
            acc[2][0] += a2*bv.x; acc[2][1] += a2*bv.y; acc[2][2] += a2*bv.z; acc[2][3] += a2*bv.w;
            acc[3][0] += a3*bv.x; acc[3][1] += a3*bv.y; acc[3][2] += a3*bv.z; acc[3][3] += a3*bv.w;
        }
        __syncthreads();
    }

    #pragma unroll
    for (int i = 0; i < 4; i++) {
        int cm = m0 + ty*4 + i;
        float4 ov;
        #pragma unroll
        for (int j = 0; j < 4; j++) {
            int cn = n0 + tx*4 + j;
            float val = acc[i][j] * scale;
            if (bias) val += bias[cn];
            if (act)  val = 1.f / (1.f + expf(-val));
            (&ov.x)[j] = val;
        }
        *(float4*)(Cm + (size_t)cm * N + n0 + tx*4) = ov;
    }
}

// ---------------------------------------------------------------------------
// i/f gate projection: per row (B*T), 8 outputs of dot-256.
// One wave per row. lane = out*8 + part; part sums 32 elems; shfl-reduce by 8.
// ---------------------------------------------------------------------------
__global__ __launch_bounds__(64) void ifproj(
    const float* __restrict__ h, const float* __restrict__ wi,
    const float* __restrict__ wf, const float* __restrict__ bi,
    const float* __restrict__ bf, float* __restrict__ iout,
    float* __restrict__ fout)
{
    const int row  = blockIdx.x;
    const int lane = threadIdx.x;
    __shared__ float hr[HIDN];
    float4 hv = *(const float4*)(h + (size_t)row * HIDN + lane * 4);
    *(float4*)(hr + lane * 4) = hv;
    __syncthreads();

    const int out  = lane >> 3;   // 0..7
    const int part = lane & 7;    // 0..7
    const float* W = (out < 4) ? wi : wf;
    const int oc   = out & 3;
    float s = 0.f;
    #pragma unroll
    for (int c = 0; c < 32; c++) {
        int idx = part * 32 + c;
        s += hr[idx] * W[idx * NH + oc];
    }
    s += __shfl_xor(s, 1);
    s += __shfl_xor(s, 2);
    s += __shfl_xor(s, 4);
    if (part == 0) {
        float bias = (out < 4) ? bi[oc] : bf[oc];
        float r = s + bias;
        if (out < 4) iout[(size_t)row * NH + oc] = r;
        else         fout[(size_t)row * NH + oc] = r;
    }
}

// ---------------------------------------------------------------------------
// mLSTM sequential scan. One wave per (b, head). Lane e owns C[:, e] (64 regs),
// n[e], and writes h_out[..., e]. hout may alias q (read-before-write per step).
// ---------------------------------------------------------------------------
__global__ __launch_bounds__(64) void mlstm_scan(
    const float* q, const float* k, const float* v, const float* o,
    const float* __restrict__ ir, const float* __restrict__ fr,
    float* hout)
{
    const int bh = blockIdx.x;
    const int b  = bh >> 2;
    const int hh = bh & 3;
    const int e  = threadIdx.x;

    float C[DH];
    #pragma unroll
    for (int d = 0; d < DH; d++) C[d] = 0.f;
    float n_e = 0.f;
    float m   = 0.f;

    __shared__ float lv[DH];
    __shared__ float lq[DH];

    for (int t = 0; t < TT; t++) {
        const size_t base = ((size_t)(b * TT + t) * NH + hh) * DH + e;
        const float qv = q[base];
        const float kv = k[base];
        const float vv = v[base];
        const float ov = o[base];
        const int ib   = (b * TT + t) * NH + hh;
        const float it = ir[ib];
        const float ft = fr[ib];

        const float mn = fmaxf(ft + m, it);
        const float fg = expf(ft + m - mn);
        const float ig = expf(it - mn);
        m = mn;

        __syncthreads();           // previous iteration's readers done
        lv[e] = vv;
        lq[e] = qv;
        __syncthreads();

        const float igk = ig * kv;
        float cq = 0.f;
        #pragma unroll
        for (int d = 0; d < DH; d++) {
            C[d] = fg * C[d] + igk * lv[d];
            cq  += C[d] * lq[d];
        }
        n_e = fg * n_e + igk;

        float nd = n_e * qv;
        #pragma unroll
        for (int off = 32; off; off >>= 1) nd += __shfl_xor(nd, off);
        const float nq = fmaxf(fabsf(nd), 1.0f);

        hout[base] = ov * cq / nq;
    }
}

// ---------------------------------------------------------------------------
// LayerNorm over last dim (256). One wave per row, float4 per lane.
// ---------------------------------------------------------------------------
__global__ __launch_bounds__(64) void layernorm_f32(
    const float* __restrict__ xin, const float* __restrict__ g,
    const float* __restrict__ bta, float* __restrict__ y)
{
    const int row  = blockIdx.x;
    const int lane = threadIdx.x;
    const float4 xv = *(const float4*)(xin + (size_t)row * HIDN + lane * 4);
    float s = xv.x + xv.y + xv.z + xv.w;
    #pragma unroll
    for (int off = 32; off; off >>= 1) s += __shfl_xor(s, off);
    const float mu = s * (1.f / 256.f);
    const float d0 = xv.x - mu, d1 = xv.y - mu, d2 = xv.z - mu, d3 = xv.w - mu;
    float vs = d0*d0 + d1*d1 + d2*d2 + d3*d3;
    #pragma unroll
    for (int off = 32; off; off >>= 1) vs += __shfl_xor(vs, off);
    const float rstd = rsqrtf(vs * (1.f / 256.f) + EPS);
    const float4 gv = *(const float4*)(g + lane * 4);
    const float4 bv = *(const float4*)(bta + lane * 4);
    float4 ov;
    ov.x = d0 * rstd * gv.x + bv.x;
    ov.y = d1 * rstd * gv.y + bv.y;
    ov.z = d2 * rstd * gv.z + bv.z;
    ov.w = d3 * rstd * gv.w + bv.w;
    *(float4*)(y + (size_t)row * HIDN + lane * 4) = ov;
}

// ---------------------------------------------------------------------------
// Final head: z = h[:, T-1, :]; out = relu(z@W1 + b1) @ W2 + b2
// One block (128 threads) per batch row.
// ---------------------------------------------------------------------------
__global__ __launch_bounds__(128) void head_mlp(
    const float* __restrict__ h, const float* __restrict__ W1,
    const float* __restrict__ b1, const float* __restrict__ W2,
    const float* __restrict__ b2, float* __restrict__ out)
{
    const int b = blockIdx.x;
    const int j = threadIdx.x;
    __shared__ float z[HIDN];
    __shared__ float a[128];
    const float* zr = h + ((size_t)b * TT + (TT - 1)) * HIDN;
    z[j]       = zr[j];
    z[j + 128] = zr[j + 128];
    __syncthreads();
    float acc = b1[j];
    #pragma unroll 4
    for (int c = 0; c < HIDN; c++) acc += z[c] * W1[c * 128 + j];
    a[j] = fmaxf(acc, 0.f);
    __syncthreads();
    if (j < 2) {
        float s = b2[j];
        for (int c = 0; c < 128; c++) s += a[c] * W2[c * 2 + j];
        out[b * 2 + j] = s;
    }
}

// ---------------------------------------------------------------------------
extern "C" void kernel_launch(void* const* d_in, const int* in_sizes, int n_in,
                              void* d_out, int out_size, void* d_ws, size_t ws_size,
                              hipStream_t stream)
{
    const float* x   = (const float*)d_in[0];
    const float* Wp  = (const float*)d_in[1];
    const float* bp  = (const float*)d_in[2];
    const float* Wq  = (const float*)d_in[3];
    const float* Wk  = (const float*)d_in[4];
    const float* Wv  = (const float*)d_in[5];
    const float* Wo  = (const float*)d_in[6];
    const float* bo  = (const float*)d_in[7];
    const float* wi  = (const float*)d_in[8];
    const float* bi  = (const float*)d_in[9];
    const float* wf  = (const float*)d_in[10];
    const float* bf  = (const float*)d_in[11];
    const float* lng = (const float*)d_in[12];
    const float* lnb = (const float*)d_in[13];
    const float* W1  = (const float*)d_in[14];
    const float* b1  = (const float*)d_in[15];
    const float* W2  = (const float*)d_in[16];
    const float* b2  = (const float*)d_in[17];
    float* out = (float*)d_out;

    float* h  = (float*)d_ws;
    float* q  = h  + (size_t)ROWS * HIDN;
    float* kk = q  + (size_t)ROWS * HIDN;
    float* vv = kk + (size_t)ROWS * HIDN;
    float* oo = vv + (size_t)ROWS * HIDN;
    float* ir = oo + (size_t)ROWS * HIDN;
    float* fr = ir + (size_t)ROWS * NH;

    dim3 gproj(HIDN / 64, ROWS / 64);

    // input projection: h = x @ Wp + bp
    gemm_f32<<<gproj, 256, 0, stream>>>(x, Wp, bp, h, ROWS, HIDN, INDIM, 1.f, 0);

    for (int l = 0; l < 2; l++) {
        const float* Wql = Wq + (size_t)l * HIDN * HIDN;
        const float* Wkl = Wk + (size_t)l * HIDN * HIDN;
        const float* Wvl = Wv + (size_t)l * HIDN * HIDN;
        const float* Wol = Wo + (size_t)l * HIDN * HIDN;

        gemm_f32<<<gproj, 256, 0, stream>>>(h, Wql, nullptr,      q,  ROWS, HIDN, HIDN, 0.125f, 0);
        gemm_f32<<<gproj, 256, 0, stream>>>(h, Wkl, nullptr,      kk, ROWS, HIDN, HIDN, 1.f,    0);
        gemm_f32<<<gproj, 256, 0, stream>>>(h, Wvl, nullptr,      vv, ROWS, HIDN, HIDN, 1.f,    0);
        gemm_f32<<<gproj, 256, 0, stream>>>(h, Wol, bo + l*HIDN,  oo, ROWS, HIDN, HIDN, 1.f,    1);

        ifproj<<<ROWS, 64, 0, stream>>>(h, wi + (size_t)l*HIDN*NH, wf + (size_t)l*HIDN*NH,
                                        bi + l*NH, bf + l*NH, ir, fr);

        // scan writes h_out aliased onto q (read-before-write within each wave)
        mlstm_scan<<<BATCH * NH, 64, 0, stream>>>(q, kk, vv, oo, ir, fr, q);

        layernorm_f32<<<ROWS, 64, 0, stream>>>(q, lng + l*HIDN, lnb + l*HIDN, h);
    }

    head_mlp<<<BATCH, 128, 0, stream>>>(h, W1, b1, W2, b2, out);
}

// Round 4
// 395.768 us; speedup vs baseline: 1.6426x; 1.6426x over previous
//
#include <hip/hip_runtime.h>
#include <math.h>

typedef __attribute__((ext_vector_type(4))) float f32x4;
typedef __attribute__((ext_vector_type(8))) short bf16x8;

constexpr int BATCH = 256;
constexpr int TT    = 64;
constexpr int NH    = 4;
constexpr int DH    = 64;
constexpr int HIDN  = 256;
constexpr int INDIM = 170;
constexpr int KPAD  = 192;           // input-proj K padded to multiple of 64
constexpr int ROWS  = BATCH * TT;    // 16384
constexpr float EPS = 1e-5f;

__device__ __forceinline__ unsigned short f2b(float f) {
    union { float f; unsigned int u; } v; v.f = f;
    return (unsigned short)((v.u + 0x7FFFu + ((v.u >> 16) & 1u)) >> 16);
}
__device__ __forceinline__ float b2f(unsigned short b) {
    union { unsigned int u; float f; } v; v.u = ((unsigned int)b) << 16;
    return v.f;
}
// split x into hi (bf16) and lo (bf16 of residual)
__device__ __forceinline__ void fsplit(float x, unsigned short& hi, unsigned short& lo) {
    hi = f2b(x);
    lo = f2b(x - b2f(hi));
}

// ---------------------------------------------------------------------------
// pack_x: x [ROWS][170] f32 -> xh/xl [ROWS][192] bf16 (zero-padded)
// ---------------------------------------------------------------------------
__global__ __launch_bounds__(256) void pack_x(
    const float* __restrict__ x,
    unsigned short* __restrict__ xh, unsigned short* __restrict__ xl)
{
    int idx = blockIdx.x * 256 + threadIdx.x;
    if (idx >= ROWS * KPAD) return;
    int r = idx / KPAD, c = idx % KPAD;
    float v = (c < INDIM) ? x[(size_t)r * INDIM + c] : 0.f;
    unsigned short hi, lo; fsplit(v, hi, lo);
    xh[idx] = hi; xl[idx] = lo;
}

// ---------------------------------------------------------------------------
// pack_w: transpose+convert weights to split-bf16 [N][K] layout.
//   WpT_h/l [256][192]  (from Wp [170][256], K zero-padded)
//   Wt_h/l  [2][1024][256]  rows: Wq^T | Wk^T | Wv^T | Wo^T
// ---------------------------------------------------------------------------
__global__ __launch_bounds__(256) void pack_w(
    const float* __restrict__ Wp, const float* __restrict__ Wq,
    const float* __restrict__ Wk, const float* __restrict__ Wv,
    const float* __restrict__ Wo,
    unsigned short* __restrict__ WpTh, unsigned short* __restrict__ WpTl,
    unsigned short* __restrict__ Wth,  unsigned short* __restrict__ Wtl)
{
    int idx = blockIdx.x * 256 + threadIdx.x;
    if (idx < HIDN * KPAD) {
        int n = idx / KPAD, kc = idx % KPAD;
        float v = (kc < INDIM) ? Wp[(size_t)kc * HIDN + n] : 0.f;
        unsigned short hi, lo; fsplit(v, hi, lo);
        WpTh[idx] = hi; WpTl[idx] = lo;
        return;
    }
    idx -= HIDN * KPAD;
    if (idx < 2 * 1024 * 256) {
        int l = idx / (1024 * 256);
        int r = idx % (1024 * 256);
        int n = r / 256, k = r % 256;
        int seg = n >> 8, ns = n & 255;
        const float* W = (seg == 0) ? Wq : (seg == 1) ? Wk : (seg == 2) ? Wv : Wo;
        float v = W[(size_t)l * 65536 + (size_t)k * 256 + ns];
        unsigned short hi, lo; fsplit(v, hi, lo);
        Wth[(size_t)l * 1024 * 256 + r] = hi;
        Wtl[(size_t)l * 1024 * 256 + r] = lo;
    }
}

// ---------------------------------------------------------------------------
// split-bf16 MFMA GEMM (3-product): C = epi(Ah@Bh^T + Ah@Bl^T + Al@Bh^T)
// A split [M][K], Bt split [N][K]. 128x128 tile, 4 waves, 16x16x32, BK=64.
// mode 0: +bias, write f32 Cout and split-bf16 copies Ch/Cl
// mode 1 (fused qkvo, N=1024): seg0 *0.125 ; seg3 sigmoid(+bias) ; f32 only
// ---------------------------------------------------------------------------
__global__ __launch_bounds__(256) void gemm_mfma3(
    const unsigned short* __restrict__ Ah, const unsigned short* __restrict__ Al,
    const unsigned short* __restrict__ Bh, const unsigned short* __restrict__ Bl,
    const float* __restrict__ bias,
    float* __restrict__ Cout,
    unsigned short* __restrict__ Ch, unsigned short* __restrict__ Cl,
    int M, int N, int K, int mode)
{
    __shared__ unsigned short AsH[128 * 64];
    __shared__ unsigned short AsL[128 * 64];
    __shared__ unsigned short BsH[128 * 64];
    __shared__ unsigned short BsL[128 * 64];
    const int tid  = threadIdx.x;
    const int lane = tid & 63;
    const int wave = tid >> 6;
    const int wr = wave >> 1, wc = wave & 1;
    const int m0 = blockIdx.y * 128, n0 = blockIdx.x * 128;

    f32x4 acc[4][4] = {};

    for (int k0 = 0; k0 < K; k0 += 64) {
        #pragma unroll
        for (int j = 0; j < 4; j++) {
            int c   = j * 256 + tid;        // 16-byte chunk id, 0..1023
            int row = c >> 3;               // 8 chunks per 64-elem row
            int kc  = (c & 7) * 8;
            size_t aoff = (size_t)(m0 + row) * K + k0 + kc;
            size_t boff = (size_t)(n0 + row) * K + k0 + kc;
            __builtin_amdgcn_global_load_lds(
                (const __attribute__((address_space(1))) void*)(Ah + aoff),
                (__attribute__((address_space(3))) void*)(AsH + c * 8), 16, 0, 0);
            __builtin_amdgcn_global_load_lds(
                (const __attribute__((address_space(1))) void*)(Al + aoff),
                (__attribute__((address_space(3))) void*)(AsL + c * 8), 16, 0, 0);
            __builtin_amdgcn_global_load_lds(
                (const __attribute__((address_space(1))) void*)(Bh + boff),
                (__attribute__((address_space(3))) void*)(BsH + c * 8), 16, 0, 0);
            __builtin_amdgcn_global_load_lds(
                (const __attribute__((address_space(1))) void*)(Bl + boff),
                (__attribute__((address_space(3))) void*)(BsL + c * 8), 16, 0, 0);
        }
        asm volatile("s_waitcnt vmcnt(0)" ::: "memory");
        __syncthreads();

        #pragma unroll
        for (int kk = 0; kk < 2; kk++) {
            bf16x8 ah[4], al[4], bh[4], bl[4];
            #pragma unroll
            for (int i = 0; i < 4; i++) {
                const int off = (wr * 64 + i * 16 + (lane & 15)) * 64 + kk * 32 + (lane >> 4) * 8;
                ah[i] = *(const bf16x8*)&AsH[off];
                al[i] = *(const bf16x8*)&AsL[off];
            }
            #pragma unroll
            for (int j = 0; j < 4; j++) {
                const int off = (wc * 64 + j * 16 + (lane & 15)) * 64 + kk * 32 + (lane >> 4) * 8;
                bh[j] = *(const bf16x8*)&BsH[off];
                bl[j] = *(const bf16x8*)&BsL[off];
            }
            #pragma unroll
            for (int i = 0; i < 4; i++) {
                #pragma unroll
                for (int j = 0; j < 4; j++) {
                    acc[i][j] = __builtin_amdgcn_mfma_f32_16x16x32_bf16(ah[i], bh[j], acc[i][j], 0, 0, 0);
                    acc[i][j] = __builtin_amdgcn_mfma_f32_16x16x32_bf16(ah[i], bl[j], acc[i][j], 0, 0, 0);
                    acc[i][j] = __builtin_amdgcn_mfma_f32_16x16x32_bf16(al[i], bh[j], acc[i][j], 0, 0, 0);
                }
            }
        }
        __syncthreads();
    }

    #pragma unroll
    for (int i = 0; i < 4; i++) {
        #pragma unroll
        for (int j = 0; j < 4; j++) {
            const int col = n0 + wc * 64 + j * 16 + (lane & 15);
            const int seg = col >> 8;
            const float scale = (mode == 1 && seg == 0) ? 0.125f : 1.f;
            const bool  sig   = (mode == 1 && seg == 3);
            const bool  addb  = (mode == 0) || sig;
            const float bv    = addb ? bias[col & 255] : 0.f;
            #pragma unroll
            for (int r = 0; r < 4; r++) {
                const int row = m0 + wr * 64 + i * 16 + (lane >> 4) * 4 + r;
                float v = acc[i][j][r] * scale + bv;
                if (sig) v = 1.f / (1.f + __expf(-v));
                Cout[(size_t)row * N + col] = v;
                if (Ch) {
                    unsigned short hi, lo; fsplit(v, hi, lo);
                    Ch[(size_t)row * N + col] = hi;
                    Cl[(size_t)row * N + col] = lo;
                }
            }
        }
    }
}

// ---------------------------------------------------------------------------
// i/f gate projection (reads fp32 h). One wave per row.
// ---------------------------------------------------------------------------
__global__ __launch_bounds__(64) void ifproj(
    const float* __restrict__ h, const float* __restrict__ wi,
    const float* __restrict__ wf, const float* __restrict__ bi,
    const float* __restrict__ bf, float* __restrict__ iout,
    float* __restrict__ fout)
{
    const int row  = blockIdx.x;
    const int lane = threadIdx.x;
    __shared__ float hr[HIDN];
    float4 hv = *(const float4*)(h + (size_t)row * HIDN + lane * 4);
    *(float4*)(hr + lane * 4) = hv;
    __syncthreads();

    const int out  = lane >> 3;
    const int part = lane & 7;
    const float* W = (out < 4) ? wi : wf;
    const int oc   = out & 3;
    float s = 0.f;
    #pragma unroll
    for (int c = 0; c < 32; c++) {
        int idx = part * 32 + c;
        s += hr[idx] * W[idx * NH + oc];
    }
    s += __shfl_xor(s, 1);
    s += __shfl_xor(s, 2);
    s += __shfl_xor(s, 4);
    if (part == 0) {
        float b = (out < 4) ? bi[oc] : bf[oc];
        float r = s + b;
        if (out < 4) iout[(size_t)row * NH + oc] = r;
        else         fout[(size_t)row * NH + oc] = r;
    }
}

// ---------------------------------------------------------------------------
// mLSTM scan v2: one wave per (b,head). Whole q/v sequence + gates in LDS
// up-front (one barrier), then barrier-free t-loop; k/o streamed + prefetched.
// Reads fused qkvo [ROWS][1024] (segs q,k,v,o). Writes sout [ROWS][256].
// ---------------------------------------------------------------------------
__global__ __launch_bounds__(64) void mlstm_scan2(
    const float* __restrict__ qkvo, const float* __restrict__ irg,
    const float* __restrict__ frg, float* __restrict__ sout)
{
    const int bh = blockIdx.x;
    const int b  = bh >> 2;
    const int hh = bh & 3;
    const int e  = threadIdx.x;

    __shared__ float qs[TT][DH];
    __shared__ float vs[TT][DH];
    __shared__ float gi[TT], gf[TT];

    const float* qbase = qkvo + (size_t)(b * TT) * 1024 + 0   + hh * DH;
    const float* vbase = qkvo + (size_t)(b * TT) * 1024 + 512 + hh * DH;

    #pragma unroll
    for (int i = 0; i < 16; i++) {
        int c  = i * 64 + e;      // 0..1023 float4-chunks of the 64x64 tile
        int t  = c >> 4;
        int c4 = c & 15;
        float4 qv4 = *(const float4*)(qbase + (size_t)t * 1024 + c4 * 4);
        float4 vv4 = *(const float4*)(vbase + (size_t)t * 1024 + c4 * 4);
        *(float4*)&qs[t][c4 * 4] = qv4;
        *(float4*)&vs[t][c4 * 4] = vv4;
    }
    gi[e] = irg[(size_t)(b * TT + e) * NH + hh];
    gf[e] = frg[(size_t)(b * TT + e) * NH + hh];
    __syncthreads();

    const float* kbase = qkvo + (size_t)(b * TT) * 1024 + 256 + hh * DH + e;
    const float* obase = qkvo + (size_t)(b * TT) * 1024 + 768 + hh * DH + e;
    float* srow = sout + (size_t)(b * TT) * HIDN + hh * DH + e;

    float C[DH];
    #pragma unroll
    for (int d = 0; d < DH; d++) C[d] = 0.f;
    float n_e = 0.f, m = 0.f;

    float kv_n = kbase[0];
    float ov_n = obase[0];

    for (int t = 0; t < TT; t++) {
        const float kv = kv_n, ov = ov_n;
        if (t < TT - 1) {
            kv_n = kbase[(size_t)(t + 1) * 1024];
            ov_n = obase[(size_t)(t + 1) * 1024];
        }
        const float it = gi[t], ft = gf[t];
        const float mn = fmaxf(ft + m, it);
        const float fg = expf(ft + m - mn);
        const float ig = expf(it - mn);
        m = mn;
        const float igk = ig * kv;

        float cq0 = 0.f, cq1 = 0.f, cq2 = 0.f, cq3 = 0.f;
        #pragma unroll
        for (int d4 = 0; d4 < 16; d4++) {
            float4 vv = *(const float4*)&vs[t][d4 * 4];
            float4 qv = *(const float4*)&qs[t][d4 * 4];
            C[d4*4+0] = fg * C[d4*4+0] + igk * vv.x;  cq0 += C[d4*4+0] * qv.x;
            C[d4*4+1] = fg * C[d4*4+1] + igk * vv.y;  cq1 += C[d4*4+1] * qv.y;
            C[d4*4+2] = fg * C[d4*4+2] + igk * vv.z;  cq2 += C[d4*4+2] * qv.z;
            C[d4*4+3] = fg * C[d4*4+3] + igk * vv.w;  cq3 += C[d4*4+3] * qv.w;
        }
        n_e = fg * n_e + igk;
        const float cq = (cq0 + cq1) + (cq2 + cq3);

        float nd = n_e * qs[t][e];
        #pragma unroll
        for (int off = 32; off; off >>= 1) nd += __shfl_xor(nd, off);
        const float nq = fmaxf(fabsf(nd), 1.f);

        srow[(size_t)t * HIDN] = ov * cq / nq;
    }
}

// ---------------------------------------------------------------------------
// LayerNorm (in-place safe), also writes split-bf16 copies hh/hl.
// ---------------------------------------------------------------------------
__global__ __launch_bounds__(64) void layernorm_f32(
    const float* __restrict__ xin, const float* __restrict__ g,
    const float* __restrict__ bta, float* __restrict__ y,
    unsigned short* __restrict__ hbh, unsigned short* __restrict__ hbl)
{
    const int row  = blockIdx.x;
    const int lane = threadIdx.x;
    const float4 xv = *(const float4*)(xin + (size_t)row * HIDN + lane * 4);
    float s = xv.x + xv.y + xv.z + xv.w;
    #pragma unroll
    for (int off = 32; off; off >>= 1) s += __shfl_xor(s, off);
    const float mu = s * (1.f / 256.f);
    const float d0 = xv.x - mu, d1 = xv.y - mu, d2 = xv.z - mu, d3 = xv.w - mu;
    float vs = d0*d0 + d1*d1 + d2*d2 + d3*d3;
    #pragma unroll
    for (int off = 32; off; off >>= 1) vs += __shfl_xor(vs, off);
    const float rstd = rsqrtf(vs * (1.f / 256.f) + EPS);
    const float4 gv = *(const float4*)(g + lane * 4);
    const float4 bv = *(const float4*)(bta + lane * 4);
    float4 ov;
    ov.x = d0 * rstd * gv.x + bv.x;
    ov.y = d1 * rstd * gv.y + bv.y;
    ov.z = d2 * rstd * gv.z + bv.z;
    ov.w = d3 * rstd * gv.w + bv.w;
    *(float4*)(y + (size_t)row * HIDN + lane * 4) = ov;
    ushort4 h4, l4;
    fsplit(ov.x, h4.x, l4.x); fsplit(ov.y, h4.y, l4.y);
    fsplit(ov.z, h4.z, l4.z); fsplit(ov.w, h4.w, l4.w);
    *(ushort4*)(hbh + (size_t)row * HIDN + lane * 4) = h4;
    *(ushort4*)(hbl + (size_t)row * HIDN + lane * 4) = l4;
}

// ---------------------------------------------------------------------------
// Final head
// ---------------------------------------------------------------------------
__global__ __launch_bounds__(128) void head_mlp(
    const float* __restrict__ h, const float* __restrict__ W1,
    const float* __restrict__ b1, const float* __restrict__ W2,
    const float* __restrict__ b2, float* __restrict__ out)
{
    const int b = blockIdx.x;
    const int j = threadIdx.x;
    __shared__ float z[HIDN];
    __shared__ float a[128];
    const float* zr = h + ((size_t)b * TT + (TT - 1)) * HIDN;
    z[j]       = zr[j];
    z[j + 128] = zr[j + 128];
    __syncthreads();
    float acc = b1[j];
    #pragma unroll 4
    for (int c = 0; c < HIDN; c++) acc += z[c] * W1[c * 128 + j];
    a[j] = fmaxf(acc, 0.f);
    __syncthreads();
    if (j < 2) {
        float s = b2[j];
        for (int c = 0; c < 128; c++) s += a[c] * W2[c * 2 + j];
        out[b * 2 + j] = s;
    }
}

// ---------------------------------------------------------------------------
extern "C" void kernel_launch(void* const* d_in, const int* in_sizes, int n_in,
                              void* d_out, int out_size, void* d_ws, size_t ws_size,
                              hipStream_t stream)
{
    const float* x   = (const float*)d_in[0];
    const float* Wp  = (const float*)d_in[1];
    const float* bp  = (const float*)d_in[2];
    const float* Wq  = (const float*)d_in[3];
    const float* Wk  = (const float*)d_in[4];
    const float* Wv  = (const float*)d_in[5];
    const float* Wo  = (const float*)d_in[6];
    const float* bo  = (const float*)d_in[7];
    const float* wi  = (const float*)d_in[8];
    const float* bi  = (const float*)d_in[9];
    const float* wf  = (const float*)d_in[10];
    const float* bf  = (const float*)d_in[11];
    const float* lng = (const float*)d_in[12];
    const float* lnb = (const float*)d_in[13];
    const float* W1  = (const float*)d_in[14];
    const float* b1  = (const float*)d_in[15];
    const float* W2  = (const float*)d_in[16];
    const float* b2  = (const float*)d_in[17];
    float* out = (float*)d_out;

    // workspace layout
    char* ws = (char*)d_ws;
    float*          qkvo = (float*)ws;                                   // 67.1 MB [ROWS][1024]
    unsigned short* xh   = (unsigned short*)ws;                          // aliases qkvo (dead after input proj)
    unsigned short* xl   = xh + (size_t)ROWS * KPAD;
    float*          h    = (float*)(ws + (size_t)ROWS * 1024 * 4);       // 16.8 MB
    unsigned short* hbh  = (unsigned short*)((char*)h + (size_t)ROWS * HIDN * 4);   // 8.4 MB
    unsigned short* hbl  = hbh + (size_t)ROWS * HIDN;                               // 8.4 MB
    float*          ir   = (float*)(hbl + (size_t)ROWS * HIDN);
    float*          fr   = ir + (size_t)ROWS * NH;
    unsigned short* WpTh = (unsigned short*)(fr + (size_t)ROWS * NH);
    unsigned short* WpTl = WpTh + (size_t)HIDN * KPAD;
    unsigned short* Wth  = WpTl + (size_t)HIDN * KPAD;
    unsigned short* Wtl  = Wth + (size_t)2 * 1024 * 256;

    pack_x<<<(ROWS * KPAD + 255) / 256, 256, 0, stream>>>(x, xh, xl);
    {
        int tot = HIDN * KPAD + 2 * 1024 * 256;
        pack_w<<<(tot + 255) / 256, 256, 0, stream>>>(Wp, Wq, Wk, Wv, Wo,
                                                      WpTh, WpTl, Wth, Wtl);
    }

    // input projection: h(,split copies) = x @ Wp + bp
    gemm_mfma3<<<dim3(2, 128), 256, 0, stream>>>(
        xh, xl, WpTh, WpTl, bp, h, hbh, hbl, ROWS, HIDN, KPAD, 0);

    for (int l = 0; l < 2; l++) {
        gemm_mfma3<<<dim3(8, 128), 256, 0, stream>>>(
            hbh, hbl, Wth + (size_t)l * 1024 * 256, Wtl + (size_t)l * 1024 * 256,
            bo + (size_t)l * HIDN, qkvo, nullptr, nullptr, ROWS, 1024, HIDN, 1);

        ifproj<<<ROWS, 64, 0, stream>>>(h, wi + (size_t)l * HIDN * NH,
                                        wf + (size_t)l * HIDN * NH,
                                        bi + l * NH, bf + l * NH, ir, fr);

        mlstm_scan2<<<BATCH * NH, 64, 0, stream>>>(qkvo, ir, fr, h);  // writes over h

        layernorm_f32<<<ROWS, 64, 0, stream>>>(h, lng + (size_t)l * HIDN,
                                               lnb + (size_t)l * HIDN, h, hbh, hbl);
    }

    head_mlp<<<BATCH, 128, 0, stream>>>(h, W1, b1, W2, b2, out);
}

// Round 5
// 321.157 us; speedup vs baseline: 2.0242x; 1.2323x over previous
//
#include <hip/hip_runtime.h>
#include <math.h>

typedef __attribute__((ext_vector_type(4))) float f32x4;
typedef __attribute__((ext_vector_type(8))) short bf16x8;

constexpr int BATCH = 256;
constexpr int TT    = 64;
constexpr int NH    = 4;
constexpr int DH    = 64;
constexpr int HIDN  = 256;
constexpr int INDIM = 170;
constexpr int KPAD  = 192;
constexpr int ROWS  = BATCH * TT;    // 16384
constexpr float EPS = 1e-5f;

#define MF(a, b, c) __builtin_amdgcn_mfma_f32_16x16x32_bf16((a), (b), (c), 0, 0, 0)

__device__ __forceinline__ unsigned short f2b(float f) {
    union { float f; unsigned int u; } v; v.f = f;
    return (unsigned short)((v.u + 0x7FFFu + ((v.u >> 16) & 1u)) >> 16);
}
__device__ __forceinline__ float b2f(unsigned short b) {
    union { unsigned int u; float f; } v; v.u = ((unsigned int)b) << 16;
    return v.f;
}
__device__ __forceinline__ void fsplit(float x, unsigned short& hi, unsigned short& lo) {
    hi = f2b(x);
    lo = f2b(x - b2f(hi));
}

// ---------------------------------------------------------------------------
// pack_x: x [ROWS][170] f32 -> xh/xl [ROWS][192] split bf16 (zero-padded)
// ---------------------------------------------------------------------------
__global__ __launch_bounds__(256) void pack_x(
    const float* __restrict__ x,
    unsigned short* __restrict__ xh, unsigned short* __restrict__ xl)
{
    int idx = blockIdx.x * 256 + threadIdx.x;
    if (idx >= ROWS * KPAD) return;
    int r = idx / KPAD, c = idx % KPAD;
    float v = (c < INDIM) ? x[(size_t)r * INDIM + c] : 0.f;
    unsigned short hi, lo; fsplit(v, hi, lo);
    xh[idx] = hi; xl[idx] = lo;
}

// ---------------------------------------------------------------------------
// pack_w: weights -> split-bf16 [N][K] (B-transposed) layout.
// ---------------------------------------------------------------------------
__global__ __launch_bounds__(256) void pack_w(
    const float* __restrict__ Wp, const float* __restrict__ Wq,
    const float* __restrict__ Wk, const float* __restrict__ Wv,
    const float* __restrict__ Wo,
    unsigned short* __restrict__ WpTh, unsigned short* __restrict__ WpTl,
    unsigned short* __restrict__ Wth,  unsigned short* __restrict__ Wtl)
{
    int idx = blockIdx.x * 256 + threadIdx.x;
    if (idx < HIDN * KPAD) {
        int n = idx / KPAD, kc = idx % KPAD;
        float v = (kc < INDIM) ? Wp[(size_t)kc * HIDN + n] : 0.f;
        unsigned short hi, lo; fsplit(v, hi, lo);
        WpTh[idx] = hi; WpTl[idx] = lo;
        return;
    }
    idx -= HIDN * KPAD;
    if (idx < 2 * 1024 * 256) {
        int l = idx / (1024 * 256);
        int r = idx % (1024 * 256);
        int n = r / 256, k = r % 256;
        int seg = n >> 8, ns = n & 255;
        const float* W = (seg == 0) ? Wq : (seg == 1) ? Wk : (seg == 2) ? Wv : Wo;
        float v = W[(size_t)l * 65536 + (size_t)k * 256 + ns];
        unsigned short hi, lo; fsplit(v, hi, lo);
        Wth[(size_t)l * 1024 * 256 + r] = hi;
        Wtl[(size_t)l * 1024 * 256 + r] = lo;
    }
}

// ---------------------------------------------------------------------------
// split-bf16 MFMA GEMM (3-product). 128x128 tile, 4 waves, 16x16x32, BK=64.
// mode 0: out = A@B + bias -> split write to c0/c1 [M][N]
// mode 1: fused qkvo (N=1024). Epilogue scatters per-(b,h) 4096-elem tiles:
//   seg0 q*0.125 -> qh/ql swizzled [t][d^((t&7)<<3)]
//   seg1 k       -> kh/kl swizzled + kth/ktl transposed-swizzled [d][t^((d&7)<<3)]
//   seg2 v       -> vh/vl swizzled
//   seg3 sigmoid(o+bias) -> ob bf16 [t][d] linear
// ---------------------------------------------------------------------------
__global__ __launch_bounds__(256) void gemm_mfma3(
    const unsigned short* __restrict__ Ah, const unsigned short* __restrict__ Al,
    const unsigned short* __restrict__ Bh, const unsigned short* __restrict__ Bl,
    const float* __restrict__ bias,
    unsigned short* __restrict__ c0, unsigned short* __restrict__ c1,
    unsigned short* __restrict__ qh, unsigned short* __restrict__ ql,
    unsigned short* __restrict__ kh, unsigned short* __restrict__ kl,
    unsigned short* __restrict__ kth, unsigned short* __restrict__ ktl,
    unsigned short* __restrict__ vh, unsigned short* __restrict__ vl,
    unsigned short* __restrict__ ob,
    int M, int N, int K, int mode)
{
    __shared__ unsigned short AsH[128 * 64];
    __shared__ unsigned short AsL[128 * 64];
    __shared__ unsigned short BsH[128 * 64];
    __shared__ unsigned short BsL[128 * 64];
    const int tid  = threadIdx.x;
    const int lane = tid & 63;
    const int wave = tid >> 6;
    const int wr = wave >> 1, wc = wave & 1;
    const int m0 = blockIdx.y * 128, n0 = blockIdx.x * 128;

    f32x4 acc[4][4] = {};

    for (int k0 = 0; k0 < K; k0 += 64) {
        #pragma unroll
        for (int j = 0; j < 4; j++) {
            int c   = j * 256 + tid;
            int row = c >> 3;
            int kc  = (c & 7) * 8;
            size_t aoff = (size_t)(m0 + row) * K + k0 + kc;
            size_t boff = (size_t)(n0 + row) * K + k0 + kc;
            __builtin_amdgcn_global_load_lds(
                (const __attribute__((address_space(1))) void*)(Ah + aoff),
                (__attribute__((address_space(3))) void*)(AsH + c * 8), 16, 0, 0);
            __builtin_amdgcn_global_load_lds(
                (const __attribute__((address_space(1))) void*)(Al + aoff),
                (__attribute__((address_space(3))) void*)(AsL + c * 8), 16, 0, 0);
            __builtin_amdgcn_global_load_lds(
                (const __attribute__((address_space(1))) void*)(Bh + boff),
                (__attribute__((address_space(3))) void*)(BsH + c * 8), 16, 0, 0);
            __builtin_amdgcn_global_load_lds(
                (const __attribute__((address_space(1))) void*)(Bl + boff),
                (__attribute__((address_space(3))) void*)(BsL + c * 8), 16, 0, 0);
        }
        asm volatile("s_waitcnt vmcnt(0)" ::: "memory");
        __syncthreads();

        #pragma unroll
        for (int kk = 0; kk < 2; kk++) {
            bf16x8 ah[4], al[4], bh[4], bl[4];
            #pragma unroll
            for (int i = 0; i < 4; i++) {
                const int off = (wr * 64 + i * 16 + (lane & 15)) * 64 + kk * 32 + (lane >> 4) * 8;
                ah[i] = *(const bf16x8*)&AsH[off];
                al[i] = *(const bf16x8*)&AsL[off];
            }
            #pragma unroll
            for (int j = 0; j < 4; j++) {
                const int off = (wc * 64 + j * 16 + (lane & 15)) * 64 + kk * 32 + (lane >> 4) * 8;
                bh[j] = *(const bf16x8*)&BsH[off];
                bl[j] = *(const bf16x8*)&BsL[off];
            }
            #pragma unroll
            for (int i = 0; i < 4; i++) {
                #pragma unroll
                for (int j = 0; j < 4; j++) {
                    acc[i][j] = MF(ah[i], bh[j], acc[i][j]);
                    acc[i][j] = MF(ah[i], bl[j], acc[i][j]);
                    acc[i][j] = MF(al[i], bh[j], acc[i][j]);
                }
            }
        }
        __syncthreads();
    }

    if (mode == 0) {
        #pragma unroll
        for (int i = 0; i < 4; i++) {
            #pragma unroll
            for (int j = 0; j < 4; j++) {
                const int col = n0 + wc * 64 + j * 16 + (lane & 15);
                const float bv = bias[col];
                #pragma unroll
                for (int r = 0; r < 4; r++) {
                    const int row = m0 + wr * 64 + i * 16 + (lane >> 4) * 4 + r;
                    float v = acc[i][j][r] + bv;
                    unsigned short hi, lo; fsplit(v, hi, lo);
                    c0[(size_t)row * N + col] = hi;
                    c1[(size_t)row * N + col] = lo;
                }
            }
        }
    } else {
        #pragma unroll
        for (int i = 0; i < 4; i++) {
            #pragma unroll
            for (int j = 0; j < 4; j++) {
                const int col = n0 + wc * 64 + j * 16 + (lane & 15);
                const int seg = col >> 8;
                const int hh2 = (col >> 6) & 3;
                const int d   = col & 63;
                const float scale = (seg == 0) ? 0.125f : 1.f;
                const float bv    = (seg == 3) ? bias[col & 255] : 0.f;
                #pragma unroll
                for (int r = 0; r < 4; r++) {
                    const int row = m0 + wr * 64 + i * 16 + (lane >> 4) * 4 + r;
                    const int bb = row >> 6, t = row & 63;
                    const size_t tb = (size_t)(bb * 4 + hh2) * 4096;
                    float v = acc[i][j][r] * scale;
                    if (seg == 3) {
                        v = 1.f / (1.f + __expf(-(v + bv)));
                        ob[tb + t * 64 + d] = f2b(v);
                    } else {
                        unsigned short hi, lo; fsplit(v, hi, lo);
                        const int idx = tb + t * 64 + (d ^ ((t & 7) << 3));
                        if (seg == 0)      { qh[idx] = hi; ql[idx] = lo; }
                        else if (seg == 1) { kh[idx] = hi; kl[idx] = lo;
                            const int idx2 = tb + d * 64 + (t ^ ((d & 7) << 3));
                            kth[idx2] = hi; ktl[idx2] = lo; }
                        else               { vh[idx] = hi; vl[idx] = lo; }
                    }
                }
            }
        }
    }
}

// ---------------------------------------------------------------------------
// i/f gate projection (reads split h). One wave per row.
// ---------------------------------------------------------------------------
__global__ __launch_bounds__(64) void ifproj(
    const unsigned short* __restrict__ hbh, const unsigned short* __restrict__ hbl,
    const float* __restrict__ wi, const float* __restrict__ wf,
    const float* __restrict__ bi, const float* __restrict__ bf,
    float* __restrict__ iout, float* __restrict__ fout)
{
    const int row  = blockIdx.x;
    const int lane = threadIdx.x;
    __shared__ float hr[HIDN];
    ushort4 a4 = *(const ushort4*)(hbh + (size_t)row * HIDN + lane * 4);
    ushort4 l4 = *(const ushort4*)(hbl + (size_t)row * HIDN + lane * 4);
    hr[lane * 4 + 0] = b2f(a4.x) + b2f(l4.x);
    hr[lane * 4 + 1] = b2f(a4.y) + b2f(l4.y);
    hr[lane * 4 + 2] = b2f(a4.z) + b2f(l4.z);
    hr[lane * 4 + 3] = b2f(a4.w) + b2f(l4.w);
    __syncthreads();

    const int out  = lane >> 3;
    const int part = lane & 7;
    const float* W = (out < 4) ? wi : wf;
    const int oc   = out & 3;
    float s = 0.f;
    #pragma unroll
    for (int c = 0; c < 32; c++) {
        int idx = part * 32 + c;
        s += hr[idx] * W[idx * NH + oc];
    }
    s += __shfl_xor(s, 1);
    s += __shfl_xor(s, 2);
    s += __shfl_xor(s, 4);
    if (part == 0) {
        float b = (out < 4) ? bi[oc] : bf[oc];
        float r = s + b;
        if (out < 4) iout[(size_t)row * NH + oc] = r;
        else         fout[(size_t)row * NH + oc] = r;
    }
}

// ---------------------------------------------------------------------------
// mLSTM parallel (quadratic) form. One block (4 waves) per (b,h).
//   Sv = Q@V^T, Sk = Q@K^T (both split-bf16 3-product MFMA)
//   w_ts = exp(a_s + F_t - m_t) for s<=t;  P = W.*Sv;  den = rowsum(W.*Sk)
//   num = P@K (via KT tile);  h = o .* num / max(|den|,1)  -> split out
// ---------------------------------------------------------------------------
__global__ __launch_bounds__(256) void mlstm_attn(
    const unsigned short* __restrict__ qh, const unsigned short* __restrict__ ql,
    const unsigned short* __restrict__ kh, const unsigned short* __restrict__ kl,
    const unsigned short* __restrict__ kth, const unsigned short* __restrict__ ktl,
    const unsigned short* __restrict__ vh, const unsigned short* __restrict__ vl,
    const unsigned short* __restrict__ ob,
    const float* __restrict__ irg, const float* __restrict__ frg,
    unsigned short* __restrict__ hoh, unsigned short* __restrict__ hol)
{
    __shared__ unsigned short sm[8 * 4096];   // Qh Ql Kh Kl Th Tl Vh Vl (8KB each)
    __shared__ float sa[TT], sc[TT];
    const int bh = blockIdx.x;
    const int b  = bh >> 2;
    const int hh = bh & 3;
    const int tid = threadIdx.x, lane = tid & 63, w = tid >> 6;

    // stage all 8 tiles (64KB) via async global->LDS
    const unsigned short* gsrc[8] = {qh, ql, kh, kl, kth, ktl, vh, vl};
    #pragma unroll
    for (int a2 = 0; a2 < 8; a2++) {
        #pragma unroll
        for (int is = 0; is < 2; is++) {
            __builtin_amdgcn_global_load_lds(
                (const __attribute__((address_space(1))) void*)(gsrc[a2] + (size_t)bh * 4096 + is * 2048 + tid * 8),
                (__attribute__((address_space(3))) void*)(sm + a2 * 4096 + is * 2048 + tid * 8), 16, 0, 0);
        }
    }

    // wave 0: gate prefix scans
    if (w == 0) {
        const int t = lane;
        float iv = irg[(size_t)(b * TT + t) * NH + hh];
        float fv = frg[(size_t)(b * TT + t) * NH + hh];
        float F = fv;
        #pragma unroll
        for (int d2 = 1; d2 < 64; d2 <<= 1) { float o2 = __shfl_up(F, d2); if (lane >= d2) F += o2; }
        float av = iv - F;
        float pm = av;
        #pragma unroll
        for (int d2 = 1; d2 < 64; d2 <<= 1) { float o2 = __shfl_up(pm, d2); if (lane >= d2) pm = fmaxf(pm, o2); }
        sa[t] = av;
        sc[t] = -fmaxf(0.f, pm);   // F_t - m_t
    }
    asm volatile("s_waitcnt vmcnt(0)" ::: "memory");
    __syncthreads();

    // S phase: wave w owns t-rows [16w,16w+16)
    f32x4 accv[4] = {}, acck[4] = {};
    const int tA = w * 16 + (lane & 15);
    #pragma unroll
    for (int kk = 0; kk < 2; kk++) {
        const int eA = (kk * 32 + (lane >> 4) * 8) ^ ((tA & 7) << 3);
        bf16x8 aQh = *(const bf16x8*)&sm[0 * 4096 + tA * 64 + eA];
        bf16x8 aQl = *(const bf16x8*)&sm[1 * 4096 + tA * 64 + eA];
        #pragma unroll
        for (int j = 0; j < 4; j++) {
            const int sB = j * 16 + (lane & 15);
            const int eB = (kk * 32 + (lane >> 4) * 8) ^ ((sB & 7) << 3);
            bf16x8 bKh = *(const bf16x8*)&sm[2 * 4096 + sB * 64 + eB];
            bf16x8 bKl = *(const bf16x8*)&sm[3 * 4096 + sB * 64 + eB];
            bf16x8 bVh = *(const bf16x8*)&sm[6 * 4096 + sB * 64 + eB];
            bf16x8 bVl = *(const bf16x8*)&sm[7 * 4096 + sB * 64 + eB];
            accv[j] = MF(aQh, bVh, accv[j]);
            accv[j] = MF(aQh, bVl, accv[j]);
            accv[j] = MF(aQl, bVh, accv[j]);
            acck[j] = MF(aQh, bKh, acck[j]);
            acck[j] = MF(aQh, bKl, acck[j]);
            acck[j] = MF(aQl, bKh, acck[j]);
        }
    }

    // mask + denominator
    const int tbase = w * 16 + (lane >> 4) * 4;
    float cw[4];
    #pragma unroll
    for (int r = 0; r < 4; r++) cw[r] = sc[tbase + r];
    float den4[4] = {0.f, 0.f, 0.f, 0.f};
    #pragma unroll
    for (int j = 0; j < 4; j++) {
        const int s = j * 16 + (lane & 15);
        const float as = sa[s];
        #pragma unroll
        for (int r = 0; r < 4; r++) {
            const int t = tbase + r;
            const float wgt = (s <= t) ? __expf(as + cw[r]) : 0.f;
            accv[j][r] *= wgt;
            den4[r] += acck[j][r] * wgt;
        }
    }
    #pragma unroll
    for (int r = 0; r < 4; r++) {
        den4[r] += __shfl_xor(den4[r], 1);
        den4[r] += __shfl_xor(den4[r], 2);
        den4[r] += __shfl_xor(den4[r], 4);
        den4[r] += __shfl_xor(den4[r], 8);
        den4[r] = fmaxf(fabsf(den4[r]), 1.f);
    }

    __syncthreads();   // all waves done reading Q/K before P overlays them

    // write P split into sm[0..9216) with row stride 72 (wave-local rows)
    #pragma unroll
    for (int j = 0; j < 4; j++) {
        const int s = j * 16 + (lane & 15);
        #pragma unroll
        for (int r = 0; r < 4; r++) {
            const int t = tbase + r;
            unsigned short hi, lo; fsplit(accv[j][r], hi, lo);
            sm[t * 72 + s] = hi;
            sm[4608 + t * 72 + s] = lo;
        }
    }
    __syncthreads();

    // PV phase: num = P @ K  (B operand from KT tile)
    f32x4 num[4] = {};
    #pragma unroll
    for (int kk = 0; kk < 2; kk++) {
        const int sA = kk * 32 + (lane >> 4) * 8;
        bf16x8 aPh = *(const bf16x8*)&sm[tA * 72 + sA];
        bf16x8 aPl = *(const bf16x8*)&sm[4608 + tA * 72 + sA];
        #pragma unroll
        for (int j = 0; j < 4; j++) {
            const int eB2 = j * 16 + (lane & 15);
            const int tB = (kk * 32 + (lane >> 4) * 8) ^ ((eB2 & 7) << 3);
            bf16x8 bTh = *(const bf16x8*)&sm[4 * 4096 + eB2 * 64 + tB];
            bf16x8 bTl = *(const bf16x8*)&sm[5 * 4096 + eB2 * 64 + tB];
            num[j] = MF(aPh, bTh, num[j]);
            num[j] = MF(aPh, bTl, num[j]);
            num[j] = MF(aPl, bTh, num[j]);
        }
    }

    // output: h = o * num / den  -> split bf16
    #pragma unroll
    for (int j = 0; j < 4; j++) {
        const int e = j * 16 + (lane & 15);
        #pragma unroll
        for (int r = 0; r < 4; r++) {
            const int t = tbase + r;
            const float o = b2f(ob[(size_t)bh * 4096 + t * 64 + e]);
            const float hval = o * num[j][r] / den4[r];
            unsigned short hi, lo; fsplit(hval, hi, lo);
            const size_t oidx = (size_t)(b * TT + t) * HIDN + hh * DH + e;
            hoh[oidx] = hi; hol[oidx] = lo;
        }
    }
}

// ---------------------------------------------------------------------------
// LayerNorm over 256, in-place on the split pair.
// ---------------------------------------------------------------------------
__global__ __launch_bounds__(64) void layernorm_sp(
    unsigned short* __restrict__ hh_, unsigned short* __restrict__ hl_,
    const float* __restrict__ g, const float* __restrict__ bta)
{
    const int row  = blockIdx.x;
    const int lane = threadIdx.x;
    ushort4 a4 = *(const ushort4*)(hh_ + (size_t)row * HIDN + lane * 4);
    ushort4 l4 = *(const ushort4*)(hl_ + (size_t)row * HIDN + lane * 4);
    float x0 = b2f(a4.x) + b2f(l4.x);
    float x1 = b2f(a4.y) + b2f(l4.y);
    float x2 = b2f(a4.z) + b2f(l4.z);
    float x3 = b2f(a4.w) + b2f(l4.w);
    float s = x0 + x1 + x2 + x3;
    #pragma unroll
    for (int off = 32; off; off >>= 1) s += __shfl_xor(s, off);
    const float mu = s * (1.f / 256.f);
    const float d0 = x0 - mu, d1 = x1 - mu, d2 = x2 - mu, d3 = x3 - mu;
    float vs = d0*d0 + d1*d1 + d2*d2 + d3*d3;
    #pragma unroll
    for (int off = 32; off; off >>= 1) vs += __shfl_xor(vs, off);
    const float rstd = rsqrtf(vs * (1.f / 256.f) + EPS);
    const float4 gv = *(const float4*)(g + lane * 4);
    const float4 bv = *(const float4*)(bta + lane * 4);
    float y0 = d0 * rstd * gv.x + bv.x;
    float y1 = d1 * rstd * gv.y + bv.y;
    float y2 = d2 * rstd * gv.z + bv.z;
    float y3 = d3 * rstd * gv.w + bv.w;
    ushort4 h4, o4;
    fsplit(y0, h4.x, o4.x); fsplit(y1, h4.y, o4.y);
    fsplit(y2, h4.z, o4.z); fsplit(y3, h4.w, o4.w);
    *(ushort4*)(hh_ + (size_t)row * HIDN + lane * 4) = h4;
    *(ushort4*)(hl_ + (size_t)row * HIDN + lane * 4) = o4;
}

// ---------------------------------------------------------------------------
// Final head: z = h[:, T-1, :]; out = relu(z@W1 + b1) @ W2 + b2
// ---------------------------------------------------------------------------
__global__ __launch_bounds__(128) void head_mlp(
    const unsigned short* __restrict__ hbh, const unsigned short* __restrict__ hbl,
    const float* __restrict__ W1, const float* __restrict__ b1,
    const float* __restrict__ W2, const float* __restrict__ b2,
    float* __restrict__ out)
{
    const int b = blockIdx.x;
    const int j = threadIdx.x;
    __shared__ float z[HIDN];
    __shared__ float a[128];
    const size_t rb = ((size_t)b * TT + (TT - 1)) * HIDN;
    z[j]       = b2f(hbh[rb + j])       + b2f(hbl[rb + j]);
    z[j + 128] = b2f(hbh[rb + j + 128]) + b2f(hbl[rb + j + 128]);
    __syncthreads();
    float acc = b1[j];
    #pragma unroll 4
    for (int c = 0; c < HIDN; c++) acc += z[c] * W1[c * 128 + j];
    a[j] = fmaxf(acc, 0.f);
    __syncthreads();
    if (j < 2) {
        float s = b2[j];
        for (int c = 0; c < 128; c++) s += a[c] * W2[c * 2 + j];
        out[b * 2 + j] = s;
    }
}

// ---------------------------------------------------------------------------
extern "C" void kernel_launch(void* const* d_in, const int* in_sizes, int n_in,
                              void* d_out, int out_size, void* d_ws, size_t ws_size,
                              hipStream_t stream)
{
    const float* x   = (const float*)d_in[0];
    const float* Wp  = (const float*)d_in[1];
    const float* bp  = (const float*)d_in[2];
    const float* Wq  = (const float*)d_in[3];
    const float* Wk  = (const float*)d_in[4];
    const float* Wv  = (const float*)d_in[5];
    const float* Wo  = (const float*)d_in[6];
    const float* bo  = (const float*)d_in[7];
    const float* wi  = (const float*)d_in[8];
    const float* bi  = (const float*)d_in[9];
    const float* wf  = (const float*)d_in[10];
    const float* bf  = (const float*)d_in[11];
    const float* lng = (const float*)d_in[12];
    const float* lnb = (const float*)d_in[13];
    const float* W1  = (const float*)d_in[14];
    const float* b1  = (const float*)d_in[15];
    const float* W2  = (const float*)d_in[16];
    const float* b2  = (const float*)d_in[17];
    float* out = (float*)d_out;

    // workspace layout (~97.2 MB)
    const size_t TSZ = (size_t)1024 * 4096;       // per-(b,h) tile array elems
    unsigned short* qh  = (unsigned short*)d_ws;
    unsigned short* ql  = qh  + TSZ;
    unsigned short* kh  = ql  + TSZ;
    unsigned short* kl  = kh  + TSZ;
    unsigned short* kth = kl  + TSZ;
    unsigned short* ktl = kth + TSZ;
    unsigned short* vh  = ktl + TSZ;
    unsigned short* vl  = vh  + TSZ;
    unsigned short* ob  = vl  + TSZ;
    unsigned short* hbh = ob  + TSZ;
    unsigned short* hbl = hbh + (size_t)ROWS * HIDN;
    float*          ir  = (float*)(hbl + (size_t)ROWS * HIDN);
    float*          fr  = ir + (size_t)ROWS * NH;
    unsigned short* WpTh = (unsigned short*)(fr + (size_t)ROWS * NH);
    unsigned short* WpTl = WpTh + (size_t)HIDN * KPAD;
    unsigned short* Wth  = WpTl + (size_t)HIDN * KPAD;
    unsigned short* Wtl  = Wth + (size_t)2 * 1024 * 256;
    // pack_x outputs alias the q tile region (dead until first layer GEMM)
    unsigned short* xh = qh;
    unsigned short* xl = ql;

    pack_x<<<(ROWS * KPAD + 255) / 256, 256, 0, stream>>>(x, xh, xl);
    {
        int tot = HIDN * KPAD + 2 * 1024 * 256;
        pack_w<<<(tot + 255) / 256, 256, 0, stream>>>(Wp, Wq, Wk, Wv, Wo,
                                                      WpTh, WpTl, Wth, Wtl);
    }

    // input projection: hb = x @ Wp + bp (split)
    gemm_mfma3<<<dim3(2, 128), 256, 0, stream>>>(
        xh, xl, WpTh, WpTl, bp, hbh, hbl,
        nullptr, nullptr, nullptr, nullptr, nullptr, nullptr, nullptr, nullptr, nullptr,
        ROWS, HIDN, KPAD, 0);

    for (int l = 0; l < 2; l++) {
        gemm_mfma3<<<dim3(8, 128), 256, 0, stream>>>(
            hbh, hbl, Wth + (size_t)l * 1024 * 256, Wtl + (size_t)l * 1024 * 256,
            bo + (size_t)l * HIDN, nullptr, nullptr,
            qh, ql, kh, kl, kth, ktl, vh, vl, ob,
            ROWS, 1024, HIDN, 1);

        ifproj<<<ROWS, 64, 0, stream>>>(hbh, hbl,
                                        wi + (size_t)l * HIDN * NH,
                                        wf + (size_t)l * HIDN * NH,
                                        bi + l * NH, bf + l * NH, ir, fr);

        mlstm_attn<<<BATCH * NH, 256, 0, stream>>>(
            qh, ql, kh, kl, kth, ktl, vh, vl, ob, ir, fr, hbh, hbl);

        layernorm_sp<<<ROWS, 64, 0, stream>>>(hbh, hbl,
                                              lng + (size_t)l * HIDN,
                                              lnb + (size_t)l * HIDN);
    }

    head_mlp<<<BATCH, 128, 0, stream>>>(hbh, hbl, W1, b1, W2, b2, out);
}

// Round 6
// 288.092 us; speedup vs baseline: 2.2565x; 1.1148x over previous
//
#include <hip/hip_runtime.h>
#include <math.h>

typedef __attribute__((ext_vector_type(4))) float f32x4;
typedef __attribute__((ext_vector_type(8))) short bf16x8;

constexpr int BATCH = 256;
constexpr int TT    = 64;
constexpr int NH    = 4;
constexpr int DH    = 64;
constexpr int HIDN  = 256;
constexpr int INDIM = 170;
constexpr int KPAD  = 192;
constexpr int ROWS  = BATCH * TT;    // 16384
constexpr float EPS = 1e-5f;

#define MF(a, b, c) __builtin_amdgcn_mfma_f32_16x16x32_bf16((a), (b), (c), 0, 0, 0)

__device__ __forceinline__ unsigned short f2b(float f) {
    union { float f; unsigned int u; } v; v.f = f;
    return (unsigned short)((v.u + 0x7FFFu + ((v.u >> 16) & 1u)) >> 16);
}
__device__ __forceinline__ float b2f(unsigned short b) {
    union { unsigned int u; float f; } v; v.u = ((unsigned int)b) << 16;
    return v.f;
}
__device__ __forceinline__ void fsplit(float x, unsigned short& hi, unsigned short& lo) {
    hi = f2b(x);
    lo = f2b(x - b2f(hi));
}

// ---------------------------------------------------------------------------
// pack_x: x [ROWS][170] f32 -> xh/xl [ROWS][192] split bf16 (zero-padded)
// ---------------------------------------------------------------------------
__global__ __launch_bounds__(256) void pack_x(
    const float* __restrict__ x,
    unsigned short* __restrict__ xh, unsigned short* __restrict__ xl)
{
    int idx = blockIdx.x * 256 + threadIdx.x;
    if (idx >= ROWS * KPAD) return;
    int r = idx / KPAD, c = idx % KPAD;
    float v = (c < INDIM) ? x[(size_t)r * INDIM + c] : 0.f;
    unsigned short hi, lo; fsplit(v, hi, lo);
    xh[idx] = hi; xl[idx] = lo;
}

// ---------------------------------------------------------------------------
// pack_w: weights -> split-bf16 [N][K] (B-transposed) layout.
// ---------------------------------------------------------------------------
__global__ __launch_bounds__(256) void pack_w(
    const float* __restrict__ Wp, const float* __restrict__ Wq,
    const float* __restrict__ Wk, const float* __restrict__ Wv,
    const float* __restrict__ Wo,
    unsigned short* __restrict__ WpTh, unsigned short* __restrict__ WpTl,
    unsigned short* __restrict__ Wth,  unsigned short* __restrict__ Wtl)
{
    int idx = blockIdx.x * 256 + threadIdx.x;
    if (idx < HIDN * KPAD) {
        int n = idx / KPAD, kc = idx % KPAD;
        float v = (kc < INDIM) ? Wp[(size_t)kc * HIDN + n] : 0.f;
        unsigned short hi, lo; fsplit(v, hi, lo);
        WpTh[idx] = hi; WpTl[idx] = lo;
        return;
    }
    idx -= HIDN * KPAD;
    if (idx < 2 * 1024 * 256) {
        int l = idx / (1024 * 256);
        int r = idx % (1024 * 256);
        int n = r / 256, k = r % 256;
        int seg = n >> 8, ns = n & 255;
        const float* W = (seg == 0) ? Wq : (seg == 1) ? Wk : (seg == 2) ? Wv : Wo;
        float v = W[(size_t)l * 65536 + (size_t)k * 256 + ns];
        unsigned short hi, lo; fsplit(v, hi, lo);
        Wth[(size_t)l * 1024 * 256 + r] = hi;
        Wtl[(size_t)l * 1024 * 256 + r] = lo;
    }
}

// ---------------------------------------------------------------------------
// split-bf16 MFMA GEMM (3-product): C = epi(Ah@Bh^T + Ah@Bl^T + Al@Bh^T)
// 128x128 tile, 4 waves, 16x16x32, BK=64.
// LDS tiles bank-conflict-free: global source column pre-swizzled
// (cb ^ (row&7), 16B blocks), ds_read applies the matching XOR.
// mode 0: +bias -> split write c0/c1 [M][N] (2B each)
// mode 1: fused qkvo (N=1024): seg0 *0.125, seg3 sigmoid(+bias);
//         single packed u32 (hi<<16|lo) coalesced write to qkvoP [M][1024]
// ---------------------------------------------------------------------------
__global__ __launch_bounds__(256) void gemm_mfma3(
    const unsigned short* __restrict__ Ah, const unsigned short* __restrict__ Al,
    const unsigned short* __restrict__ Bh, const unsigned short* __restrict__ Bl,
    const float* __restrict__ bias,
    unsigned short* __restrict__ c0, unsigned short* __restrict__ c1,
    unsigned int* __restrict__ qkvoP,
    int M, int N, int K, int mode)
{
    __shared__ unsigned short AsH[128 * 64];
    __shared__ unsigned short AsL[128 * 64];
    __shared__ unsigned short BsH[128 * 64];
    __shared__ unsigned short BsL[128 * 64];
    const int tid  = threadIdx.x;
    const int lane = tid & 63;
    const int wave = tid >> 6;
    const int wr = wave >> 1, wc = wave & 1;
    const int m0 = blockIdx.y * 128, n0 = blockIdx.x * 128;

    f32x4 acc[4][4] = {};

    for (int k0 = 0; k0 < K; k0 += 64) {
        #pragma unroll
        for (int j = 0; j < 4; j++) {
            int c   = j * 256 + tid;          // 16B chunk id 0..1023
            int row = c >> 3;
            int kcs = ((c & 7) ^ (row & 7)) * 8;   // pre-swizzled source column
            size_t aoff = (size_t)(m0 + row) * K + k0 + kcs;
            size_t boff = (size_t)(n0 + row) * K + k0 + kcs;
            __builtin_amdgcn_global_load_lds(
                (const __attribute__((address_space(1))) void*)(Ah + aoff),
                (__attribute__((address_space(3))) void*)(AsH + c * 8), 16, 0, 0);
            __builtin_amdgcn_global_load_lds(
                (const __attribute__((address_space(1))) void*)(Al + aoff),
                (__attribute__((address_space(3))) void*)(AsL + c * 8), 16, 0, 0);
            __builtin_amdgcn_global_load_lds(
                (const __attribute__((address_space(1))) void*)(Bh + boff),
                (__attribute__((address_space(3))) void*)(BsH + c * 8), 16, 0, 0);
            __builtin_amdgcn_global_load_lds(
                (const __attribute__((address_space(1))) void*)(Bl + boff),
                (__attribute__((address_space(3))) void*)(BsL + c * 8), 16, 0, 0);
        }
        asm volatile("s_waitcnt vmcnt(0)" ::: "memory");
        __syncthreads();

        #pragma unroll
        for (int kk = 0; kk < 2; kk++) {
            bf16x8 ah[4], al[4], bh[4], bl[4];
            #pragma unroll
            for (int i = 0; i < 4; i++) {
                const int ar  = wr * 64 + i * 16 + (lane & 15);
                const int off = ar * 64 + (((kk * 4 + (lane >> 4)) ^ (ar & 7)) * 8);
                ah[i] = *(const bf16x8*)&AsH[off];
                al[i] = *(const bf16x8*)&AsL[off];
            }
            #pragma unroll
            for (int j = 0; j < 4; j++) {
                const int br  = wc * 64 + j * 16 + (lane & 15);
                const int off = br * 64 + (((kk * 4 + (lane >> 4)) ^ (br & 7)) * 8);
                bh[j] = *(const bf16x8*)&BsH[off];
                bl[j] = *(const bf16x8*)&BsL[off];
            }
            #pragma unroll
            for (int i = 0; i < 4; i++) {
                #pragma unroll
                for (int j = 0; j < 4; j++) {
                    acc[i][j] = MF(ah[i], bh[j], acc[i][j]);
                    acc[i][j] = MF(ah[i], bl[j], acc[i][j]);
                    acc[i][j] = MF(al[i], bh[j], acc[i][j]);
                }
            }
        }
        __syncthreads();
    }

    if (mode == 0) {
        #pragma unroll
        for (int i = 0; i < 4; i++) {
            #pragma unroll
            for (int j = 0; j < 4; j++) {
                const int col = n0 + wc * 64 + j * 16 + (lane & 15);
                const float bv = bias[col];
                #pragma unroll
                for (int r = 0; r < 4; r++) {
                    const int row = m0 + wr * 64 + i * 16 + (lane >> 4) * 4 + r;
                    float v = acc[i][j][r] + bv;
                    unsigned short hi, lo; fsplit(v, hi, lo);
                    c0[(size_t)row * N + col] = hi;
                    c1[(size_t)row * N + col] = lo;
                }
            }
        }
    } else {
        #pragma unroll
        for (int i = 0; i < 4; i++) {
            #pragma unroll
            for (int j = 0; j < 4; j++) {
                const int col = n0 + wc * 64 + j * 16 + (lane & 15);
                const int seg = col >> 8;
                const float scale = (seg == 0) ? 0.125f : 1.f;
                #pragma unroll
                for (int r = 0; r < 4; r++) {
                    const int row = m0 + wr * 64 + i * 16 + (lane >> 4) * 4 + r;
                    float v = acc[i][j][r] * scale;
                    if (seg == 3) v = 1.f / (1.f + __expf(-(v + bias[col & 255])));
                    unsigned short hi, lo; fsplit(v, hi, lo);
                    qkvoP[(size_t)row * 1024 + col] = ((unsigned int)hi << 16) | lo;
                }
            }
        }
    }
}

// ---------------------------------------------------------------------------
// i/f gate projection. 256 threads = 4 waves, one row per wave.
// ---------------------------------------------------------------------------
__global__ __launch_bounds__(256) void ifproj(
    const unsigned short* __restrict__ hbh, const unsigned short* __restrict__ hbl,
    const float* __restrict__ wi, const float* __restrict__ wf,
    const float* __restrict__ bi, const float* __restrict__ bf,
    float* __restrict__ iout, float* __restrict__ fout)
{
    __shared__ float hr[4][HIDN];
    const int w    = threadIdx.x >> 6;
    const int lane = threadIdx.x & 63;
    const int row  = blockIdx.x * 4 + w;
    ushort4 a4 = *(const ushort4*)(hbh + (size_t)row * HIDN + lane * 4);
    ushort4 l4 = *(const ushort4*)(hbl + (size_t)row * HIDN + lane * 4);
    hr[w][lane * 4 + 0] = b2f(a4.x) + b2f(l4.x);
    hr[w][lane * 4 + 1] = b2f(a4.y) + b2f(l4.y);
    hr[w][lane * 4 + 2] = b2f(a4.z) + b2f(l4.z);
    hr[w][lane * 4 + 3] = b2f(a4.w) + b2f(l4.w);
    __syncthreads();

    const int out  = lane >> 3;
    const int part = lane & 7;
    const float* W = (out < 4) ? wi : wf;
    const int oc   = out & 3;
    float s = 0.f;
    #pragma unroll
    for (int c = 0; c < 32; c++) {
        int idx = part * 32 + c;
        s += hr[w][idx] * W[idx * NH + oc];
    }
    s += __shfl_xor(s, 1);
    s += __shfl_xor(s, 2);
    s += __shfl_xor(s, 4);
    if (part == 0) {
        float b = (out < 4) ? bi[oc] : bf[oc];
        float r = s + b;
        if (out < 4) iout[(size_t)row * NH + oc] = r;
        else         fout[(size_t)row * NH + oc] = r;
    }
}

// ---------------------------------------------------------------------------
// mLSTM parallel form. One block (4 waves) per (b,h). Input: packed qkvoP.
// Reg-stage + unpack + swizzled ds_write builds Q/K/KT/V hi/lo LDS tiles.
//   Sv = Q@V^T, Sk = Q@K^T; w_ts = exp(a_s + F_t - m_t) (s<=t)
//   P = W.*Sv; den = rowsum(W.*Sk); num = P@K (KT tile); h = o.*num/den
// ---------------------------------------------------------------------------
__global__ __launch_bounds__(256) void mlstm_attn(
    const unsigned int* __restrict__ qkvoP,
    const float* __restrict__ irg, const float* __restrict__ frg,
    unsigned short* __restrict__ hoh, unsigned short* __restrict__ hol)
{
    __shared__ unsigned short sm[8 * 4096];   // Qh Ql Kh Kl Th Tl Vh Vl
    __shared__ float sa[TT], sc[TT];
    const int bh = blockIdx.x;
    const int b  = bh >> 2;
    const int hh = bh & 3;
    const int tid = threadIdx.x, lane = tid & 63, w = tid >> 6;

    // stage q,k,v from packed buffer
    const int tS = tid >> 4;           // 0..15 row within 16-row slab
    const int dw = (tid & 15) * 4;     // word col base
    #pragma unroll
    for (int seg = 0; seg < 3; seg++) {
        #pragma unroll
        for (int itr = 0; itr < 4; itr++) {
            const int t = itr * 16 + tS;
            const uint4 wv = *(const uint4*)&qkvoP[(size_t)(b * TT + t) * 1024 + seg * 256 + hh * DH + dw];
            ushort4 h4, l4;
            h4.x = (unsigned short)(wv.x >> 16); l4.x = (unsigned short)wv.x;
            h4.y = (unsigned short)(wv.y >> 16); l4.y = (unsigned short)wv.y;
            h4.z = (unsigned short)(wv.z >> 16); l4.z = (unsigned short)wv.z;
            h4.w = (unsigned short)(wv.w >> 16); l4.w = (unsigned short)wv.w;
            const int col = dw ^ ((t & 7) << 3);
            if (seg == 0) {
                *(ushort4*)&sm[0 * 4096 + t * 64 + col] = h4;
                *(ushort4*)&sm[1 * 4096 + t * 64 + col] = l4;
            } else if (seg == 1) {
                *(ushort4*)&sm[2 * 4096 + t * 64 + col] = h4;
                *(ushort4*)&sm[3 * 4096 + t * 64 + col] = l4;
                // transposed copy for the PV B-operand
                sm[4 * 4096 + (dw + 0) * 64 + (t ^ (((dw + 0) & 7) << 3))] = h4.x;
                sm[4 * 4096 + (dw + 1) * 64 + (t ^ (((dw + 1) & 7) << 3))] = h4.y;
                sm[4 * 4096 + (dw + 2) * 64 + (t ^ (((dw + 2) & 7) << 3))] = h4.z;
                sm[4 * 4096 + (dw + 3) * 64 + (t ^ (((dw + 3) & 7) << 3))] = h4.w;
                sm[5 * 4096 + (dw + 0) * 64 + (t ^ (((dw + 0) & 7) << 3))] = l4.x;
                sm[5 * 4096 + (dw + 1) * 64 + (t ^ (((dw + 1) & 7) << 3))] = l4.y;
                sm[5 * 4096 + (dw + 2) * 64 + (t ^ (((dw + 2) & 7) << 3))] = l4.z;
                sm[5 * 4096 + (dw + 3) * 64 + (t ^ (((dw + 3) & 7) << 3))] = l4.w;
            } else {
                *(ushort4*)&sm[6 * 4096 + t * 64 + col] = h4;
                *(ushort4*)&sm[7 * 4096 + t * 64 + col] = l4;
            }
        }
    }

    // wave 0: gate prefix scans
    if (w == 0) {
        const int t = lane;
        float iv = irg[(size_t)(b * TT + t) * NH + hh];
        float fv = frg[(size_t)(b * TT + t) * NH + hh];
        float F = fv;
        #pragma unroll
        for (int d2 = 1; d2 < 64; d2 <<= 1) { float o2 = __shfl_up(F, d2); if (lane >= d2) F += o2; }
        float av = iv - F;
        float pm = av;
        #pragma unroll
        for (int d2 = 1; d2 < 64; d2 <<= 1) { float o2 = __shfl_up(pm, d2); if (lane >= d2) pm = fmaxf(pm, o2); }
        sa[t] = av;
        sc[t] = -fmaxf(0.f, pm);   // F_t - m_t
    }
    __syncthreads();

    // S phase: wave w owns t-rows [16w,16w+16)
    f32x4 accv[4] = {}, acck[4] = {};
    const int tA = w * 16 + (lane & 15);
    #pragma unroll
    for (int kk = 0; kk < 2; kk++) {
        const int eA = (kk * 32 + (lane >> 4) * 8) ^ ((tA & 7) << 3);
        bf16x8 aQh = *(const bf16x8*)&sm[0 * 4096 + tA * 64 + eA];
        bf16x8 aQl = *(const bf16x8*)&sm[1 * 4096 + tA * 64 + eA];
        #pragma unroll
        for (int j = 0; j < 4; j++) {
            const int sB = j * 16 + (lane & 15);
            const int eB = (kk * 32 + (lane >> 4) * 8) ^ ((sB & 7) << 3);
            bf16x8 bKh = *(const bf16x8*)&sm[2 * 4096 + sB * 64 + eB];
            bf16x8 bKl = *(const bf16x8*)&sm[3 * 4096 + sB * 64 + eB];
            bf16x8 bVh = *(const bf16x8*)&sm[6 * 4096 + sB * 64 + eB];
            bf16x8 bVl = *(const bf16x8*)&sm[7 * 4096 + sB * 64 + eB];
            accv[j] = MF(aQh, bVh, accv[j]);
            accv[j] = MF(aQh, bVl, accv[j]);
            accv[j] = MF(aQl, bVh, accv[j]);
            acck[j] = MF(aQh, bKh, acck[j]);
            acck[j] = MF(aQh, bKl, acck[j]);
            acck[j] = MF(aQl, bKh, acck[j]);
        }
    }

    // mask + denominator
    const int tbase = w * 16 + (lane >> 4) * 4;
    float cw[4];
    #pragma unroll
    for (int r = 0; r < 4; r++) cw[r] = sc[tbase + r];
    float den4[4] = {0.f, 0.f, 0.f, 0.f};
    #pragma unroll
    for (int j = 0; j < 4; j++) {
        const int s = j * 16 + (lane & 15);
        const float as = sa[s];
        #pragma unroll
        for (int r = 0; r < 4; r++) {
            const int t = tbase + r;
            const float wgt = (s <= t) ? __expf(as + cw[r]) : 0.f;
            accv[j][r] *= wgt;
            den4[r] += acck[j][r] * wgt;
        }
    }
    #pragma unroll
    for (int r = 0; r < 4; r++) {
        den4[r] += __shfl_xor(den4[r], 1);
        den4[r] += __shfl_xor(den4[r], 2);
        den4[r] += __shfl_xor(den4[r], 4);
        den4[r] += __shfl_xor(den4[r], 8);
        den4[r] = fmaxf(fabsf(den4[r]), 1.f);
    }

    __syncthreads();   // all waves done reading Q/K before P overlays them

    // P split into sm[0..9216) with row stride 72
    #pragma unroll
    for (int j = 0; j < 4; j++) {
        const int s = j * 16 + (lane & 15);
        #pragma unroll
        for (int r = 0; r < 4; r++) {
            const int t = tbase + r;
            unsigned short hi, lo; fsplit(accv[j][r], hi, lo);
            sm[t * 72 + s] = hi;
            sm[4608 + t * 72 + s] = lo;
        }
    }
    __syncthreads();

    // PV phase: num = P @ K (B operand from KT tile)
    f32x4 num[4] = {};
    #pragma unroll
    for (int kk = 0; kk < 2; kk++) {
        const int sA = kk * 32 + (lane >> 4) * 8;
        bf16x8 aPh = *(const bf16x8*)&sm[tA * 72 + sA];
        bf16x8 aPl = *(const bf16x8*)&sm[4608 + tA * 72 + sA];
        #pragma unroll
        for (int j = 0; j < 4; j++) {
            const int eB2 = j * 16 + (lane & 15);
            const int tB = (kk * 32 + (lane >> 4) * 8) ^ ((eB2 & 7) << 3);
            bf16x8 bTh = *(const bf16x8*)&sm[4 * 4096 + eB2 * 64 + tB];
            bf16x8 bTl = *(const bf16x8*)&sm[5 * 4096 + eB2 * 64 + tB];
            num[j] = MF(aPh, bTh, num[j]);
            num[j] = MF(aPh, bTl, num[j]);
            num[j] = MF(aPl, bTh, num[j]);
        }
    }

    // output: h = o * num / den -> split bf16 (o read from packed buffer)
    #pragma unroll
    for (int j = 0; j < 4; j++) {
        const int e = j * 16 + (lane & 15);
        #pragma unroll
        for (int r = 0; r < 4; r++) {
            const int t = tbase + r;
            const unsigned int ow = qkvoP[(size_t)(b * TT + t) * 1024 + 768 + hh * DH + e];
            const float o = b2f((unsigned short)(ow >> 16)) + b2f((unsigned short)ow);
            const float hval = o * num[j][r] / den4[r];
            unsigned short hi, lo; fsplit(hval, hi, lo);
            const size_t oidx = (size_t)(b * TT + t) * HIDN + hh * DH + e;
            hoh[oidx] = hi; hol[oidx] = lo;
        }
    }
}

// ---------------------------------------------------------------------------
// LayerNorm over 256, in-place on the split pair. 4 waves = 4 rows per block.
// ---------------------------------------------------------------------------
__global__ __launch_bounds__(256) void layernorm_sp(
    unsigned short* __restrict__ hh_, unsigned short* __restrict__ hl_,
    const float* __restrict__ g, const float* __restrict__ bta)
{
    const int w    = threadIdx.x >> 6;
    const int lane = threadIdx.x & 63;
    const int row  = blockIdx.x * 4 + w;
    ushort4 a4 = *(const ushort4*)(hh_ + (size_t)row * HIDN + lane * 4);
    ushort4 l4 = *(const ushort4*)(hl_ + (size_t)row * HIDN + lane * 4);
    float x0 = b2f(a4.x) + b2f(l4.x);
    float x1 = b2f(a4.y) + b2f(l4.y);
    float x2 = b2f(a4.z) + b2f(l4.z);
    float x3 = b2f(a4.w) + b2f(l4.w);
    float s = x0 + x1 + x2 + x3;
    #pragma unroll
    for (int off = 32; off; off >>= 1) s += __shfl_xor(s, off);
    const float mu = s * (1.f / 256.f);
    const float d0 = x0 - mu, d1 = x1 - mu, d2 = x2 - mu, d3 = x3 - mu;
    float vs = d0*d0 + d1*d1 + d2*d2 + d3*d3;
    #pragma unroll
    for (int off = 32; off; off >>= 1) vs += __shfl_xor(vs, off);
    const float rstd = rsqrtf(vs * (1.f / 256.f) + EPS);
    const float4 gv = *(const float4*)(g + lane * 4);
    const float4 bv = *(const float4*)(bta + lane * 4);
    float y0 = d0 * rstd * gv.x + bv.x;
    float y1 = d1 * rstd * gv.y + bv.y;
    float y2 = d2 * rstd * gv.z + bv.z;
    float y3 = d3 * rstd * gv.w + bv.w;
    ushort4 h4, o4;
    fsplit(y0, h4.x, o4.x); fsplit(y1, h4.y, o4.y);
    fsplit(y2, h4.z, o4.z); fsplit(y3, h4.w, o4.w);
    *(ushort4*)(hh_ + (size_t)row * HIDN + lane * 4) = h4;
    *(ushort4*)(hl_ + (size_t)row * HIDN + lane * 4) = o4;
}

// ---------------------------------------------------------------------------
// Final head: z = h[:, T-1, :]; out = relu(z@W1 + b1) @ W2 + b2
// ---------------------------------------------------------------------------
__global__ __launch_bounds__(128) void head_mlp(
    const unsigned short* __restrict__ hbh, const unsigned short* __restrict__ hbl,
    const float* __restrict__ W1, const float* __restrict__ b1,
    const float* __restrict__ W2, const float* __restrict__ b2,
    float* __restrict__ out)
{
    const int b = blockIdx.x;
    const int j = threadIdx.x;
    __shared__ float z[HIDN];
    __shared__ float a[128];
    const size_t rb = ((size_t)b * TT + (TT - 1)) * HIDN;
    z[j]       = b2f(hbh[rb + j])       + b2f(hbl[rb + j]);
    z[j + 128] = b2f(hbh[rb + j + 128]) + b2f(hbl[rb + j + 128]);
    __syncthreads();
    float acc = b1[j];
    #pragma unroll 4
    for (int c = 0; c < HIDN; c++) acc += z[c] * W1[c * 128 + j];
    a[j] = fmaxf(acc, 0.f);
    __syncthreads();
    if (j < 2) {
        float s = b2[j];
        for (int c = 0; c < 128; c++) s += a[c] * W2[c * 2 + j];
        out[b * 2 + j] = s;
    }
}

// ---------------------------------------------------------------------------
extern "C" void kernel_launch(void* const* d_in, const int* in_sizes, int n_in,
                              void* d_out, int out_size, void* d_ws, size_t ws_size,
                              hipStream_t stream)
{
    const float* x   = (const float*)d_in[0];
    const float* Wp  = (const float*)d_in[1];
    const float* bp  = (const float*)d_in[2];
    const float* Wq  = (const float*)d_in[3];
    const float* Wk  = (const float*)d_in[4];
    const float* Wv  = (const float*)d_in[5];
    const float* Wo  = (const float*)d_in[6];
    const float* bo  = (const float*)d_in[7];
    const float* wi  = (const float*)d_in[8];
    const float* bi  = (const float*)d_in[9];
    const float* wf  = (const float*)d_in[10];
    const float* bf  = (const float*)d_in[11];
    const float* lng = (const float*)d_in[12];
    const float* lnb = (const float*)d_in[13];
    const float* W1  = (const float*)d_in[14];
    const float* b1  = (const float*)d_in[15];
    const float* W2  = (const float*)d_in[16];
    const float* b2  = (const float*)d_in[17];
    float* out = (float*)d_out;

    // workspace layout (~87 MB)
    unsigned int*   qkvoP = (unsigned int*)d_ws;                       // 67.1 MB [ROWS][1024] u32
    unsigned short* hbh   = (unsigned short*)(qkvoP + (size_t)ROWS * 1024);
    unsigned short* hbl   = hbh + (size_t)ROWS * HIDN;
    float*          ir    = (float*)(hbl + (size_t)ROWS * HIDN);
    float*          fr    = ir + (size_t)ROWS * NH;
    unsigned short* WpTh  = (unsigned short*)(fr + (size_t)ROWS * NH);
    unsigned short* WpTl  = WpTh + (size_t)HIDN * KPAD;
    unsigned short* Wth   = WpTl + (size_t)HIDN * KPAD;
    unsigned short* Wtl   = Wth + (size_t)2 * 1024 * 256;
    // pack_x outputs alias qkvoP (dead until first mode-1 GEMM)
    unsigned short* xh = (unsigned short*)qkvoP;
    unsigned short* xl = xh + (size_t)ROWS * KPAD;

    pack_x<<<(ROWS * KPAD + 255) / 256, 256, 0, stream>>>(x, xh, xl);
    {
        int tot = HIDN * KPAD + 2 * 1024 * 256;
        pack_w<<<(tot + 255) / 256, 256, 0, stream>>>(Wp, Wq, Wk, Wv, Wo,
                                                      WpTh, WpTl, Wth, Wtl);
    }

    // input projection: hb = x @ Wp + bp (split)
    gemm_mfma3<<<dim3(2, 128), 256, 0, stream>>>(
        xh, xl, WpTh, WpTl, bp, hbh, hbl, nullptr, ROWS, HIDN, KPAD, 0);

    for (int l = 0; l < 2; l++) {
        gemm_mfma3<<<dim3(8, 128), 256, 0, stream>>>(
            hbh, hbl, Wth + (size_t)l * 1024 * 256, Wtl + (size_t)l * 1024 * 256,
            bo + (size_t)l * HIDN, nullptr, nullptr, qkvoP,
            ROWS, 1024, HIDN, 1);

        ifproj<<<ROWS / 4, 256, 0, stream>>>(hbh, hbl,
                                             wi + (size_t)l * HIDN * NH,
                                             wf + (size_t)l * HIDN * NH,
                                             bi + l * NH, bf + l * NH, ir, fr);

        mlstm_attn<<<BATCH * NH, 256, 0, stream>>>(qkvoP, ir, fr, hbh, hbl);

        layernorm_sp<<<ROWS / 4, 256, 0, stream>>>(hbh, hbl,
                                                   lng + (size_t)l * HIDN,
                                                   lnb + (size_t)l * HIDN);
    }

    head_mlp<<<BATCH, 128, 0, stream>>>(hbh, hbl, W1, b1, W2, b2, out);
}

// Round 7
// 250.646 us; speedup vs baseline: 2.5936x; 1.1494x over previous
//
#include <hip/hip_runtime.h>
#include <math.h>

typedef __attribute__((ext_vector_type(4))) float f32x4;
typedef __attribute__((ext_vector_type(8))) short bf16x8;

constexpr int BATCH = 256;
constexpr int TT    = 64;
constexpr int NH    = 4;
constexpr int DH    = 64;
constexpr int HIDN  = 256;
constexpr int INDIM = 170;
constexpr int KPAD  = 192;
constexpr int ROWS  = BATCH * TT;    // 16384
constexpr float EPS = 1e-5f;

#define MF(a, b, c) __builtin_amdgcn_mfma_f32_16x16x32_bf16((a), (b), (c), 0, 0, 0)

__device__ __forceinline__ unsigned short f2b(float f) {
    union { float f; unsigned int u; } v; v.f = f;
    return (unsigned short)((v.u + 0x7FFFu + ((v.u >> 16) & 1u)) >> 16);
}
__device__ __forceinline__ float b2f(unsigned short b) {
    union { unsigned int u; float f; } v; v.u = ((unsigned int)b) << 16;
    return v.f;
}
__device__ __forceinline__ void fsplit(float x, unsigned short& hi, unsigned short& lo) {
    hi = f2b(x);
    lo = f2b(x - b2f(hi));
}

// ---------------------------------------------------------------------------
// pack_x: x [ROWS][170] f32 -> xh/xl [ROWS][192] split bf16 (zero-padded)
// ---------------------------------------------------------------------------
__global__ __launch_bounds__(256) void pack_x(
    const float* __restrict__ x,
    unsigned short* __restrict__ xh, unsigned short* __restrict__ xl)
{
    int idx = blockIdx.x * 256 + threadIdx.x;
    if (idx >= ROWS * KPAD) return;
    int r = idx / KPAD, c = idx % KPAD;
    float v = (c < INDIM) ? x[(size_t)r * INDIM + c] : 0.f;
    unsigned short hi, lo; fsplit(v, hi, lo);
    xh[idx] = hi; xl[idx] = lo;
}

// ---------------------------------------------------------------------------
// pack_w: weights -> split-bf16 [N][K] (B-transposed) layout.
// ---------------------------------------------------------------------------
__global__ __launch_bounds__(256) void pack_w(
    const float* __restrict__ Wp, const float* __restrict__ Wq,
    const float* __restrict__ Wk, const float* __restrict__ Wv,
    const float* __restrict__ Wo,
    unsigned short* __restrict__ WpTh, unsigned short* __restrict__ WpTl,
    unsigned short* __restrict__ Wth,  unsigned short* __restrict__ Wtl)
{
    int idx = blockIdx.x * 256 + threadIdx.x;
    if (idx < HIDN * KPAD) {
        int n = idx / KPAD, kc = idx % KPAD;
        float v = (kc < INDIM) ? Wp[(size_t)kc * HIDN + n] : 0.f;
        unsigned short hi, lo; fsplit(v, hi, lo);
        WpTh[idx] = hi; WpTl[idx] = lo;
        return;
    }
    idx -= HIDN * KPAD;
    if (idx < 2 * 1024 * 256) {
        int l = idx / (1024 * 256);
        int r = idx % (1024 * 256);
        int n = r / 256, k = r % 256;
        int seg = n >> 8, ns = n & 255;
        const float* W = (seg == 0) ? Wq : (seg == 1) ? Wk : (seg == 2) ? Wv : Wo;
        float v = W[(size_t)l * 65536 + (size_t)k * 256 + ns];
        unsigned short hi, lo; fsplit(v, hi, lo);
        Wth[(size_t)l * 1024 * 256 + r] = hi;
        Wtl[(size_t)l * 1024 * 256 + r] = lo;
    }
}

// ---------------------------------------------------------------------------
// split-bf16 MFMA GEMM (3-product), mode-0 only (input projection).
// 128x128 tile, 4 waves. m from blockIdx.x so same-A blocks share an XCD.
// ---------------------------------------------------------------------------
__global__ __launch_bounds__(256) void gemm_mfma3(
    const unsigned short* __restrict__ Ah, const unsigned short* __restrict__ Al,
    const unsigned short* __restrict__ Bh, const unsigned short* __restrict__ Bl,
    const float* __restrict__ bias,
    unsigned short* __restrict__ c0, unsigned short* __restrict__ c1,
    int M, int N, int K)
{
    __shared__ unsigned short AsH[128 * 64];
    __shared__ unsigned short AsL[128 * 64];
    __shared__ unsigned short BsH[128 * 64];
    __shared__ unsigned short BsL[128 * 64];
    const int tid  = threadIdx.x;
    const int lane = tid & 63;
    const int wave = tid >> 6;
    const int wr = wave >> 1, wc = wave & 1;
    const int m0 = blockIdx.x * 128, n0 = blockIdx.y * 128;

    f32x4 acc[4][4] = {};

    for (int k0 = 0; k0 < K; k0 += 64) {
        #pragma unroll
        for (int j = 0; j < 4; j++) {
            int c   = j * 256 + tid;
            int row = c >> 3;
            int kcs = ((c & 7) ^ (row & 7)) * 8;
            size_t aoff = (size_t)(m0 + row) * K + k0 + kcs;
            size_t boff = (size_t)(n0 + row) * K + k0 + kcs;
            __builtin_amdgcn_global_load_lds(
                (const __attribute__((address_space(1))) void*)(Ah + aoff),
                (__attribute__((address_space(3))) void*)(AsH + c * 8), 16, 0, 0);
            __builtin_amdgcn_global_load_lds(
                (const __attribute__((address_space(1))) void*)(Al + aoff),
                (__attribute__((address_space(3))) void*)(AsL + c * 8), 16, 0, 0);
            __builtin_amdgcn_global_load_lds(
                (const __attribute__((address_space(1))) void*)(Bh + boff),
                (__attribute__((address_space(3))) void*)(BsH + c * 8), 16, 0, 0);
            __builtin_amdgcn_global_load_lds(
                (const __attribute__((address_space(1))) void*)(Bl + boff),
                (__attribute__((address_space(3))) void*)(BsL + c * 8), 16, 0, 0);
        }
        asm volatile("s_waitcnt vmcnt(0)" ::: "memory");
        __syncthreads();

        #pragma unroll
        for (int kk = 0; kk < 2; kk++) {
            bf16x8 ah[4], al[4], bh[4], bl[4];
            #pragma unroll
            for (int i = 0; i < 4; i++) {
                const int ar  = wr * 64 + i * 16 + (lane & 15);
                const int off = ar * 64 + (((kk * 4 + (lane >> 4)) ^ (ar & 7)) * 8);
                ah[i] = *(const bf16x8*)&AsH[off];
                al[i] = *(const bf16x8*)&AsL[off];
            }
            #pragma unroll
            for (int j = 0; j < 4; j++) {
                const int br  = wc * 64 + j * 16 + (lane & 15);
                const int off = br * 64 + (((kk * 4 + (lane >> 4)) ^ (br & 7)) * 8);
                bh[j] = *(const bf16x8*)&BsH[off];
                bl[j] = *(const bf16x8*)&BsL[off];
            }
            #pragma unroll
            for (int i = 0; i < 4; i++) {
                #pragma unroll
                for (int j = 0; j < 4; j++) {
                    acc[i][j] = MF(ah[i], bh[j], acc[i][j]);
                    acc[i][j] = MF(ah[i], bl[j], acc[i][j]);
                    acc[i][j] = MF(al[i], bh[j], acc[i][j]);
                }
            }
        }
        __syncthreads();
    }

    #pragma unroll
    for (int i = 0; i < 4; i++) {
        #pragma unroll
        for (int j = 0; j < 4; j++) {
            const int col = n0 + wc * 64 + j * 16 + (lane & 15);
            const float bv = bias[col];
            #pragma unroll
            for (int r = 0; r < 4; r++) {
                const int row = m0 + wr * 64 + i * 16 + (lane >> 4) * 4 + r;
                float v = acc[i][j][r] + bv;
                unsigned short hi, lo; fsplit(v, hi, lo);
                c0[(size_t)row * N + col] = hi;
                c1[(size_t)row * N + col] = lo;
            }
        }
    }
}

// ---------------------------------------------------------------------------
// i/f gate projection. 256 threads = 4 waves, one row per wave.
// ---------------------------------------------------------------------------
__global__ __launch_bounds__(256) void ifproj(
    const unsigned short* __restrict__ hbh, const unsigned short* __restrict__ hbl,
    const float* __restrict__ wi, const float* __restrict__ wf,
    const float* __restrict__ bi, const float* __restrict__ bf,
    float* __restrict__ iout, float* __restrict__ fout)
{
    __shared__ float hr[4][HIDN];
    const int w    = threadIdx.x >> 6;
    const int lane = threadIdx.x & 63;
    const int row  = blockIdx.x * 4 + w;
    ushort4 a4 = *(const ushort4*)(hbh + (size_t)row * HIDN + lane * 4);
    ushort4 l4 = *(const ushort4*)(hbl + (size_t)row * HIDN + lane * 4);
    hr[w][lane * 4 + 0] = b2f(a4.x) + b2f(l4.x);
    hr[w][lane * 4 + 1] = b2f(a4.y) + b2f(l4.y);
    hr[w][lane * 4 + 2] = b2f(a4.z) + b2f(l4.z);
    hr[w][lane * 4 + 3] = b2f(a4.w) + b2f(l4.w);
    __syncthreads();

    const int out  = lane >> 3;
    const int part = lane & 7;
    const float* W = (out < 4) ? wi : wf;
    const int oc   = out & 3;
    float s = 0.f;
    #pragma unroll
    for (int c = 0; c < 32; c++) {
        int idx = part * 32 + c;
        s += hr[w][idx] * W[idx * NH + oc];
    }
    s += __shfl_xor(s, 1);
    s += __shfl_xor(s, 2);
    s += __shfl_xor(s, 4);
    if (part == 0) {
        float b = (out < 4) ? bi[oc] : bf[oc];
        float r = s + b;
        if (out < 4) iout[(size_t)row * NH + oc] = r;
        else         fout[(size_t)row * NH + oc] = r;
    }
}

// ---------------------------------------------------------------------------
// FUSED layer kernel: per-(b,h) qkvo projection (MFMA, split-bf16 3-product)
// + mLSTM parallel attention, all in LDS. Block = (b, h), 4 waves.
//   GEMM: M=64 (t), N=256 (wave w owns seg w: q|k|v|o), K=256 streamed BK=64.
//   Epilogue scatters Q/K/KT/V split tiles + f32 o-tile into LDS.
//   Attn: Sv=Q@V^T, Sk=Q@K^T; w_ts=exp(a_s + F_t - m_t); P=W.*Sv;
//   den=rowsum(W.*Sk); num=P@K (KT); h = o.*num/max(|den|,1) -> split out.
// Dynamic LDS 80 KiB (2 blocks/CU):
//   shorts: [0,4096) AsH / [4096,8192) AsL   -> f32 o-tile after k-loop
//           [8192,24576) BsH / [24576,40960) BsL
//   attn tiles over Bs: Qh 8192 Ql 12288 Kh 16384 Kl 20480
//                       Th 24576 Tl 28672 Vh 32768 Vl 36864
//   P overlay: Ph @8192 (stride 72), Pl @12800 (over dead Q/K-hi)
// ---------------------------------------------------------------------------
__global__ __launch_bounds__(256) void fused_layer(
    const unsigned short* __restrict__ Ah, const unsigned short* __restrict__ Al,
    const unsigned short* __restrict__ Bh, const unsigned short* __restrict__ Bl,
    const float* __restrict__ bo,
    const float* __restrict__ irg, const float* __restrict__ frg,
    unsigned short* __restrict__ hoh, unsigned short* __restrict__ hol)
{
    extern __shared__ char smem[];
    unsigned short* const S = (unsigned short*)smem;
    float* const Ot = (float*)smem;
    const int b  = blockIdx.x;
    const int hh = blockIdx.y;
    const int tid = threadIdx.x, lane = tid & 63, w = tid >> 6;

    // gate prefix scans, fully in registers (redundant per wave)
    float iv = irg[(size_t)(b * TT + lane) * NH + hh];
    float fv = frg[(size_t)(b * TT + lane) * NH + hh];
    float F = fv;
    #pragma unroll
    for (int d2 = 1; d2 < 64; d2 <<= 1) { float o2 = __shfl_up(F, d2); if (lane >= d2) F += o2; }
    const float sa_r = iv - F;                     // a_t = i_t - F_t
    float pm = sa_r;
    #pragma unroll
    for (int d2 = 1; d2 < 64; d2 <<= 1) { float o2 = __shfl_up(pm, d2); if (lane >= d2) pm = fmaxf(pm, o2); }
    const float sc_r = -fmaxf(0.f, pm);            // F_t - m_t

    // ---- GEMM phase ----
    f32x4 acc[4][4] = {};
    for (int k0 = 0; k0 < 256; k0 += 64) {
        #pragma unroll
        for (int j2 = 0; j2 < 2; j2++) {           // A tile: 64x64 h+l
            int c = j2 * 256 + tid;                // 0..511
            int row = c >> 3;
            int kcs = ((c & 7) ^ (row & 7)) * 8;
            size_t off = (size_t)(b * TT + row) * 256 + k0 + kcs;
            __builtin_amdgcn_global_load_lds(
                (const __attribute__((address_space(1))) void*)(Ah + off),
                (__attribute__((address_space(3))) void*)(S + c * 8), 16, 0, 0);
            __builtin_amdgcn_global_load_lds(
                (const __attribute__((address_space(1))) void*)(Al + off),
                (__attribute__((address_space(3))) void*)(S + 4096 + c * 8), 16, 0, 0);
        }
        #pragma unroll
        for (int j2 = 0; j2 < 8; j2++) {           // B tile: 256x64 h+l
            int c = j2 * 256 + tid;                // 0..2047
            int n = c >> 3;
            int kcs = ((c & 7) ^ (n & 7)) * 8;
            int grow = (n >> 6) * 256 + hh * 64 + (n & 63);
            size_t off = (size_t)grow * 256 + k0 + kcs;
            __builtin_amdgcn_global_load_lds(
                (const __attribute__((address_space(1))) void*)(Bh + off),
                (__attribute__((address_space(3))) void*)(S + 8192 + c * 8), 16, 0, 0);
            __builtin_amdgcn_global_load_lds(
                (const __attribute__((address_space(1))) void*)(Bl + off),
                (__attribute__((address_space(3))) void*)(S + 24576 + c * 8), 16, 0, 0);
        }
        asm volatile("s_waitcnt vmcnt(0)" ::: "memory");
        __syncthreads();

        #pragma unroll
        for (int kk = 0; kk < 2; kk++) {
            bf16x8 a_h[4], a_l[4], b_h[4], b_l[4];
            #pragma unroll
            for (int i = 0; i < 4; i++) {
                const int ar  = i * 16 + (lane & 15);
                const int off = ar * 64 + (((kk * 4 + (lane >> 4)) ^ (ar & 7)) * 8);
                a_h[i] = *(const bf16x8*)&S[off];
                a_l[i] = *(const bf16x8*)&S[4096 + off];
            }
            #pragma unroll
            for (int j = 0; j < 4; j++) {
                const int br  = w * 64 + j * 16 + (lane & 15);
                const int off = br * 64 + (((kk * 4 + (lane >> 4)) ^ (br & 7)) * 8);
                b_h[j] = *(const bf16x8*)&S[8192 + off];
                b_l[j] = *(const bf16x8*)&S[24576 + off];
            }
            #pragma unroll
            for (int i = 0; i < 4; i++) {
                #pragma unroll
                for (int j = 0; j < 4; j++) {
                    acc[i][j] = MF(a_h[i], b_h[j], acc[i][j]);
                    acc[i][j] = MF(a_h[i], b_l[j], acc[i][j]);
                    acc[i][j] = MF(a_l[i], b_h[j], acc[i][j]);
                }
            }
        }
        __syncthreads();
    }

    // ---- epilogue: scatter q/k/kt/v/o into LDS tiles ----
    const int colb = lane & 15;
    const int rowb = (lane >> 4) * 4;
    #pragma unroll
    for (int i = 0; i < 4; i++) {
        #pragma unroll
        for (int j = 0; j < 4; j++) {
            const int d = j * 16 + colb;
            #pragma unroll
            for (int r = 0; r < 4; r++) {
                const int t = i * 16 + rowb + r;
                float v = acc[i][j][r];
                if (w == 0) {                      // q * D^-1/2
                    v *= 0.125f;
                    unsigned short hi, lo; fsplit(v, hi, lo);
                    const int idx = t * 64 + (d ^ ((t & 7) << 3));
                    S[8192 + idx] = hi; S[12288 + idx] = lo;
                } else if (w == 1) {               // k (+ transposed copy)
                    unsigned short hi, lo; fsplit(v, hi, lo);
                    const int idx = t * 64 + (d ^ ((t & 7) << 3));
                    S[16384 + idx] = hi; S[20480 + idx] = lo;
                    const int idx2 = d * 64 + (t ^ ((d & 7) << 3));
                    S[24576 + idx2] = hi; S[28672 + idx2] = lo;
                } else if (w == 2) {               // v
                    unsigned short hi, lo; fsplit(v, hi, lo);
                    const int idx = t * 64 + (d ^ ((t & 7) << 3));
                    S[32768 + idx] = hi; S[36864 + idx] = lo;
                } else {                           // o = sigmoid(.+bo), f32
                    Ot[t * 64 + d] = 1.f / (1.f + __expf(-(v + bo[hh * 64 + d])));
                }
            }
        }
    }
    __syncthreads();

    // ---- S phase: wave w owns t-rows [16w,16w+16) ----
    f32x4 accv[4] = {}, acck[4] = {};
    const int tA = w * 16 + (lane & 15);
    #pragma unroll
    for (int kk = 0; kk < 2; kk++) {
        const int eA = (kk * 32 + (lane >> 4) * 8) ^ ((tA & 7) << 3);
        bf16x8 aQh = *(const bf16x8*)&S[8192  + tA * 64 + eA];
        bf16x8 aQl = *(const bf16x8*)&S[12288 + tA * 64 + eA];
        #pragma unroll
        for (int j = 0; j < 4; j++) {
            const int sB = j * 16 + (lane & 15);
            const int eB = (kk * 32 + (lane >> 4) * 8) ^ ((sB & 7) << 3);
            bf16x8 bKh = *(const bf16x8*)&S[16384 + sB * 64 + eB];
            bf16x8 bKl = *(const bf16x8*)&S[20480 + sB * 64 + eB];
            bf16x8 bVh = *(const bf16x8*)&S[32768 + sB * 64 + eB];
            bf16x8 bVl = *(const bf16x8*)&S[36864 + sB * 64 + eB];
            accv[j] = MF(aQh, bVh, accv[j]);
            accv[j] = MF(aQh, bVl, accv[j]);
            accv[j] = MF(aQl, bVh, accv[j]);
            acck[j] = MF(aQh, bKh, acck[j]);
            acck[j] = MF(aQh, bKl, acck[j]);
            acck[j] = MF(aQl, bKh, acck[j]);
        }
    }

    // mask + denominator (gates via shfl from registers)
    const int tbase = w * 16 + (lane >> 4) * 4;
    float cw[4], den4[4] = {0.f, 0.f, 0.f, 0.f};
    #pragma unroll
    for (int r = 0; r < 4; r++) cw[r] = __shfl(sc_r, tbase + r);
    #pragma unroll
    for (int j = 0; j < 4; j++) {
        const int s = j * 16 + (lane & 15);
        const float as = __shfl(sa_r, s);
        #pragma unroll
        for (int r = 0; r < 4; r++) {
            const int t = tbase + r;
            const float wgt = (s <= t) ? __expf(as + cw[r]) : 0.f;
            accv[j][r] *= wgt;
            den4[r] += acck[j][r] * wgt;
        }
    }
    #pragma unroll
    for (int r = 0; r < 4; r++) {
        den4[r] += __shfl_xor(den4[r], 1);
        den4[r] += __shfl_xor(den4[r], 2);
        den4[r] += __shfl_xor(den4[r], 4);
        den4[r] += __shfl_xor(den4[r], 8);
        den4[r] = fmaxf(fabsf(den4[r]), 1.f);
    }

    __syncthreads();   // all waves done reading Q/K before P overlays them

    // P split, stride-72 rows over dead Q/K-hi regions
    #pragma unroll
    for (int j = 0; j < 4; j++) {
        const int s = j * 16 + (lane & 15);
        #pragma unroll
        for (int r = 0; r < 4; r++) {
            const int t = tbase + r;
            unsigned short hi, lo; fsplit(accv[j][r], hi, lo);
            S[8192  + t * 72 + s] = hi;
            S[12800 + t * 72 + s] = lo;
        }
    }
    __syncthreads();

    // ---- PV phase: num = P @ K (B from KT tiles) ----
    f32x4 num[4] = {};
    #pragma unroll
    for (int kk = 0; kk < 2; kk++) {
        const int sA2 = kk * 32 + (lane >> 4) * 8;
        bf16x8 aPh = *(const bf16x8*)&S[8192  + tA * 72 + sA2];
        bf16x8 aPl = *(const bf16x8*)&S[12800 + tA * 72 + sA2];
        #pragma unroll
        for (int j = 0; j < 4; j++) {
            const int e2 = j * 16 + (lane & 15);
            const int tB = (kk * 32 + (lane >> 4) * 8) ^ ((e2 & 7) << 3);
            bf16x8 bTh = *(const bf16x8*)&S[24576 + e2 * 64 + tB];
            bf16x8 bTl = *(const bf16x8*)&S[28672 + e2 * 64 + tB];
            num[j] = MF(aPh, bTh, num[j]);
            num[j] = MF(aPh, bTl, num[j]);
            num[j] = MF(aPl, bTh, num[j]);
        }
    }

    // ---- output: h = o * num / den -> split bf16 ----
    #pragma unroll
    for (int j = 0; j < 4; j++) {
        const int e = j * 16 + (lane & 15);
        #pragma unroll
        for (int r = 0; r < 4; r++) {
            const int t = tbase + r;
            const float o = Ot[t * 64 + e];
            const float hval = o * num[j][r] / den4[r];
            unsigned short hi, lo; fsplit(hval, hi, lo);
            const size_t oidx = (size_t)(b * TT + t) * HIDN + hh * DH + e;
            hoh[oidx] = hi; hol[oidx] = lo;
        }
    }
}

// ---------------------------------------------------------------------------
// LayerNorm over 256: src split pair -> dst split pair. 4 rows per block.
// ---------------------------------------------------------------------------
__global__ __launch_bounds__(256) void layernorm_sp(
    const unsigned short* __restrict__ sh_, const unsigned short* __restrict__ sl_,
    unsigned short* __restrict__ dh_, unsigned short* __restrict__ dl_,
    const float* __restrict__ g, const float* __restrict__ bta)
{
    const int w    = threadIdx.x >> 6;
    const int lane = threadIdx.x & 63;
    const int row  = blockIdx.x * 4 + w;
    ushort4 a4 = *(const ushort4*)(sh_ + (size_t)row * HIDN + lane * 4);
    ushort4 l4 = *(const ushort4*)(sl_ + (size_t)row * HIDN + lane * 4);
    float x0 = b2f(a4.x) + b2f(l4.x);
    float x1 = b2f(a4.y) + b2f(l4.y);
    float x2 = b2f(a4.z) + b2f(l4.z);
    float x3 = b2f(a4.w) + b2f(l4.w);
    float s = x0 + x1 + x2 + x3;
    #pragma unroll
    for (int off = 32; off; off >>= 1) s += __shfl_xor(s, off);
    const float mu = s * (1.f / 256.f);
    const float d0 = x0 - mu, d1 = x1 - mu, d2 = x2 - mu, d3 = x3 - mu;
    float vs = d0*d0 + d1*d1 + d2*d2 + d3*d3;
    #pragma unroll
    for (int off = 32; off; off >>= 1) vs += __shfl_xor(vs, off);
    const float rstd = rsqrtf(vs * (1.f / 256.f) + EPS);
    const float4 gv = *(const float4*)(g + lane * 4);
    const float4 bv = *(const float4*)(bta + lane * 4);
    float y0 = d0 * rstd * gv.x + bv.x;
    float y1 = d1 * rstd * gv.y + bv.y;
    float y2 = d2 * rstd * gv.z + bv.z;
    float y3 = d3 * rstd * gv.w + bv.w;
    ushort4 h4, o4;
    fsplit(y0, h4.x, o4.x); fsplit(y1, h4.y, o4.y);
    fsplit(y2, h4.z, o4.z); fsplit(y3, h4.w, o4.w);
    *(ushort4*)(dh_ + (size_t)row * HIDN + lane * 4) = h4;
    *(ushort4*)(dl_ + (size_t)row * HIDN + lane * 4) = o4;
}

// ---------------------------------------------------------------------------
// Final head: z = h[:, T-1, :]; out = relu(z@W1 + b1) @ W2 + b2
// ---------------------------------------------------------------------------
__global__ __launch_bounds__(128) void head_mlp(
    const unsigned short* __restrict__ hbh, const unsigned short* __restrict__ hbl,
    const float* __restrict__ W1, const float* __restrict__ b1,
    const float* __restrict__ W2, const float* __restrict__ b2,
    float* __restrict__ out)
{
    const int b = blockIdx.x;
    const int j = threadIdx.x;
    __shared__ float z[HIDN];
    __shared__ float a[128];
    const size_t rb = ((size_t)b * TT + (TT - 1)) * HIDN;
    z[j]       = b2f(hbh[rb + j])       + b2f(hbl[rb + j]);
    z[j + 128] = b2f(hbh[rb + j + 128]) + b2f(hbl[rb + j + 128]);
    __syncthreads();
    float acc = b1[j];
    #pragma unroll 4
    for (int c = 0; c < HIDN; c++) acc += z[c] * W1[c * 128 + j];
    a[j] = fmaxf(acc, 0.f);
    __syncthreads();
    if (j < 2) {
        float s = b2[j];
        for (int c = 0; c < 128; c++) s += a[c] * W2[c * 2 + j];
        out[b * 2 + j] = s;
    }
}

// ---------------------------------------------------------------------------
extern "C" void kernel_launch(void* const* d_in, const int* in_sizes, int n_in,
                              void* d_out, int out_size, void* d_ws, size_t ws_size,
                              hipStream_t stream)
{
    const float* x   = (const float*)d_in[0];
    const float* Wp  = (const float*)d_in[1];
    const float* bp  = (const float*)d_in[2];
    const float* Wq  = (const float*)d_in[3];
    const float* Wk  = (const float*)d_in[4];
    const float* Wv  = (const float*)d_in[5];
    const float* Wo  = (const float*)d_in[6];
    const float* bo  = (const float*)d_in[7];
    const float* wi  = (const float*)d_in[8];
    const float* bi  = (const float*)d_in[9];
    const float* wf  = (const float*)d_in[10];
    const float* bf  = (const float*)d_in[11];
    const float* lng = (const float*)d_in[12];
    const float* lnb = (const float*)d_in[13];
    const float* W1  = (const float*)d_in[14];
    const float* b1  = (const float*)d_in[15];
    const float* W2  = (const float*)d_in[16];
    const float* b2  = (const float*)d_in[17];
    float* out = (float*)d_out;

    // workspace layout (~37 MB)
    unsigned short* hbh = (unsigned short*)d_ws;            // [ROWS][256]
    unsigned short* hbl = hbh + (size_t)ROWS * HIDN;
    unsigned short* h2h = hbl + (size_t)ROWS * HIDN;        // fused-layer output
    unsigned short* h2l = h2h + (size_t)ROWS * HIDN;
    float*          ir  = (float*)(h2l + (size_t)ROWS * HIDN);
    float*          fr  = ir + (size_t)ROWS * NH;
    unsigned short* WpTh = (unsigned short*)(fr + (size_t)ROWS * NH);
    unsigned short* WpTl = WpTh + (size_t)HIDN * KPAD;
    unsigned short* Wth  = WpTl + (size_t)HIDN * KPAD;
    unsigned short* Wtl  = Wth + (size_t)2 * 1024 * 256;
    // pack_x outputs alias h2h/h2l (dead until first fused layer writes them)
    unsigned short* xh = h2h;
    unsigned short* xl = h2l;

    pack_x<<<(ROWS * KPAD + 255) / 256, 256, 0, stream>>>(x, xh, xl);
    {
        int tot = HIDN * KPAD + 2 * 1024 * 256;
        pack_w<<<(tot + 255) / 256, 256, 0, stream>>>(Wp, Wq, Wk, Wv, Wo,
                                                      WpTh, WpTl, Wth, Wtl);
    }

    // input projection: hb = x @ Wp + bp (split); grid transposed (m = x)
    gemm_mfma3<<<dim3(128, 2), 256, 0, stream>>>(
        xh, xl, WpTh, WpTl, bp, hbh, hbl, ROWS, HIDN, KPAD);

    for (int l = 0; l < 2; l++) {
        ifproj<<<ROWS / 4, 256, 0, stream>>>(hbh, hbl,
                                             wi + (size_t)l * HIDN * NH,
                                             wf + (size_t)l * HIDN * NH,
                                             bi + l * NH, bf + l * NH, ir, fr);

        fused_layer<<<dim3(BATCH, NH), 256, 81920, stream>>>(
            hbh, hbl,
            Wth + (size_t)l * 1024 * 256, Wtl + (size_t)l * 1024 * 256,
            bo + (size_t)l * HIDN, ir, fr, h2h, h2l);

        layernorm_sp<<<ROWS / 4, 256, 0, stream>>>(h2h, h2l, hbh, hbl,
                                                   lng + (size_t)l * HIDN,
                                                   lnb + (size_t)l * HIDN);
    }

    head_mlp<<<BATCH, 128, 0, stream>>>(hbh, hbl, W1, b1, W2, b2, out);
}

// Round 8
// 212.314 us; speedup vs baseline: 3.0618x; 1.1805x over previous
//
#include <hip/hip_runtime.h>
#include <math.h>

typedef __attribute__((ext_vector_type(4))) float f32x4;
typedef __attribute__((ext_vector_type(8))) short bf16x8;

constexpr int BATCH = 256;
constexpr int TT    = 64;
constexpr int NH    = 4;
constexpr int DH    = 64;
constexpr int HIDN  = 256;
constexpr int INDIM = 170;
constexpr int KPAD  = 192;
constexpr int ROWS  = BATCH * TT;    // 16384
constexpr float EPS = 1e-5f;

#define MF(a, b, c) __builtin_amdgcn_mfma_f32_16x16x32_bf16((a), (b), (c), 0, 0, 0)

__device__ __forceinline__ unsigned short f2b(float f) {
    union { float f; unsigned int u; } v; v.f = f;
    return (unsigned short)((v.u + 0x7FFFu + ((v.u >> 16) & 1u)) >> 16);
}
__device__ __forceinline__ float b2f(unsigned short b) {
    union { unsigned int u; float f; } v; v.u = ((unsigned int)b) << 16;
    return v.f;
}
__device__ __forceinline__ void fsplit(float x, unsigned short& hi, unsigned short& lo) {
    hi = f2b(x);
    lo = f2b(x - b2f(hi));
}

// ---------------------------------------------------------------------------
// pack_x: x [ROWS][170] f32 -> xh/xl [ROWS][192] split bf16 (zero-padded)
// ---------------------------------------------------------------------------
__global__ __launch_bounds__(256) void pack_x(
    const float* __restrict__ x,
    unsigned short* __restrict__ xh, unsigned short* __restrict__ xl)
{
    int idx = blockIdx.x * 256 + threadIdx.x;
    if (idx >= ROWS * KPAD) return;
    int r = idx / KPAD, c = idx % KPAD;
    float v = (c < INDIM) ? x[(size_t)r * INDIM + c] : 0.f;
    unsigned short hi, lo; fsplit(v, hi, lo);
    xh[idx] = hi; xl[idx] = lo;
}

// ---------------------------------------------------------------------------
// pack_w: weights -> split-bf16 [N][K] (B-transposed) layout.
// ---------------------------------------------------------------------------
__global__ __launch_bounds__(256) void pack_w(
    const float* __restrict__ Wp, const float* __restrict__ Wq,
    const float* __restrict__ Wk, const float* __restrict__ Wv,
    const float* __restrict__ Wo,
    unsigned short* __restrict__ WpTh, unsigned short* __restrict__ WpTl,
    unsigned short* __restrict__ Wth,  unsigned short* __restrict__ Wtl)
{
    int idx = blockIdx.x * 256 + threadIdx.x;
    if (idx < HIDN * KPAD) {
        int n = idx / KPAD, kc = idx % KPAD;
        float v = (kc < INDIM) ? Wp[(size_t)kc * HIDN + n] : 0.f;
        unsigned short hi, lo; fsplit(v, hi, lo);
        WpTh[idx] = hi; WpTl[idx] = lo;
        return;
    }
    idx -= HIDN * KPAD;
    if (idx < 2 * 1024 * 256) {
        int l = idx / (1024 * 256);
        int r = idx % (1024 * 256);
        int n = r / 256, k = r % 256;
        int seg = n >> 8, ns = n & 255;
        const float* W = (seg == 0) ? Wq : (seg == 1) ? Wk : (seg == 2) ? Wv : Wo;
        float v = W[(size_t)l * 65536 + (size_t)k * 256 + ns];
        unsigned short hi, lo; fsplit(v, hi, lo);
        Wth[(size_t)l * 1024 * 256 + r] = hi;
        Wtl[(size_t)l * 1024 * 256 + r] = lo;
    }
}

// ---------------------------------------------------------------------------
// split-bf16 MFMA GEMM (3-product), input projection only.
// 128x128 tile, 4 waves; m on blockIdx.x so same-A blocks share an XCD.
// ---------------------------------------------------------------------------
__global__ __launch_bounds__(256) void gemm_mfma3(
    const unsigned short* __restrict__ Ah, const unsigned short* __restrict__ Al,
    const unsigned short* __restrict__ Bh, const unsigned short* __restrict__ Bl,
    const float* __restrict__ bias,
    unsigned short* __restrict__ c0, unsigned short* __restrict__ c1,
    int M, int N, int K)
{
    __shared__ unsigned short AsH[128 * 64];
    __shared__ unsigned short AsL[128 * 64];
    __shared__ unsigned short BsH[128 * 64];
    __shared__ unsigned short BsL[128 * 64];
    const int tid  = threadIdx.x;
    const int lane = tid & 63;
    const int wave = tid >> 6;
    const int wr = wave >> 1, wc = wave & 1;
    const int m0 = blockIdx.x * 128, n0 = blockIdx.y * 128;

    f32x4 acc[4][4] = {};

    for (int k0 = 0; k0 < K; k0 += 64) {
        #pragma unroll
        for (int j = 0; j < 4; j++) {
            int c   = j * 256 + tid;
            int row = c >> 3;
            int kcs = ((c & 7) ^ (row & 7)) * 8;
            size_t aoff = (size_t)(m0 + row) * K + k0 + kcs;
            size_t boff = (size_t)(n0 + row) * K + k0 + kcs;
            __builtin_amdgcn_global_load_lds(
                (const __attribute__((address_space(1))) void*)(Ah + aoff),
                (__attribute__((address_space(3))) void*)(AsH + c * 8), 16, 0, 0);
            __builtin_amdgcn_global_load_lds(
                (const __attribute__((address_space(1))) void*)(Al + aoff),
                (__attribute__((address_space(3))) void*)(AsL + c * 8), 16, 0, 0);
            __builtin_amdgcn_global_load_lds(
                (const __attribute__((address_space(1))) void*)(Bh + boff),
                (__attribute__((address_space(3))) void*)(BsH + c * 8), 16, 0, 0);
            __builtin_amdgcn_global_load_lds(
                (const __attribute__((address_space(1))) void*)(Bl + boff),
                (__attribute__((address_space(3))) void*)(BsL + c * 8), 16, 0, 0);
        }
        asm volatile("s_waitcnt vmcnt(0)" ::: "memory");
        __syncthreads();

        #pragma unroll
        for (int kk = 0; kk < 2; kk++) {
            bf16x8 ah[4], al[4], bh[4], bl[4];
            #pragma unroll
            for (int i = 0; i < 4; i++) {
                const int ar  = wr * 64 + i * 16 + (lane & 15);
                const int off = ar * 64 + (((kk * 4 + (lane >> 4)) ^ (ar & 7)) * 8);
                ah[i] = *(const bf16x8*)&AsH[off];
                al[i] = *(const bf16x8*)&AsL[off];
            }
            #pragma unroll
            for (int j = 0; j < 4; j++) {
                const int br  = wc * 64 + j * 16 + (lane & 15);
                const int off = br * 64 + (((kk * 4 + (lane >> 4)) ^ (br & 7)) * 8);
                bh[j] = *(const bf16x8*)&BsH[off];
                bl[j] = *(const bf16x8*)&BsL[off];
            }
            #pragma unroll
            for (int i = 0; i < 4; i++) {
                #pragma unroll
                for (int j = 0; j < 4; j++) {
                    acc[i][j] = MF(ah[i], bh[j], acc[i][j]);
                    acc[i][j] = MF(ah[i], bl[j], acc[i][j]);
                    acc[i][j] = MF(al[i], bh[j], acc[i][j]);
                }
            }
        }
        __syncthreads();
    }

    #pragma unroll
    for (int i = 0; i < 4; i++) {
        #pragma unroll
        for (int j = 0; j < 4; j++) {
            const int col = n0 + wc * 64 + j * 16 + (lane & 15);
            const float bv = bias[col];
            #pragma unroll
            for (int r = 0; r < 4; r++) {
                const int row = m0 + wr * 64 + i * 16 + (lane >> 4) * 4 + r;
                float v = acc[i][j][r] + bv;
                unsigned short hi, lo; fsplit(v, hi, lo);
                c0[(size_t)row * N + col] = hi;
                c1[(size_t)row * N + col] = lo;
            }
        }
    }
}

// ---------------------------------------------------------------------------
// i/f gate projection. 256 threads = 4 waves, one row per wave.
// ---------------------------------------------------------------------------
__global__ __launch_bounds__(256) void ifproj(
    const unsigned short* __restrict__ hbh, const unsigned short* __restrict__ hbl,
    const float* __restrict__ wi, const float* __restrict__ wf,
    const float* __restrict__ bi, const float* __restrict__ bf,
    float* __restrict__ iout, float* __restrict__ fout)
{
    __shared__ float hr[4][HIDN];
    const int w    = threadIdx.x >> 6;
    const int lane = threadIdx.x & 63;
    const int row  = blockIdx.x * 4 + w;
    ushort4 a4 = *(const ushort4*)(hbh + (size_t)row * HIDN + lane * 4);
    ushort4 l4 = *(const ushort4*)(hbl + (size_t)row * HIDN + lane * 4);
    hr[w][lane * 4 + 0] = b2f(a4.x) + b2f(l4.x);
    hr[w][lane * 4 + 1] = b2f(a4.y) + b2f(l4.y);
    hr[w][lane * 4 + 2] = b2f(a4.z) + b2f(l4.z);
    hr[w][lane * 4 + 3] = b2f(a4.w) + b2f(l4.w);
    __syncthreads();

    const int out  = lane >> 3;
    const int part = lane & 7;
    const float* W = (out < 4) ? wi : wf;
    const int oc   = out & 3;
    float s = 0.f;
    #pragma unroll
    for (int c = 0; c < 32; c++) {
        int idx = part * 32 + c;
        s += hr[w][idx] * W[idx * NH + oc];
    }
    s += __shfl_xor(s, 1);
    s += __shfl_xor(s, 2);
    s += __shfl_xor(s, 4);
    if (part == 0) {
        float b = (out < 4) ? bi[oc] : bf[oc];
        float r = s + b;
        if (out < 4) iout[(size_t)row * NH + oc] = r;
        else         fout[(size_t)row * NH + oc] = r;
    }
}

// ---------------------------------------------------------------------------
// FUSED layer kernel v2: 8 waves (512 thr), one block per (b,h), 80 KiB LDS
// (2 blocks/CU = 16 waves/CU). Flat grid with XCD swizzle so the 4 heads of
// one batch (sharing the A-panel) land on the same XCD.
//   GEMM: M=64, N=256, K=256, BK=64. Wave grid 2(m)x4(n), acc[2][4].
//   Attn: S split (4 t-groups x 2 s-halves), den halves combined via LDS;
//         PV split (4 t-groups x 2 e-halves).
// LDS (short idx): AsH [0,4096) AsL [4096,8192) -> f32 Ot after GEMM
//   BsH [8192,24576) BsL [24576,40960)
//   attn: Qh 8192 Ql 12288 Kh 16384 Kl 20480 Th 24576 Tl 28672 Vh 32768 Vl 36864
//   P overlay: Ph@8192 Pl@12800 (stride 72); denF f32x128 @ short 18432 (dead Kh)
// ---------------------------------------------------------------------------
__global__ __launch_bounds__(512, 4) void fused_layer(
    const unsigned short* __restrict__ Ah, const unsigned short* __restrict__ Al,
    const unsigned short* __restrict__ Bh, const unsigned short* __restrict__ Bl,
    const float* __restrict__ bo,
    const float* __restrict__ irg, const float* __restrict__ frg,
    unsigned short* __restrict__ hoh, unsigned short* __restrict__ hol)
{
    extern __shared__ char smem[];
    unsigned short* const S = (unsigned short*)smem;
    float* const Ot   = (float*)smem;              // overlays As region after GEMM
    float* const denF = (float*)(S + 18432);       // 128 f32 in dead Kh region

    const int n0  = blockIdx.x;
    const int mm  = n0 >> 3;
    const int hh  = mm & 3;
    const int b   = (n0 & 7) + 8 * (mm >> 2);      // 4 heads of b -> same XCD
    const int tid = threadIdx.x, lane = tid & 63, w = tid >> 6;

    // gate prefix scans, in registers (redundant per wave)
    float iv = irg[(size_t)(b * TT + lane) * NH + hh];
    float fv = frg[(size_t)(b * TT + lane) * NH + hh];
    float F = fv;
    #pragma unroll
    for (int d2 = 1; d2 < 64; d2 <<= 1) { float o2 = __shfl_up(F, d2); if (lane >= d2) F += o2; }
    const float sa_r = iv - F;                     // a_t = i_t - F_t
    float pm = sa_r;
    #pragma unroll
    for (int d2 = 1; d2 < 64; d2 <<= 1) { float o2 = __shfl_up(pm, d2); if (lane >= d2) pm = fmaxf(pm, o2); }
    const float sc_r = -fmaxf(0.f, pm);            // F_t - m_t

    // ---- GEMM phase ----
    const int wm = w >> 2, wn = w & 3;
    f32x4 acc[2][4] = {};
    for (int k0 = 0; k0 < 256; k0 += 64) {
        {                                          // A tile: 1 chunk/thread/array
            int c = tid;
            int row = c >> 3;
            int kcs = ((c & 7) ^ (row & 7)) * 8;
            size_t off = (size_t)(b * TT + row) * 256 + k0 + kcs;
            __builtin_amdgcn_global_load_lds(
                (const __attribute__((address_space(1))) void*)(Ah + off),
                (__attribute__((address_space(3))) void*)(S + c * 8), 16, 0, 0);
            __builtin_amdgcn_global_load_lds(
                (const __attribute__((address_space(1))) void*)(Al + off),
                (__attribute__((address_space(3))) void*)(S + 4096 + c * 8), 16, 0, 0);
        }
        #pragma unroll
        for (int j2 = 0; j2 < 4; j2++) {           // B tile: 256x64 h+l
            int c = j2 * 512 + tid;                // 0..2047
            int nr = c >> 3;
            int kcs = ((c & 7) ^ (nr & 7)) * 8;
            int grow = (nr >> 6) * 256 + hh * 64 + (nr & 63);
            size_t off = (size_t)grow * 256 + k0 + kcs;
            __builtin_amdgcn_global_load_lds(
                (const __attribute__((address_space(1))) void*)(Bh + off),
                (__attribute__((address_space(3))) void*)(S + 8192 + c * 8), 16, 0, 0);
            __builtin_amdgcn_global_load_lds(
                (const __attribute__((address_space(1))) void*)(Bl + off),
                (__attribute__((address_space(3))) void*)(S + 24576 + c * 8), 16, 0, 0);
        }
        asm volatile("s_waitcnt vmcnt(0)" ::: "memory");
        __syncthreads();

        #pragma unroll
        for (int kk = 0; kk < 2; kk++) {
            bf16x8 a_h[2], a_l[2], b_h[4], b_l[4];
            #pragma unroll
            for (int i = 0; i < 2; i++) {
                const int ar  = wm * 32 + i * 16 + (lane & 15);
                const int off = ar * 64 + (((kk * 4 + (lane >> 4)) ^ (ar & 7)) * 8);
                a_h[i] = *(const bf16x8*)&S[off];
                a_l[i] = *(const bf16x8*)&S[4096 + off];
            }
            #pragma unroll
            for (int j = 0; j < 4; j++) {
                const int br  = wn * 64 + j * 16 + (lane & 15);
                const int off = br * 64 + (((kk * 4 + (lane >> 4)) ^ (br & 7)) * 8);
                b_h[j] = *(const bf16x8*)&S[8192 + off];
                b_l[j] = *(const bf16x8*)&S[24576 + off];
            }
            #pragma unroll
            for (int i = 0; i < 2; i++) {
                #pragma unroll
                for (int j = 0; j < 4; j++) {
                    acc[i][j] = MF(a_h[i], b_h[j], acc[i][j]);
                    acc[i][j] = MF(a_h[i], b_l[j], acc[i][j]);
                    acc[i][j] = MF(a_l[i], b_h[j], acc[i][j]);
                }
            }
        }
        __syncthreads();
    }

    // ---- epilogue: scatter q/k/kt/v/o into LDS tiles (wave wn owns seg wn) --
    const int colb = lane & 15;
    const int rowb = (lane >> 4) * 4;
    #pragma unroll
    for (int i = 0; i < 2; i++) {
        #pragma unroll
        for (int j = 0; j < 4; j++) {
            const int d = j * 16 + colb;
            #pragma unroll
            for (int r = 0; r < 4; r++) {
                const int t = wm * 32 + i * 16 + rowb + r;
                float v = acc[i][j][r];
                if (wn == 0) {                     // q * D^-1/2
                    v *= 0.125f;
                    unsigned short hi, lo; fsplit(v, hi, lo);
                    const int idx = t * 64 + (d ^ ((t & 7) << 3));
                    S[8192 + idx] = hi; S[12288 + idx] = lo;
                } else if (wn == 1) {              // k (+ transposed copy)
                    unsigned short hi, lo; fsplit(v, hi, lo);
                    const int idx = t * 64 + (d ^ ((t & 7) << 3));
                    S[16384 + idx] = hi; S[20480 + idx] = lo;
                    const int idx2 = d * 64 + (t ^ ((d & 7) << 3));
                    S[24576 + idx2] = hi; S[28672 + idx2] = lo;
                } else if (wn == 2) {              // v
                    unsigned short hi, lo; fsplit(v, hi, lo);
                    const int idx = t * 64 + (d ^ ((t & 7) << 3));
                    S[32768 + idx] = hi; S[36864 + idx] = lo;
                } else {                           // o = sigmoid(.+bo), f32
                    Ot[t * 64 + d] = 1.f / (1.f + __expf(-(v + bo[hh * 64 + d])));
                }
            }
        }
    }
    __syncthreads();

    // ---- S phase: wave (tg = w&3) t-rows [16tg,16tg+16), (sh = w>>2) s-half -
    const int tg = w & 3, sh = w >> 2;
    f32x4 sv[2] = {}, sk[2] = {};
    const int tA = tg * 16 + (lane & 15);
    #pragma unroll
    for (int kk = 0; kk < 2; kk++) {
        const int eA = (kk * 32 + (lane >> 4) * 8) ^ ((tA & 7) << 3);
        bf16x8 aQh = *(const bf16x8*)&S[8192  + tA * 64 + eA];
        bf16x8 aQl = *(const bf16x8*)&S[12288 + tA * 64 + eA];
        #pragma unroll
        for (int j = 0; j < 2; j++) {
            const int sB = sh * 32 + j * 16 + (lane & 15);
            const int eB = (kk * 32 + (lane >> 4) * 8) ^ ((sB & 7) << 3);
            bf16x8 bKh = *(const bf16x8*)&S[16384 + sB * 64 + eB];
            bf16x8 bKl = *(const bf16x8*)&S[20480 + sB * 64 + eB];
            bf16x8 bVh = *(const bf16x8*)&S[32768 + sB * 64 + eB];
            bf16x8 bVl = *(const bf16x8*)&S[36864 + sB * 64 + eB];
            sv[j] = MF(aQh, bVh, sv[j]);
            sv[j] = MF(aQh, bVl, sv[j]);
            sv[j] = MF(aQl, bVh, sv[j]);
            sk[j] = MF(aQh, bKh, sk[j]);
            sk[j] = MF(aQh, bKl, sk[j]);
            sk[j] = MF(aQl, bKh, sk[j]);
        }
    }

    // mask + half-denominator
    const int tbase = tg * 16 + (lane >> 4) * 4;
    float cw[4], dh4[4] = {0.f, 0.f, 0.f, 0.f};
    #pragma unroll
    for (int r = 0; r < 4; r++) cw[r] = __shfl(sc_r, tbase + r);
    #pragma unroll
    for (int j = 0; j < 2; j++) {
        const int s = sh * 32 + j * 16 + (lane & 15);
        const float as = __shfl(sa_r, s);
        #pragma unroll
        for (int r = 0; r < 4; r++) {
            const int t = tbase + r;
            const float wgt = (s <= t) ? __expf(as + cw[r]) : 0.f;
            sv[j][r] *= wgt;
            dh4[r] += sk[j][r] * wgt;
        }
    }
    #pragma unroll
    for (int r = 0; r < 4; r++) {
        dh4[r] += __shfl_xor(dh4[r], 1);
        dh4[r] += __shfl_xor(dh4[r], 2);
        dh4[r] += __shfl_xor(dh4[r], 4);
        dh4[r] += __shfl_xor(dh4[r], 8);
    }

    __syncthreads();   // all waves done reading Q/K/V before overlays

    // write P split (stride-72 rows over dead Q region) + den halves
    #pragma unroll
    for (int j = 0; j < 2; j++) {
        const int s = sh * 32 + j * 16 + (lane & 15);
        #pragma unroll
        for (int r = 0; r < 4; r++) {
            const int t = tbase + r;
            unsigned short hi, lo; fsplit(sv[j][r], hi, lo);
            S[8192  + t * 72 + s] = hi;
            S[12800 + t * 72 + s] = lo;
        }
    }
    if ((lane & 15) == 0) {
        #pragma unroll
        for (int r = 0; r < 4; r++) denF[sh * 64 + tbase + r] = dh4[r];
    }
    __syncthreads();

    // ---- PV phase: num = P @ K (B from KT tiles); wave (tg, eh=sh) ----
    f32x4 num[2] = {};
    #pragma unroll
    for (int kk = 0; kk < 2; kk++) {
        const int sA2 = kk * 32 + (lane >> 4) * 8;
        bf16x8 aPh = *(const bf16x8*)&S[8192  + tA * 72 + sA2];
        bf16x8 aPl = *(const bf16x8*)&S[12800 + tA * 72 + sA2];
        #pragma unroll
        for (int j = 0; j < 2; j++) {
            const int e2 = sh * 32 + j * 16 + (lane & 15);
            const int tB = (kk * 32 + (lane >> 4) * 8) ^ ((e2 & 7) << 3);
            bf16x8 bTh = *(const bf16x8*)&S[24576 + e2 * 64 + tB];
            bf16x8 bTl = *(const bf16x8*)&S[28672 + e2 * 64 + tB];
            num[j] = MF(aPh, bTh, num[j]);
            num[j] = MF(aPh, bTl, num[j]);
            num[j] = MF(aPl, bTh, num[j]);
        }
    }

    // ---- output: h = o * num / den -> split bf16 ----
    #pragma unroll
    for (int j = 0; j < 2; j++) {
        const int e = sh * 32 + j * 16 + (lane & 15);
        #pragma unroll
        for (int r = 0; r < 4; r++) {
            const int t = tbase + r;
            const float den = fmaxf(fabsf(denF[t] + denF[64 + t]), 1.f);
            const float o = Ot[t * 64 + e];
            const float hval = o * num[j][r] / den;
            unsigned short hi, lo; fsplit(hval, hi, lo);
            const size_t oidx = (size_t)(b * TT + t) * HIDN + hh * DH + e;
            hoh[oidx] = hi; hol[oidx] = lo;
        }
    }
}

// ---------------------------------------------------------------------------
// LayerNorm over 256: src split pair -> dst split pair. 4 rows per block.
// ---------------------------------------------------------------------------
__global__ __launch_bounds__(256) void layernorm_sp(
    const unsigned short* __restrict__ sh_, const unsigned short* __restrict__ sl_,
    unsigned short* __restrict__ dh_, unsigned short* __restrict__ dl_,
    const float* __restrict__ g, const float* __restrict__ bta)
{
    const int w    = threadIdx.x >> 6;
    const int lane = threadIdx.x & 63;
    const int row  = blockIdx.x * 4 + w;
    ushort4 a4 = *(const ushort4*)(sh_ + (size_t)row * HIDN + lane * 4);
    ushort4 l4 = *(const ushort4*)(sl_ + (size_t)row * HIDN + lane * 4);
    float x0 = b2f(a4.x) + b2f(l4.x);
    float x1 = b2f(a4.y) + b2f(l4.y);
    float x2 = b2f(a4.z) + b2f(l4.z);
    float x3 = b2f(a4.w) + b2f(l4.w);
    float s = x0 + x1 + x2 + x3;
    #pragma unroll
    for (int off = 32; off; off >>= 1) s += __shfl_xor(s, off);
    const float mu = s * (1.f / 256.f);
    const float d0 = x0 - mu, d1 = x1 - mu, d2 = x2 - mu, d3 = x3 - mu;
    float vs = d0*d0 + d1*d1 + d2*d2 + d3*d3;
    #pragma unroll
    for (int off = 32; off; off >>= 1) vs += __shfl_xor(vs, off);
    const float rstd = rsqrtf(vs * (1.f / 256.f) + EPS);
    const float4 gv = *(const float4*)(g + lane * 4);
    const float4 bv = *(const float4*)(bta + lane * 4);
    float y0 = d0 * rstd * gv.x + bv.x;
    float y1 = d1 * rstd * gv.y + bv.y;
    float y2 = d2 * rstd * gv.z + bv.z;
    float y3 = d3 * rstd * gv.w + bv.w;
    ushort4 h4, o4;
    fsplit(y0, h4.x, o4.x); fsplit(y1, h4.y, o4.y);
    fsplit(y2, h4.z, o4.z); fsplit(y3, h4.w, o4.w);
    *(ushort4*)(dh_ + (size_t)row * HIDN + lane * 4) = h4;
    *(ushort4*)(dl_ + (size_t)row * HIDN + lane * 4) = o4;
}

// ---------------------------------------------------------------------------
// Final head: z = h[:, T-1, :]; out = relu(z@W1 + b1) @ W2 + b2
// ---------------------------------------------------------------------------
__global__ __launch_bounds__(128) void head_mlp(
    const unsigned short* __restrict__ hbh, const unsigned short* __restrict__ hbl,
    const float* __restrict__ W1, const float* __restrict__ b1,
    const float* __restrict__ W2, const float* __restrict__ b2,
    float* __restrict__ out)
{
    const int b = blockIdx.x;
    const int j = threadIdx.x;
    __shared__ float z[HIDN];
    __shared__ float a[128];
    const size_t rb = ((size_t)b * TT + (TT - 1)) * HIDN;
    z[j]       = b2f(hbh[rb + j])       + b2f(hbl[rb + j]);
    z[j + 128] = b2f(hbh[rb + j + 128]) + b2f(hbl[rb + j + 128]);
    __syncthreads();
    float acc = b1[j];
    #pragma unroll 4
    for (int c = 0; c < HIDN; c++) acc += z[c] * W1[c * 128 + j];
    a[j] = fmaxf(acc, 0.f);
    __syncthreads();
    if (j < 2) {
        float s = b2[j];
        for (int c = 0; c < 128; c++) s += a[c] * W2[c * 2 + j];
        out[b * 2 + j] = s;
    }
}

// ---------------------------------------------------------------------------
extern "C" void kernel_launch(void* const* d_in, const int* in_sizes, int n_in,
                              void* d_out, int out_size, void* d_ws, size_t ws_size,
                              hipStream_t stream)
{
    const float* x   = (const float*)d_in[0];
    const float* Wp  = (const float*)d_in[1];
    const float* bp  = (const float*)d_in[2];
    const float* Wq  = (const float*)d_in[3];
    const float* Wk  = (const float*)d_in[4];
    const float* Wv  = (const float*)d_in[5];
    const float* Wo  = (const float*)d_in[6];
    const float* bo  = (const float*)d_in[7];
    const float* wi  = (const float*)d_in[8];
    const float* bi  = (const float*)d_in[9];
    const float* wf  = (const float*)d_in[10];
    const float* bf  = (const float*)d_in[11];
    const float* lng = (const float*)d_in[12];
    const float* lnb = (const float*)d_in[13];
    const float* W1  = (const float*)d_in[14];
    const float* b1  = (const float*)d_in[15];
    const float* W2  = (const float*)d_in[16];
    const float* b2  = (const float*)d_in[17];
    float* out = (float*)d_out;

    // workspace layout (~37 MB)
    unsigned short* hbh = (unsigned short*)d_ws;            // [ROWS][256]
    unsigned short* hbl = hbh + (size_t)ROWS * HIDN;
    unsigned short* h2h = hbl + (size_t)ROWS * HIDN;        // fused-layer output
    unsigned short* h2l = h2h + (size_t)ROWS * HIDN;
    float*          ir  = (float*)(h2l + (size_t)ROWS * HIDN);
    float*          fr  = ir + (size_t)ROWS * NH;
    unsigned short* WpTh = (unsigned short*)(fr + (size_t)ROWS * NH);
    unsigned short* WpTl = WpTh + (size_t)HIDN * KPAD;
    unsigned short* Wth  = WpTl + (size_t)HIDN * KPAD;
    unsigned short* Wtl  = Wth + (size_t)2 * 1024 * 256;
    // pack_x outputs alias h2h/h2l (dead until first fused layer writes them)
    unsigned short* xh = h2h;
    unsigned short* xl = h2l;

    pack_x<<<(ROWS * KPAD + 255) / 256, 256, 0, stream>>>(x, xh, xl);
    {
        int tot = HIDN * KPAD + 2 * 1024 * 256;
        pack_w<<<(tot + 255) / 256, 256, 0, stream>>>(Wp, Wq, Wk, Wv, Wo,
                                                      WpTh, WpTl, Wth, Wtl);
    }

    // input projection: hb = x @ Wp + bp (split); grid transposed (m = x)
    gemm_mfma3<<<dim3(128, 2), 256, 0, stream>>>(
        xh, xl, WpTh, WpTl, bp, hbh, hbl, ROWS, HIDN, KPAD);

    for (int l = 0; l < 2; l++) {
        ifproj<<<ROWS / 4, 256, 0, stream>>>(hbh, hbl,
                                             wi + (size_t)l * HIDN * NH,
                                             wf + (size_t)l * HIDN * NH,
                                             bi + l * NH, bf + l * NH, ir, fr);

        fused_layer<<<BATCH * NH, 512, 81920, stream>>>(
            hbh, hbl,
            Wth + (size_t)l * 1024 * 256, Wtl + (size_t)l * 1024 * 256,
            bo + (size_t)l * HIDN, ir, fr, h2h, h2l);

        layernorm_sp<<<ROWS / 4, 256, 0, stream>>>(h2h, h2l, hbh, hbl,
                                                   lng + (size_t)l * HIDN,
                                                   lnb + (size_t)l * HIDN);
    }

    head_mlp<<<BATCH, 128, 0, stream>>>(hbh, hbl, W1, b1, W2, b2, out);
}

// Round 9
// 171.874 us; speedup vs baseline: 3.7822x; 1.2353x over previous
//
#include <hip/hip_runtime.h>
#include <math.h>

typedef __attribute__((ext_vector_type(4))) float f32x4;
typedef __attribute__((ext_vector_type(8))) short bf16x8;

constexpr int BATCH = 256;
constexpr int TT    = 64;
constexpr int NH    = 4;
constexpr int DH    = 64;
constexpr int HIDN  = 256;
constexpr int INDIM = 170;
constexpr int KPAD  = 192;
constexpr int ROWS  = BATCH * TT;    // 16384
constexpr float EPS = 1e-5f;

#define MF(a, b, c) __builtin_amdgcn_mfma_f32_16x16x32_bf16((a), (b), (c), 0, 0, 0)

__device__ __forceinline__ unsigned short f2b(float f) {
    union { float f; unsigned int u; } v; v.f = f;
    return (unsigned short)((v.u + 0x7FFFu + ((v.u >> 16) & 1u)) >> 16);
}
__device__ __forceinline__ float b2f(unsigned short b) {
    union { unsigned int u; float f; } v; v.u = ((unsigned int)b) << 16;
    return v.f;
}
__device__ __forceinline__ void fsplit(float x, unsigned short& hi, unsigned short& lo) {
    hi = f2b(x);
    lo = f2b(x - b2f(hi));
}

// ---------------------------------------------------------------------------
// pack_x: x [ROWS][170] f32 -> xh/xl [ROWS][192] split bf16 (zero-padded)
// ---------------------------------------------------------------------------
__global__ __launch_bounds__(256) void pack_x(
    const float* __restrict__ x,
    unsigned short* __restrict__ xh, unsigned short* __restrict__ xl)
{
    int idx = blockIdx.x * 256 + threadIdx.x;
    if (idx >= ROWS * KPAD) return;
    int r = idx / KPAD, c = idx % KPAD;
    float v = (c < INDIM) ? x[(size_t)r * INDIM + c] : 0.f;
    unsigned short hi, lo; fsplit(v, hi, lo);
    xh[idx] = hi; xl[idx] = lo;
}

// ---------------------------------------------------------------------------
// pack_w2: LDS-transpose weight pack (coalesced reads and writes).
//   tiles 0..127 : Wt  [2][1024 n][256 k]  from Wq/Wk/Wv/Wo [2][256 k][256 n]
//   tiles 128..139: WpT [256 n][192 k]     from Wp [170 k][256 n] (k zero-pad)
// ---------------------------------------------------------------------------
__global__ __launch_bounds__(256) void pack_w2(
    const float* __restrict__ Wp, const float* __restrict__ Wq,
    const float* __restrict__ Wk, const float* __restrict__ Wv,
    const float* __restrict__ Wo,
    unsigned short* __restrict__ WpTh, unsigned short* __restrict__ WpTl,
    unsigned short* __restrict__ Wth,  unsigned short* __restrict__ Wtl)
{
    __shared__ float T[64][65];
    const int t = blockIdx.x, tid = threadIdx.x;

    if (t < 128) {
        const int l = t >> 6, rem = t & 63;
        const int kt = rem >> 4, nt = rem & 15;      // k-tile 0..3, n-tile 0..15
        const int n0 = nt * 64;
        const int seg = n0 >> 8, ns0 = n0 & 255;
        const float* W = (seg == 0) ? Wq : (seg == 1) ? Wk : (seg == 2) ? Wv : Wo;
        #pragma unroll
        for (int p = 0; p < 16; p++) {
            const int idx = p * 256 + tid;
            const int r = idx >> 6, c = idx & 63;    // k-local, n-local
            T[r][c] = W[(size_t)l * 65536 + (size_t)(kt * 64 + r) * 256 + ns0 + c];
        }
        __syncthreads();
        #pragma unroll
        for (int p = 0; p < 16; p++) {
            const int idx = p * 256 + tid;
            const int nl = idx >> 6, kl = idx & 63;
            unsigned short hi, lo; fsplit(T[kl][nl], hi, lo);
            const size_t d = (size_t)l * 1024 * 256 + (size_t)(n0 + nl) * 256 + kt * 64 + kl;
            Wth[d] = hi; Wtl[d] = lo;
        }
    } else {
        const int t2 = t - 128;
        const int kt = t2 % 3, nt = t2 / 3;          // k-tile 0..2, n-tile 0..3
        #pragma unroll
        for (int p = 0; p < 16; p++) {
            const int idx = p * 256 + tid;
            const int r = idx >> 6, c = idx & 63;
            const int k = kt * 64 + r;
            T[r][c] = (k < INDIM) ? Wp[(size_t)k * HIDN + nt * 64 + c] : 0.f;
        }
        __syncthreads();
        #pragma unroll
        for (int p = 0; p < 16; p++) {
            const int idx = p * 256 + tid;
            const int nl = idx >> 6, kl = idx & 63;
            unsigned short hi, lo; fsplit(T[kl][nl], hi, lo);
            const size_t d = (size_t)(nt * 64 + nl) * KPAD + kt * 64 + kl;
            WpTh[d] = hi; WpTl[d] = lo;
        }
    }
}

// ---------------------------------------------------------------------------
// split-bf16 MFMA GEMM (3-product), input projection only.
// 128x128 tile, 4 waves; m on blockIdx.x so same-A blocks share an XCD.
// ---------------------------------------------------------------------------
__global__ __launch_bounds__(256) void gemm_mfma3(
    const unsigned short* __restrict__ Ah, const unsigned short* __restrict__ Al,
    const unsigned short* __restrict__ Bh, const unsigned short* __restrict__ Bl,
    const float* __restrict__ bias,
    unsigned short* __restrict__ c0, unsigned short* __restrict__ c1,
    int M, int N, int K)
{
    __shared__ unsigned short AsH[128 * 64];
    __shared__ unsigned short AsL[128 * 64];
    __shared__ unsigned short BsH[128 * 64];
    __shared__ unsigned short BsL[128 * 64];
    const int tid  = threadIdx.x;
    const int lane = tid & 63;
    const int wave = tid >> 6;
    const int wr = wave >> 1, wc = wave & 1;
    const int m0 = blockIdx.x * 128, n0 = blockIdx.y * 128;

    f32x4 acc[4][4] = {};

    for (int k0 = 0; k0 < K; k0 += 64) {
        #pragma unroll
        for (int j = 0; j < 4; j++) {
            int c   = j * 256 + tid;
            int row = c >> 3;
            int kcs = ((c & 7) ^ (row & 7)) * 8;
            size_t aoff = (size_t)(m0 + row) * K + k0 + kcs;
            size_t boff = (size_t)(n0 + row) * K + k0 + kcs;
            __builtin_amdgcn_global_load_lds(
                (const __attribute__((address_space(1))) void*)(Ah + aoff),
                (__attribute__((address_space(3))) void*)(AsH + c * 8), 16, 0, 0);
            __builtin_amdgcn_global_load_lds(
                (const __attribute__((address_space(1))) void*)(Al + aoff),
                (__attribute__((address_space(3))) void*)(AsL + c * 8), 16, 0, 0);
            __builtin_amdgcn_global_load_lds(
                (const __attribute__((address_space(1))) void*)(Bh + boff),
                (__attribute__((address_space(3))) void*)(BsH + c * 8), 16, 0, 0);
            __builtin_amdgcn_global_load_lds(
                (const __attribute__((address_space(1))) void*)(Bl + boff),
                (__attribute__((address_space(3))) void*)(BsL + c * 8), 16, 0, 0);
        }
        asm volatile("s_waitcnt vmcnt(0)" ::: "memory");
        __syncthreads();

        #pragma unroll
        for (int kk = 0; kk < 2; kk++) {
            bf16x8 ah[4], al[4], bh[4], bl[4];
            #pragma unroll
            for (int i = 0; i < 4; i++) {
                const int ar  = wr * 64 + i * 16 + (lane & 15);
                const int off = ar * 64 + (((kk * 4 + (lane >> 4)) ^ (ar & 7)) * 8);
                ah[i] = *(const bf16x8*)&AsH[off];
                al[i] = *(const bf16x8*)&AsL[off];
            }
            #pragma unroll
            for (int j = 0; j < 4; j++) {
                const int br  = wc * 64 + j * 16 + (lane & 15);
                const int off = br * 64 + (((kk * 4 + (lane >> 4)) ^ (br & 7)) * 8);
                bh[j] = *(const bf16x8*)&BsH[off];
                bl[j] = *(const bf16x8*)&BsL[off];
            }
            #pragma unroll
            for (int i = 0; i < 4; i++) {
                #pragma unroll
                for (int j = 0; j < 4; j++) {
                    acc[i][j] = MF(ah[i], bh[j], acc[i][j]);
                    acc[i][j] = MF(ah[i], bl[j], acc[i][j]);
                    acc[i][j] = MF(al[i], bh[j], acc[i][j]);
                }
            }
        }
        __syncthreads();
    }

    #pragma unroll
    for (int i = 0; i < 4; i++) {
        #pragma unroll
        for (int j = 0; j < 4; j++) {
            const int col = n0 + wc * 64 + j * 16 + (lane & 15);
            const float bv = bias[col];
            #pragma unroll
            for (int r = 0; r < 4; r++) {
                const int row = m0 + wr * 64 + i * 16 + (lane >> 4) * 4 + r;
                float v = acc[i][j][r] + bv;
                unsigned short hi, lo; fsplit(v, hi, lo);
                c0[(size_t)row * N + col] = hi;
                c1[(size_t)row * N + col] = lo;
            }
        }
    }
}

// ---------------------------------------------------------------------------
// i/f gate projection (layer 0 only). 256 threads = 4 waves, one row per wave.
// ---------------------------------------------------------------------------
__global__ __launch_bounds__(256) void ifproj(
    const unsigned short* __restrict__ hbh, const unsigned short* __restrict__ hbl,
    const float* __restrict__ wi, const float* __restrict__ wf,
    const float* __restrict__ bi, const float* __restrict__ bf,
    float* __restrict__ iout, float* __restrict__ fout)
{
    const int w    = threadIdx.x >> 6;
    const int lane = threadIdx.x & 63;
    const int row  = blockIdx.x * 4 + w;
    ushort4 a4 = *(const ushort4*)(hbh + (size_t)row * HIDN + lane * 4);
    ushort4 l4 = *(const ushort4*)(hbl + (size_t)row * HIDN + lane * 4);
    float yv[4];
    yv[0] = b2f(a4.x) + b2f(l4.x);
    yv[1] = b2f(a4.y) + b2f(l4.y);
    yv[2] = b2f(a4.z) + b2f(l4.z);
    yv[3] = b2f(a4.w) + b2f(l4.w);

    float g8[8] = {0.f,0.f,0.f,0.f,0.f,0.f,0.f,0.f};
    #pragma unroll
    for (int j = 0; j < 4; j++) {
        const float4 wiv = *(const float4*)(wi + (size_t)(lane * 4 + j) * 4);
        const float4 wfv = *(const float4*)(wf + (size_t)(lane * 4 + j) * 4);
        g8[0] += yv[j] * wiv.x; g8[1] += yv[j] * wiv.y;
        g8[2] += yv[j] * wiv.z; g8[3] += yv[j] * wiv.w;
        g8[4] += yv[j] * wfv.x; g8[5] += yv[j] * wfv.y;
        g8[6] += yv[j] * wfv.z; g8[7] += yv[j] * wfv.w;
    }
    #pragma unroll
    for (int o = 0; o < 8; o++)
        #pragma unroll
        for (int off = 32; off; off >>= 1) g8[o] += __shfl_xor(g8[o], off);
    if (lane < 8) {
        const int o = lane;
        if (o < 4) iout[(size_t)row * NH + o] = g8[0] * 0.f + ((float*)g8)[0] * 0.f + g8[o] + bi[o];
        else       fout[(size_t)row * NH + (o - 4)] = g8[o] + bf[o - 4];
    }
}

// ---------------------------------------------------------------------------
// FUSED layer kernel v3: 8 waves, one block per (b,h), 80 KiB dynamic LDS
// (2 blocks/CU). 2-phase pipelined GEMM: BK=32, double-buffered staging,
// STAGE(next) issued before compute(cur), one vmcnt(0)+barrier per step.
// Staging LDS (shorts), buffer p at p*20480:
//   AH +0 (2048) AL +2048 BH +4096 (8192) BL +12288   [40KB per buffer]
// 64B-row swizzle: phys chunk = logical chunk ^ ((row>>1)&3).
// Attn tiles overlay everything after the GEMM (same layout as v2):
//   Ot f32 [0,8192) Qh@8192 Ql@12288 Kh@16384 Kl@20480
//   Th@24576 Tl@28672 Vh@32768 Vl@36864 ; Ph@8192/Pl@12800 (stride 72);
//   denF f32x128 @ short 18432 (dead Kh)
// ---------------------------------------------------------------------------
__global__ __launch_bounds__(512, 4) void fused_layer(
    const unsigned short* __restrict__ Ah, const unsigned short* __restrict__ Al,
    const unsigned short* __restrict__ Bh, const unsigned short* __restrict__ Bl,
    const float* __restrict__ bo,
    const float* __restrict__ irg, const float* __restrict__ frg,
    unsigned short* __restrict__ hoh, unsigned short* __restrict__ hol)
{
    extern __shared__ char smem[];
    unsigned short* const S = (unsigned short*)smem;
    float* const Ot   = (float*)smem;
    float* const denF = (float*)(S + 18432);

    const int n0  = blockIdx.x;
    const int mm  = n0 >> 3;
    const int hh  = mm & 3;
    const int b   = (n0 & 7) + 8 * (mm >> 2);      // 4 heads of b -> same XCD
    const int tid = threadIdx.x, lane = tid & 63, w = tid >> 6;

    // gate prefix scans, in registers (redundant per wave)
    float iv = irg[(size_t)(b * TT + lane) * NH + hh];
    float fv = frg[(size_t)(b * TT + lane) * NH + hh];
    float F = fv;
    #pragma unroll
    for (int d2 = 1; d2 < 64; d2 <<= 1) { float o2 = __shfl_up(F, d2); if (lane >= d2) F += o2; }
    const float sa_r = iv - F;                     // a_t = i_t - F_t
    float pm = sa_r;
    #pragma unroll
    for (int d2 = 1; d2 < 64; d2 <<= 1) { float o2 = __shfl_up(pm, d2); if (lane >= d2) pm = fmaxf(pm, o2); }
    const float sc_r = -fmaxf(0.f, pm);            // F_t - m_t

    const int wm = w >> 2, wn = w & 3;

    // staging: 2560 16B-chunks per fill, 5 rounds x 512 threads
    auto STAGE = [&](int p, int k0) {
        const int bs = p * 20480;
        #pragma unroll
        for (int rd = 0; rd < 5; rd++) {
            const int cid = rd * 512 + tid;
            const unsigned short* srcp;
            int dst;
            if (cid < 512) {                       // A tile h/l (waves 0-3 / 4-7)
                const int hl = cid >> 8;
                const int c  = cid & 255;
                const int r  = c >> 2, cp = c & 3;
                const int col = k0 + ((cp ^ ((r >> 1) & 3)) * 8);
                srcp = (hl ? Al : Ah) + (size_t)(b * TT + r) * 256 + col;
                dst  = bs + hl * 2048 + c * 8;
            } else {                               // B tile h/l
                const int c2 = cid - 512;          // 0..2047
                const int hl = c2 >> 10;
                const int c  = c2 & 1023;
                const int r  = c >> 2, cp = c & 3;
                const int grow = (r >> 6) * 256 + hh * 64 + (r & 63);
                const int col = k0 + ((cp ^ ((r >> 1) & 3)) * 8);
                srcp = (hl ? Bl : Bh) + (size_t)grow * 256 + col;
                dst  = bs + 4096 + hl * 8192 + c * 8;
            }
            __builtin_amdgcn_global_load_lds(
                (const __attribute__((address_space(1))) void*)srcp,
                (__attribute__((address_space(3))) void*)(S + dst), 16, 0, 0);
        }
    };

    // ---- GEMM phase: 8 pipelined BK=32 steps ----
    STAGE(0, 0);
    asm volatile("s_waitcnt vmcnt(0)" ::: "memory");
    __syncthreads();

    f32x4 acc[2][4] = {};
    #pragma unroll
    for (int s = 0; s < 8; s++) {
        if (s < 7) STAGE((s + 1) & 1, (s + 1) * 32);

        const int pb = (s & 1) * 20480;
        bf16x8 a_h[2], a_l[2], b_h[4], b_l[4];
        #pragma unroll
        for (int i = 0; i < 2; i++) {
            const int ar = wm * 32 + i * 16 + (lane & 15);
            const int cp = (lane >> 4) ^ ((ar >> 1) & 3);
            a_h[i] = *(const bf16x8*)&S[pb + ar * 32 + cp * 8];
            a_l[i] = *(const bf16x8*)&S[pb + 2048 + ar * 32 + cp * 8];
        }
        #pragma unroll
        for (int j = 0; j < 4; j++) {
            const int br = wn * 64 + j * 16 + (lane & 15);
            const int cp = (lane >> 4) ^ ((br >> 1) & 3);
            b_h[j] = *(const bf16x8*)&S[pb + 4096 + br * 32 + cp * 8];
            b_l[j] = *(const bf16x8*)&S[pb + 12288 + br * 32 + cp * 8];
        }
        #pragma unroll
        for (int i = 0; i < 2; i++) {
            #pragma unroll
            for (int j = 0; j < 4; j++) {
                acc[i][j] = MF(a_h[i], b_h[j], acc[i][j]);
                acc[i][j] = MF(a_h[i], b_l[j], acc[i][j]);
                acc[i][j] = MF(a_l[i], b_h[j], acc[i][j]);
            }
        }
        if (s < 7) {
            asm volatile("s_waitcnt vmcnt(0)" ::: "memory");
            __syncthreads();
        }
    }
    __syncthreads();   // all waves done with staging buffers

    // ---- epilogue: scatter q/k/kt/v/o into LDS tiles (wave wn owns seg wn) --
    const int colb = lane & 15;
    const int rowb = (lane >> 4) * 4;
    #pragma unroll
    for (int i = 0; i < 2; i++) {
        #pragma unroll
        for (int j = 0; j < 4; j++) {
            const int d = j * 16 + colb;
            #pragma unroll
            for (int r = 0; r < 4; r++) {
                const int t = wm * 32 + i * 16 + rowb + r;
                float v = acc[i][j][r];
                if (wn == 0) {                     // q * D^-1/2
                    v *= 0.125f;
                    unsigned short hi, lo; fsplit(v, hi, lo);
                    const int idx = t * 64 + (d ^ ((t & 7) << 3));
                    S[8192 + idx] = hi; S[12288 + idx] = lo;
                } else if (wn == 1) {              // k (+ transposed copy)
                    unsigned short hi, lo; fsplit(v, hi, lo);
                    const int idx = t * 64 + (d ^ ((t & 7) << 3));
                    S[16384 + idx] = hi; S[20480 + idx] = lo;
                    const int idx2 = d * 64 + (t ^ ((d & 7) << 3));
                    S[24576 + idx2] = hi; S[28672 + idx2] = lo;
                } else if (wn == 2) {              // v
                    unsigned short hi, lo; fsplit(v, hi, lo);
                    const int idx = t * 64 + (d ^ ((t & 7) << 3));
                    S[32768 + idx] = hi; S[36864 + idx] = lo;
                } else {                           // o = sigmoid(.+bo), f32
                    Ot[t * 64 + d] = 1.f / (1.f + __expf(-(v + bo[hh * 64 + d])));
                }
            }
        }
    }
    __syncthreads();

    // ---- S phase: wave (tg = w&3) t-rows [16tg,16tg+16), (sh = w>>2) s-half -
    const int tg = w & 3, sh = w >> 2;
    f32x4 sv[2] = {}, sk[2] = {};
    const int tA = tg * 16 + (lane & 15);
    #pragma unroll
    for (int kk = 0; kk < 2; kk++) {
        const int eA = (kk * 32 + (lane >> 4) * 8) ^ ((tA & 7) << 3);
        bf16x8 aQh = *(const bf16x8*)&S[8192  + tA * 64 + eA];
        bf16x8 aQl = *(const bf16x8*)&S[12288 + tA * 64 + eA];
        #pragma unroll
        for (int j = 0; j < 2; j++) {
            const int sB = sh * 32 + j * 16 + (lane & 15);
            const int eB = (kk * 32 + (lane >> 4) * 8) ^ ((sB & 7) << 3);
            bf16x8 bKh = *(const bf16x8*)&S[16384 + sB * 64 + eB];
            bf16x8 bKl = *(const bf16x8*)&S[20480 + sB * 64 + eB];
            bf16x8 bVh = *(const bf16x8*)&S[32768 + sB * 64 + eB];
            bf16x8 bVl = *(const bf16x8*)&S[36864 + sB * 64 + eB];
            sv[j] = MF(aQh, bVh, sv[j]);
            sv[j] = MF(aQh, bVl, sv[j]);
            sv[j] = MF(aQl, bVh, sv[j]);
            sk[j] = MF(aQh, bKh, sk[j]);
            sk[j] = MF(aQh, bKl, sk[j]);
            sk[j] = MF(aQl, bKh, sk[j]);
        }
    }

    // mask + half-denominator
    const int tbase = tg * 16 + (lane >> 4) * 4;
    float cw[4], dh4[4] = {0.f, 0.f, 0.f, 0.f};
    #pragma unroll
    for (int r = 0; r < 4; r++) cw[r] = __shfl(sc_r, tbase + r);
    #pragma unroll
    for (int j = 0; j < 2; j++) {
        const int s = sh * 32 + j * 16 + (lane & 15);
        const float as = __shfl(sa_r, s);
        #pragma unroll
        for (int r = 0; r < 4; r++) {
            const int t = tbase + r;
            const float wgt = (s <= t) ? __expf(as + cw[r]) : 0.f;
            sv[j][r] *= wgt;
            dh4[r] += sk[j][r] * wgt;
        }
    }
    #pragma unroll
    for (int r = 0; r < 4; r++) {
        dh4[r] += __shfl_xor(dh4[r], 1);
        dh4[r] += __shfl_xor(dh4[r], 2);
        dh4[r] += __shfl_xor(dh4[r], 4);
        dh4[r] += __shfl_xor(dh4[r], 8);
    }

    __syncthreads();   // all waves done reading Q/K/V before overlays

    // write P split (stride-72 rows over dead Q region) + den halves
    #pragma unroll
    for (int j = 0; j < 2; j++) {
        const int s = sh * 32 + j * 16 + (lane & 15);
        #pragma unroll
        for (int r = 0; r < 4; r++) {
            const int t = tbase + r;
            unsigned short hi, lo; fsplit(sv[j][r], hi, lo);
            S[8192  + t * 72 + s] = hi;
            S[12800 + t * 72 + s] = lo;
        }
    }
    if ((lane & 15) == 0) {
        #pragma unroll
        for (int r = 0; r < 4; r++) denF[sh * 64 + tbase + r] = dh4[r];
    }
    __syncthreads();

    // ---- PV phase: num = P @ K (B from KT tiles); wave (tg, eh=sh) ----
    f32x4 num[2] = {};
    #pragma unroll
    for (int kk = 0; kk < 2; kk++) {
        const int sA2 = kk * 32 + (lane >> 4) * 8;
        bf16x8 aPh = *(const bf16x8*)&S[8192  + tA * 72 + sA2];
        bf16x8 aPl = *(const bf16x8*)&S[12800 + tA * 72 + sA2];
        #pragma unroll
        for (int j = 0; j < 2; j++) {
            const int e2 = sh * 32 + j * 16 + (lane & 15);
            const int tB = (kk * 32 + (lane >> 4) * 8) ^ ((e2 & 7) << 3);
            bf16x8 bTh = *(const bf16x8*)&S[24576 + e2 * 64 + tB];
            bf16x8 bTl = *(const bf16x8*)&S[28672 + e2 * 64 + tB];
            num[j] = MF(aPh, bTh, num[j]);
            num[j] = MF(aPh, bTl, num[j]);
            num[j] = MF(aPl, bTh, num[j]);
        }
    }

    // ---- output: h = o * num / den -> split bf16 ----
    #pragma unroll
    for (int j = 0; j < 2; j++) {
        const int e = sh * 32 + j * 16 + (lane & 15);
        #pragma unroll
        for (int r = 0; r < 4; r++) {
            const int t = tbase + r;
            const float den = fmaxf(fabsf(denF[t] + denF[64 + t]), 1.f);
            const float o = Ot[t * 64 + e];
            const float hval = o * num[j][r] / den;
            unsigned short hi, lo; fsplit(hval, hi, lo);
            const size_t oidx = (size_t)(b * TT + t) * HIDN + hh * DH + e;
            hoh[oidx] = hi; hol[oidx] = lo;
        }
    }
}

// ---------------------------------------------------------------------------
// LayerNorm over 256 (+optional fused i/f gate projection for the NEXT layer).
// src split pair -> dst split pair. 4 waves = 4 rows per block.
// ---------------------------------------------------------------------------
__global__ __launch_bounds__(256) void layernorm_gate(
    const unsigned short* __restrict__ sh_, const unsigned short* __restrict__ sl_,
    unsigned short* __restrict__ dh_, unsigned short* __restrict__ dl_,
    const float* __restrict__ g, const float* __restrict__ bta,
    const float* __restrict__ wi, const float* __restrict__ wf,
    const float* __restrict__ bi, const float* __restrict__ bf,
    float* __restrict__ iout, float* __restrict__ fout)
{
    const int w    = threadIdx.x >> 6;
    const int lane = threadIdx.x & 63;
    const int row  = blockIdx.x * 4 + w;
    ushort4 a4 = *(const ushort4*)(sh_ + (size_t)row * HIDN + lane * 4);
    ushort4 l4 = *(const ushort4*)(sl_ + (size_t)row * HIDN + lane * 4);
    float x0 = b2f(a4.x) + b2f(l4.x);
    float x1 = b2f(a4.y) + b2f(l4.y);
    float x2 = b2f(a4.z) + b2f(l4.z);
    float x3 = b2f(a4.w) + b2f(l4.w);
    float s = x0 + x1 + x2 + x3;
    #pragma unroll
    for (int off = 32; off; off >>= 1) s += __shfl_xor(s, off);
    const float mu = s * (1.f / 256.f);
    const float d0 = x0 - mu, d1 = x1 - mu, d2 = x2 - mu, d3 = x3 - mu;
    float vs = d0*d0 + d1*d1 + d2*d2 + d3*d3;
    #pragma unroll
    for (int off = 32; off; off >>= 1) vs += __shfl_xor(vs, off);
    const float rstd = rsqrtf(vs * (1.f / 256.f) + EPS);
    const float4 gv = *(const float4*)(g + lane * 4);
    const float4 bv = *(const float4*)(bta + lane * 4);
    float yv[4];
    yv[0] = d0 * rstd * gv.x + bv.x;
    yv[1] = d1 * rstd * gv.y + bv.y;
    yv[2] = d2 * rstd * gv.z + bv.z;
    yv[3] = d3 * rstd * gv.w + bv.w;
    ushort4 h4, o4;
    fsplit(yv[0], h4.x, o4.x); fsplit(yv[1], h4.y, o4.y);
    fsplit(yv[2], h4.z, o4.z); fsplit(yv[3], h4.w, o4.w);
    *(ushort4*)(dh_ + (size_t)row * HIDN + lane * 4) = h4;
    *(ushort4*)(dl_ + (size_t)row * HIDN + lane * 4) = o4;

    if (wi) {   // fused gate projection for the next layer
        float g8[8] = {0.f,0.f,0.f,0.f,0.f,0.f,0.f,0.f};
        #pragma unroll
        for (int j = 0; j < 4; j++) {
            const float4 wiv = *(const float4*)(wi + (size_t)(lane * 4 + j) * 4);
            const float4 wfv = *(const float4*)(wf + (size_t)(lane * 4 + j) * 4);
            g8[0] += yv[j] * wiv.x; g8[1] += yv[j] * wiv.y;
            g8[2] += yv[j] * wiv.z; g8[3] += yv[j] * wiv.w;
            g8[4] += yv[j] * wfv.x; g8[5] += yv[j] * wfv.y;
            g8[6] += yv[j] * wfv.z; g8[7] += yv[j] * wfv.w;
        }
        #pragma unroll
        for (int o = 0; o < 8; o++)
            #pragma unroll
            for (int off = 32; off; off >>= 1) g8[o] += __shfl_xor(g8[o], off);
        if (lane < 4)                iout[(size_t)row * NH + lane] = g8[lane] + bi[lane];
        else if (lane < 8)           fout[(size_t)row * NH + lane - 4] = g8[lane] + bf[lane - 4];
    }
}

// ---------------------------------------------------------------------------
// Final head: z = h[:, T-1, :]; out = relu(z@W1 + b1) @ W2 + b2
// ---------------------------------------------------------------------------
__global__ __launch_bounds__(128) void head_mlp(
    const unsigned short* __restrict__ hbh, const unsigned short* __restrict__ hbl,
    const float* __restrict__ W1, const float* __restrict__ b1,
    const float* __restrict__ W2, const float* __restrict__ b2,
    float* __restrict__ out)
{
    const int b = blockIdx.x;
    const int j = threadIdx.x;
    __shared__ float z[HIDN];
    __shared__ float a[128];
    const size_t rb = ((size_t)b * TT + (TT - 1)) * HIDN;
    z[j]       = b2f(hbh[rb + j])       + b2f(hbl[rb + j]);
    z[j + 128] = b2f(hbh[rb + j + 128]) + b2f(hbl[rb + j + 128]);
    __syncthreads();
    float acc = b1[j];
    #pragma unroll 4
    for (int c = 0; c < HIDN; c++) acc += z[c] * W1[c * 128 + j];
    a[j] = fmaxf(acc, 0.f);
    __syncthreads();
    if (j < 2) {
        float s = b2[j];
        for (int c = 0; c < 128; c++) s += a[c] * W2[c * 2 + j];
        out[b * 2 + j] = s;
    }
}

// ---------------------------------------------------------------------------
extern "C" void kernel_launch(void* const* d_in, const int* in_sizes, int n_in,
                              void* d_out, int out_size, void* d_ws, size_t ws_size,
                              hipStream_t stream)
{
    const float* x   = (const float*)d_in[0];
    const float* Wp  = (const float*)d_in[1];
    const float* bp  = (const float*)d_in[2];
    const float* Wq  = (const float*)d_in[3];
    const float* Wk  = (const float*)d_in[4];
    const float* Wv  = (const float*)d_in[5];
    const float* Wo  = (const float*)d_in[6];
    const float* bo  = (const float*)d_in[7];
    const float* wi  = (const float*)d_in[8];
    const float* bi  = (const float*)d_in[9];
    const float* wf  = (const float*)d_in[10];
    const float* bf  = (const float*)d_in[11];
    const float* lng = (const float*)d_in[12];
    const float* lnb = (const float*)d_in[13];
    const float* W1  = (const float*)d_in[14];
    const float* b1  = (const float*)d_in[15];
    const float* W2  = (const float*)d_in[16];
    const float* b2  = (const float*)d_in[17];
    float* out = (float*)d_out;

    // workspace layout (~37 MB)
    unsigned short* hbh = (unsigned short*)d_ws;            // [ROWS][256]
    unsigned short* hbl = hbh + (size_t)ROWS * HIDN;
    unsigned short* h2h = hbl + (size_t)ROWS * HIDN;        // fused-layer output
    unsigned short* h2l = h2h + (size_t)ROWS * HIDN;
    float*          ir  = (float*)(h2l + (size_t)ROWS * HIDN);
    float*          fr  = ir + (size_t)ROWS * NH;
    unsigned short* WpTh = (unsigned short*)(fr + (size_t)ROWS * NH);
    unsigned short* WpTl = WpTh + (size_t)HIDN * KPAD;
    unsigned short* Wth  = WpTl + (size_t)HIDN * KPAD;
    unsigned short* Wtl  = Wth + (size_t)2 * 1024 * 256;
    // pack_x outputs alias h2h/h2l (dead until first fused layer writes them)
    unsigned short* xh = h2h;
    unsigned short* xl = h2l;

    pack_x<<<(ROWS * KPAD + 255) / 256, 256, 0, stream>>>(x, xh, xl);
    pack_w2<<<140, 256, 0, stream>>>(Wp, Wq, Wk, Wv, Wo, WpTh, WpTl, Wth, Wtl);

    // input projection: hb = x @ Wp + bp (split); grid transposed (m = x)
    gemm_mfma3<<<dim3(128, 2), 256, 0, stream>>>(
        xh, xl, WpTh, WpTl, bp, hbh, hbl, ROWS, HIDN, KPAD);

    // layer-0 gates
    ifproj<<<ROWS / 4, 256, 0, stream>>>(hbh, hbl, wi, wf, bi, bf, ir, fr);

    // layer 0
    fused_layer<<<BATCH * NH, 512, 81920, stream>>>(
        hbh, hbl, Wth, Wtl, bo, ir, fr, h2h, h2l);
    // LN + layer-1 gates
    layernorm_gate<<<ROWS / 4, 256, 0, stream>>>(
        h2h, h2l, hbh, hbl, lng, lnb,
        wi + (size_t)HIDN * NH, wf + (size_t)HIDN * NH, bi + NH, bf + NH, ir, fr);

    // layer 1
    fused_layer<<<BATCH * NH, 512, 81920, stream>>>(
        hbh, hbl, Wth + (size_t)1024 * 256, Wtl + (size_t)1024 * 256,
        bo + HIDN, ir, fr, h2h, h2l);
    // final LN (no gates)
    layernorm_gate<<<ROWS / 4, 256, 0, stream>>>(
        h2h, h2l, hbh, hbl, lng + HIDN, lnb + HIDN,
        nullptr, nullptr, nullptr, nullptr, nullptr, nullptr);

    head_mlp<<<BATCH, 128, 0, stream>>>(hbh, hbl, W1, b1, W2, b2, out);
}

// Round 10
// 169.881 us; speedup vs baseline: 3.8266x; 1.0117x over previous
//
#include <hip/hip_runtime.h>
#include <math.h>

typedef __attribute__((ext_vector_type(4))) float f32x4;
typedef __attribute__((ext_vector_type(8))) short bf16x8;

constexpr int BATCH = 256;
constexpr int TT    = 64;
constexpr int NH    = 4;
constexpr int DH    = 64;
constexpr int HIDN  = 256;
constexpr int INDIM = 170;
constexpr int KPAD  = 192;
constexpr int ROWS  = BATCH * TT;    // 16384
constexpr float EPS = 1e-5f;

#define MF(a, b, c) __builtin_amdgcn_mfma_f32_16x16x32_bf16((a), (b), (c), 0, 0, 0)

__device__ __forceinline__ unsigned short f2b(float f) {
    union { float f; unsigned int u; } v; v.f = f;
    return (unsigned short)((v.u + 0x7FFFu + ((v.u >> 16) & 1u)) >> 16);
}
__device__ __forceinline__ float b2f(unsigned short b) {
    union { unsigned int u; float f; } v; v.u = ((unsigned int)b) << 16;
    return v.f;
}
__device__ __forceinline__ void fsplit(float x, unsigned short& hi, unsigned short& lo) {
    hi = f2b(x);
    lo = f2b(x - b2f(hi));
}

// ---------------------------------------------------------------------------
// pack_x: x [ROWS][170] f32 -> xh/xl [ROWS][192] split bf16 (zero-padded)
// ---------------------------------------------------------------------------
__global__ __launch_bounds__(256) void pack_x(
    const float* __restrict__ x,
    unsigned short* __restrict__ xh, unsigned short* __restrict__ xl)
{
    int idx = blockIdx.x * 256 + threadIdx.x;
    if (idx >= ROWS * KPAD) return;
    int r = idx / KPAD, c = idx % KPAD;
    float v = (c < INDIM) ? x[(size_t)r * INDIM + c] : 0.f;
    unsigned short hi, lo; fsplit(v, hi, lo);
    xh[idx] = hi; xl[idx] = lo;
}

// ---------------------------------------------------------------------------
// pack_w2: LDS-transpose weight pack (coalesced reads and writes).
//   tiles 0..127 : Wt  [2][1024 n][256 k]  from Wq/Wk/Wv/Wo [2][256 k][256 n]
//   tiles 128..139: WpT [256 n][192 k]     from Wp [170 k][256 n] (k zero-pad)
// ---------------------------------------------------------------------------
__global__ __launch_bounds__(256) void pack_w2(
    const float* __restrict__ Wp, const float* __restrict__ Wq,
    const float* __restrict__ Wk, const float* __restrict__ Wv,
    const float* __restrict__ Wo,
    unsigned short* __restrict__ WpTh, unsigned short* __restrict__ WpTl,
    unsigned short* __restrict__ Wth,  unsigned short* __restrict__ Wtl)
{
    __shared__ float T[64][65];
    const int t = blockIdx.x, tid = threadIdx.x;

    if (t < 128) {
        const int l = t >> 6, rem = t & 63;
        const int kt = rem >> 4, nt = rem & 15;
        const int n0 = nt * 64;
        const int seg = n0 >> 8, ns0 = n0 & 255;
        const float* W = (seg == 0) ? Wq : (seg == 1) ? Wk : (seg == 2) ? Wv : Wo;
        #pragma unroll
        for (int p = 0; p < 16; p++) {
            const int idx = p * 256 + tid;
            const int r = idx >> 6, c = idx & 63;
            T[r][c] = W[(size_t)l * 65536 + (size_t)(kt * 64 + r) * 256 + ns0 + c];
        }
        __syncthreads();
        #pragma unroll
        for (int p = 0; p < 16; p++) {
            const int idx = p * 256 + tid;
            const int nl = idx >> 6, kl = idx & 63;
            unsigned short hi, lo; fsplit(T[kl][nl], hi, lo);
            const size_t d = (size_t)l * 1024 * 256 + (size_t)(n0 + nl) * 256 + kt * 64 + kl;
            Wth[d] = hi; Wtl[d] = lo;
        }
    } else {
        const int t2 = t - 128;
        const int kt = t2 % 3, nt = t2 / 3;
        #pragma unroll
        for (int p = 0; p < 16; p++) {
            const int idx = p * 256 + tid;
            const int r = idx >> 6, c = idx & 63;
            const int k = kt * 64 + r;
            T[r][c] = (k < INDIM) ? Wp[(size_t)k * HIDN + nt * 64 + c] : 0.f;
        }
        __syncthreads();
        #pragma unroll
        for (int p = 0; p < 16; p++) {
            const int idx = p * 256 + tid;
            const int nl = idx >> 6, kl = idx & 63;
            unsigned short hi, lo; fsplit(T[kl][nl], hi, lo);
            const size_t d = (size_t)(nt * 64 + nl) * KPAD + kt * 64 + kl;
            WpTh[d] = hi; WpTl[d] = lo;
        }
    }
}

// ---------------------------------------------------------------------------
// split-bf16 MFMA GEMM (3-product), input projection only.
// 128x128 tile, 4 waves; m on blockIdx.x so same-A blocks share an XCD.
// ---------------------------------------------------------------------------
__global__ __launch_bounds__(256) void gemm_mfma3(
    const unsigned short* __restrict__ Ah, const unsigned short* __restrict__ Al,
    const unsigned short* __restrict__ Bh, const unsigned short* __restrict__ Bl,
    const float* __restrict__ bias,
    unsigned short* __restrict__ c0, unsigned short* __restrict__ c1,
    int M, int N, int K)
{
    __shared__ unsigned short AsH[128 * 64];
    __shared__ unsigned short AsL[128 * 64];
    __shared__ unsigned short BsH[128 * 64];
    __shared__ unsigned short BsL[128 * 64];
    const int tid  = threadIdx.x;
    const int lane = tid & 63;
    const int wave = tid >> 6;
    const int wr = wave >> 1, wc = wave & 1;
    const int m0 = blockIdx.x * 128, n0 = blockIdx.y * 128;

    f32x4 acc[4][4] = {};

    for (int k0 = 0; k0 < K; k0 += 64) {
        #pragma unroll
        for (int j = 0; j < 4; j++) {
            int c   = j * 256 + tid;
            int row = c >> 3;
            int kcs = ((c & 7) ^ (row & 7)) * 8;
            size_t aoff = (size_t)(m0 + row) * K + k0 + kcs;
            size_t boff = (size_t)(n0 + row) * K + k0 + kcs;
            __builtin_amdgcn_global_load_lds(
                (const __attribute__((address_space(1))) void*)(Ah + aoff),
                (__attribute__((address_space(3))) void*)(AsH + c * 8), 16, 0, 0);
            __builtin_amdgcn_global_load_lds(
                (const __attribute__((address_space(1))) void*)(Al + aoff),
                (__attribute__((address_space(3))) void*)(AsL + c * 8), 16, 0, 0);
            __builtin_amdgcn_global_load_lds(
                (const __attribute__((address_space(1))) void*)(Bh + boff),
                (__attribute__((address_space(3))) void*)(BsH + c * 8), 16, 0, 0);
            __builtin_amdgcn_global_load_lds(
                (const __attribute__((address_space(1))) void*)(Bl + boff),
                (__attribute__((address_space(3))) void*)(BsL + c * 8), 16, 0, 0);
        }
        asm volatile("s_waitcnt vmcnt(0)" ::: "memory");
        __syncthreads();

        #pragma unroll
        for (int kk = 0; kk < 2; kk++) {
            bf16x8 ah[4], al[4], bh[4], bl[4];
            #pragma unroll
            for (int i = 0; i < 4; i++) {
                const int ar  = wr * 64 + i * 16 + (lane & 15);
                const int off = ar * 64 + (((kk * 4 + (lane >> 4)) ^ (ar & 7)) * 8);
                ah[i] = *(const bf16x8*)&AsH[off];
                al[i] = *(const bf16x8*)&AsL[off];
            }
            #pragma unroll
            for (int j = 0; j < 4; j++) {
                const int br  = wc * 64 + j * 16 + (lane & 15);
                const int off = br * 64 + (((kk * 4 + (lane >> 4)) ^ (br & 7)) * 8);
                bh[j] = *(const bf16x8*)&BsH[off];
                bl[j] = *(const bf16x8*)&BsL[off];
            }
            #pragma unroll
            for (int i = 0; i < 4; i++) {
                #pragma unroll
                for (int j = 0; j < 4; j++) {
                    acc[i][j] = MF(ah[i], bh[j], acc[i][j]);
                    acc[i][j] = MF(ah[i], bl[j], acc[i][j]);
                    acc[i][j] = MF(al[i], bh[j], acc[i][j]);
                }
            }
        }
        __syncthreads();
    }

    #pragma unroll
    for (int i = 0; i < 4; i++) {
        #pragma unroll
        for (int j = 0; j < 4; j++) {
            const int col = n0 + wc * 64 + j * 16 + (lane & 15);
            const float bv = bias[col];
            #pragma unroll
            for (int r = 0; r < 4; r++) {
                const int row = m0 + wr * 64 + i * 16 + (lane >> 4) * 4 + r;
                float v = acc[i][j][r] + bv;
                unsigned short hi, lo; fsplit(v, hi, lo);
                c0[(size_t)row * N + col] = hi;
                c1[(size_t)row * N + col] = lo;
            }
        }
    }
}

// ---------------------------------------------------------------------------
// i/f gate projection (layer 0 only). 256 threads = 4 waves, one row per wave.
// ---------------------------------------------------------------------------
__global__ __launch_bounds__(256) void ifproj(
    const unsigned short* __restrict__ hbh, const unsigned short* __restrict__ hbl,
    const float* __restrict__ wi, const float* __restrict__ wf,
    const float* __restrict__ bi, const float* __restrict__ bf,
    float* __restrict__ iout, float* __restrict__ fout)
{
    const int w    = threadIdx.x >> 6;
    const int lane = threadIdx.x & 63;
    const int row  = blockIdx.x * 4 + w;
    ushort4 a4 = *(const ushort4*)(hbh + (size_t)row * HIDN + lane * 4);
    ushort4 l4 = *(const ushort4*)(hbl + (size_t)row * HIDN + lane * 4);
    float yv[4];
    yv[0] = b2f(a4.x) + b2f(l4.x);
    yv[1] = b2f(a4.y) + b2f(l4.y);
    yv[2] = b2f(a4.z) + b2f(l4.z);
    yv[3] = b2f(a4.w) + b2f(l4.w);

    float g8[8] = {0.f,0.f,0.f,0.f,0.f,0.f,0.f,0.f};
    #pragma unroll
    for (int j = 0; j < 4; j++) {
        const float4 wiv = *(const float4*)(wi + (size_t)(lane * 4 + j) * 4);
        const float4 wfv = *(const float4*)(wf + (size_t)(lane * 4 + j) * 4);
        g8[0] += yv[j] * wiv.x; g8[1] += yv[j] * wiv.y;
        g8[2] += yv[j] * wiv.z; g8[3] += yv[j] * wiv.w;
        g8[4] += yv[j] * wfv.x; g8[5] += yv[j] * wfv.y;
        g8[6] += yv[j] * wfv.z; g8[7] += yv[j] * wfv.w;
    }
    #pragma unroll
    for (int o = 0; o < 8; o++)
        #pragma unroll
        for (int off = 32; off; off >>= 1) g8[o] += __shfl_xor(g8[o], off);
    if (lane < 4)      iout[(size_t)row * NH + lane] = g8[lane] + bi[lane];
    else if (lane < 8) fout[(size_t)row * NH + lane - 4] = g8[lane] + bf[lane - 4];
}

// ---------------------------------------------------------------------------
// FUSED layer kernel v4: 8 waves, one block per (b,h), 80 KiB dynamic LDS
// (2 blocks/CU). BK=32 double-buffered pipeline with HOISTED staging
// addresses (5 (ptr,dst) pairs per thread precomputed; ptr += 32/step) and
// hoisted ds_read offsets; s_setprio(1) around the MFMA cluster.
// Staging LDS (shorts), buffer p at p*20480:
//   AH +0 AL +2048 BH +4096 BL +12288
// 64B-row swizzle: phys chunk = logical chunk ^ ((row>>1)&3).
// Attn tiles overlay after GEMM: Ot f32 [0,8192) Qh@8192 Ql@12288 Kh@16384
//   Kl@20480 Th@24576 Tl@28672 Vh@32768 Vl@36864 ; Ph@8192/Pl@12800 (stride
//   72); denF f32x128 @ short 18432 (dead Kh)
// ---------------------------------------------------------------------------
__global__ __launch_bounds__(512, 4) void fused_layer(
    const unsigned short* __restrict__ Ah, const unsigned short* __restrict__ Al,
    const unsigned short* __restrict__ Bh, const unsigned short* __restrict__ Bl,
    const float* __restrict__ bo,
    const float* __restrict__ irg, const float* __restrict__ frg,
    unsigned short* __restrict__ hoh, unsigned short* __restrict__ hol)
{
    extern __shared__ char smem[];
    unsigned short* const S = (unsigned short*)smem;
    float* const Ot   = (float*)smem;
    float* const denF = (float*)(S + 18432);

    const int n0  = blockIdx.x;
    const int mm  = n0 >> 3;
    const int hh  = mm & 3;
    const int b   = (n0 & 7) + 8 * (mm >> 2);      // 4 heads of b -> same XCD
    const int tid = threadIdx.x, lane = tid & 63, w = tid >> 6;

    // gate prefix scans, in registers (redundant per wave)
    float iv = irg[(size_t)(b * TT + lane) * NH + hh];
    float fv = frg[(size_t)(b * TT + lane) * NH + hh];
    float F = fv;
    #pragma unroll
    for (int d2 = 1; d2 < 64; d2 <<= 1) { float o2 = __shfl_up(F, d2); if (lane >= d2) F += o2; }
    const float sa_r = iv - F;                     // a_t = i_t - F_t
    float pm = sa_r;
    #pragma unroll
    for (int d2 = 1; d2 < 64; d2 <<= 1) { float o2 = __shfl_up(pm, d2); if (lane >= d2) pm = fmaxf(pm, o2); }
    const float sc_r = -fmaxf(0.f, pm);            // F_t - m_t

    const int wm = w >> 2, wn = w & 3;

    // ---- hoisted staging addresses: 5 (globalptr, ldsoff) pairs/thread ----
    const unsigned short* sptr0; const unsigned short* sptr1;
    const unsigned short* sptr2; const unsigned short* sptr3;
    const unsigned short* sptr4;
    int sdst0, sdst1, sdst2, sdst3, sdst4;
    {
        // rd = 0: A tiles (cid = tid < 512)
        {
            const int hl = tid >> 8, c = tid & 255;
            const int r = c >> 2, cp = c & 3;
            const int col = (cp ^ ((r >> 1) & 3)) * 8;
            sptr0 = (hl ? Al : Ah) + (size_t)(b * TT + r) * 256 + col;
            sdst0 = hl * 2048 + c * 8;
        }
        // rd = 1..4: B tiles (c2 = rd*512 + tid - 512 = (rd-1)*512 + tid)
        #pragma unroll
        for (int rr = 0; rr < 4; rr++) {
            const int c2 = rr * 512 + tid;
            const int hl = c2 >> 10, c = c2 & 1023;
            const int r = c >> 2, cp = c & 3;
            const int grow = (r >> 6) * 256 + hh * 64 + (r & 63);
            const int col = (cp ^ ((r >> 1) & 3)) * 8;
            const unsigned short* p = (hl ? Bl : Bh) + (size_t)grow * 256 + col;
            const int d = 4096 + hl * 8192 + c * 8;
            if (rr == 0) { sptr1 = p; sdst1 = d; }
            else if (rr == 1) { sptr2 = p; sdst2 = d; }
            else if (rr == 2) { sptr3 = p; sdst3 = d; }
            else { sptr4 = p; sdst4 = d; }
        }
    }

#define STAGE(bs)                                                              \
    do {                                                                       \
        __builtin_amdgcn_global_load_lds(                                      \
            (const __attribute__((address_space(1))) void*)sptr0,              \
            (__attribute__((address_space(3))) void*)(S + (bs) + sdst0), 16, 0, 0); \
        __builtin_amdgcn_global_load_lds(                                      \
            (const __attribute__((address_space(1))) void*)sptr1,              \
            (__attribute__((address_space(3))) void*)(S + (bs) + sdst1), 16, 0, 0); \
        __builtin_amdgcn_global_load_lds(                                      \
            (const __attribute__((address_space(1))) void*)sptr2,              \
            (__attribute__((address_space(3))) void*)(S + (bs) + sdst2), 16, 0, 0); \
        __builtin_amdgcn_global_load_lds(                                      \
            (const __attribute__((address_space(1))) void*)sptr3,              \
            (__attribute__((address_space(3))) void*)(S + (bs) + sdst3), 16, 0, 0); \
        __builtin_amdgcn_global_load_lds(                                      \
            (const __attribute__((address_space(1))) void*)sptr4,              \
            (__attribute__((address_space(3))) void*)(S + (bs) + sdst4), 16, 0, 0); \
        sptr0 += 32; sptr1 += 32; sptr2 += 32; sptr3 += 32; sptr4 += 32;       \
    } while (0)

    // hoisted ds_read offsets (buffer-relative)
    int aoff_[2], boff_[4];
    #pragma unroll
    for (int i = 0; i < 2; i++) {
        const int ar = wm * 32 + i * 16 + (lane & 15);
        aoff_[i] = ar * 32 + (((lane >> 4) ^ ((ar >> 1) & 3)) * 8);
    }
    #pragma unroll
    for (int j = 0; j < 4; j++) {
        const int br = wn * 64 + j * 16 + (lane & 15);
        boff_[j] = br * 32 + (((lane >> 4) ^ ((br >> 1) & 3)) * 8);
    }

    // ---- GEMM phase: 8 pipelined BK=32 steps ----
    STAGE(0);
    asm volatile("s_waitcnt vmcnt(0)" ::: "memory");
    __syncthreads();

    f32x4 acc[2][4] = {};
    #pragma unroll
    for (int s = 0; s < 8; s++) {
        if (s < 7) STAGE(((s + 1) & 1) * 20480);

        const int pb = (s & 1) * 20480;
        __builtin_amdgcn_s_setprio(1);
        bf16x8 a_h[2], a_l[2], b_h[4], b_l[4];
        #pragma unroll
        for (int i = 0; i < 2; i++) {
            a_h[i] = *(const bf16x8*)&S[pb + aoff_[i]];
            a_l[i] = *(const bf16x8*)&S[pb + 2048 + aoff_[i]];
        }
        #pragma unroll
        for (int j = 0; j < 4; j++) {
            b_h[j] = *(const bf16x8*)&S[pb + 4096 + boff_[j]];
            b_l[j] = *(const bf16x8*)&S[pb + 12288 + boff_[j]];
        }
        #pragma unroll
        for (int i = 0; i < 2; i++) {
            #pragma unroll
            for (int j = 0; j < 4; j++) {
                acc[i][j] = MF(a_h[i], b_h[j], acc[i][j]);
                acc[i][j] = MF(a_h[i], b_l[j], acc[i][j]);
                acc[i][j] = MF(a_l[i], b_h[j], acc[i][j]);
            }
        }
        __builtin_amdgcn_s_setprio(0);
        if (s < 7) {
            asm volatile("s_waitcnt vmcnt(0)" ::: "memory");
            __syncthreads();
        }
    }
    __syncthreads();   // all waves done with staging buffers
#undef STAGE

    // ---- epilogue: scatter q/k/kt/v/o into LDS tiles (wave wn owns seg wn) --
    const int colb = lane & 15;
    const int rowb = (lane >> 4) * 4;
    #pragma unroll
    for (int i = 0; i < 2; i++) {
        #pragma unroll
        for (int j = 0; j < 4; j++) {
            const int d = j * 16 + colb;
            #pragma unroll
            for (int r = 0; r < 4; r++) {
                const int t = wm * 32 + i * 16 + rowb + r;
                float v = acc[i][j][r];
                if (wn == 0) {                     // q * D^-1/2
                    v *= 0.125f;
                    unsigned short hi, lo; fsplit(v, hi, lo);
                    const int idx = t * 64 + (d ^ ((t & 7) << 3));
                    S[8192 + idx] = hi; S[12288 + idx] = lo;
                } else if (wn == 1) {              // k (+ transposed copy)
                    unsigned short hi, lo; fsplit(v, hi, lo);
                    const int idx = t * 64 + (d ^ ((t & 7) << 3));
                    S[16384 + idx] = hi; S[20480 + idx] = lo;
                    const int idx2 = d * 64 + (t ^ ((d & 7) << 3));
                    S[24576 + idx2] = hi; S[28672 + idx2] = lo;
                } else if (wn == 2) {              // v
                    unsigned short hi, lo; fsplit(v, hi, lo);
                    const int idx = t * 64 + (d ^ ((t & 7) << 3));
                    S[32768 + idx] = hi; S[36864 + idx] = lo;
                } else {                           // o = sigmoid(.+bo), f32
                    Ot[t * 64 + d] = 1.f / (1.f + __expf(-(v + bo[hh * 64 + d])));
                }
            }
        }
    }
    __syncthreads();

    // ---- S phase: wave (tg = w&3) t-rows [16tg,16tg+16), (sh = w>>2) s-half -
    const int tg = w & 3, sh = w >> 2;
    f32x4 sv[2] = {}, sk[2] = {};
    const int tA = tg * 16 + (lane & 15);
    #pragma unroll
    for (int kk = 0; kk < 2; kk++) {
        const int eA = (kk * 32 + (lane >> 4) * 8) ^ ((tA & 7) << 3);
        bf16x8 aQh = *(const bf16x8*)&S[8192  + tA * 64 + eA];
        bf16x8 aQl = *(const bf16x8*)&S[12288 + tA * 64 + eA];
        #pragma unroll
        for (int j = 0; j < 2; j++) {
            const int sB = sh * 32 + j * 16 + (lane & 15);
            const int eB = (kk * 32 + (lane >> 4) * 8) ^ ((sB & 7) << 3);
            bf16x8 bKh = *(const bf16x8*)&S[16384 + sB * 64 + eB];
            bf16x8 bKl = *(const bf16x8*)&S[20480 + sB * 64 + eB];
            bf16x8 bVh = *(const bf16x8*)&S[32768 + sB * 64 + eB];
            bf16x8 bVl = *(const bf16x8*)&S[36864 + sB * 64 + eB];
            sv[j] = MF(aQh, bVh, sv[j]);
            sv[j] = MF(aQh, bVl, sv[j]);
            sv[j] = MF(aQl, bVh, sv[j]);
            sk[j] = MF(aQh, bKh, sk[j]);
            sk[j] = MF(aQh, bKl, sk[j]);
            sk[j] = MF(aQl, bKh, sk[j]);
        }
    }

    // mask + half-denominator
    const int tbase = tg * 16 + (lane >> 4) * 4;
    float cw[4], dh4[4] = {0.f, 0.f, 0.f, 0.f};
    #pragma unroll
    for (int r = 0; r < 4; r++) cw[r] = __shfl(sc_r, tbase + r);
    #pragma unroll
    for (int j = 0; j < 2; j++) {
        const int s = sh * 32 + j * 16 + (lane & 15);
        const float as = __shfl(sa_r, s);
        #pragma unroll
        for (int r = 0; r < 4; r++) {
            const int t = tbase + r;
            const float wgt = (s <= t) ? __expf(as + cw[r]) : 0.f;
            sv[j][r] *= wgt;
            dh4[r] += sk[j][r] * wgt;
        }
    }
    #pragma unroll
    for (int r = 0; r < 4; r++) {
        dh4[r] += __shfl_xor(dh4[r], 1);
        dh4[r] += __shfl_xor(dh4[r], 2);
        dh4[r] += __shfl_xor(dh4[r], 4);
        dh4[r] += __shfl_xor(dh4[r], 8);
    }

    __syncthreads();   // all waves done reading Q/K/V before overlays

    // write P split (stride-72 rows over dead Q region) + den halves
    #pragma unroll
    for (int j = 0; j < 2; j++) {
        const int s = sh * 32 + j * 16 + (lane & 15);
        #pragma unroll
        for (int r = 0; r < 4; r++) {
            const int t = tbase + r;
            unsigned short hi, lo; fsplit(sv[j][r], hi, lo);
            S[8192  + t * 72 + s] = hi;
            S[12800 + t * 72 + s] = lo;
        }
    }
    if ((lane & 15) == 0) {
        #pragma unroll
        for (int r = 0; r < 4; r++) denF[sh * 64 + tbase + r] = dh4[r];
    }
    __syncthreads();

    // ---- PV phase: num = P @ K (B from KT tiles); wave (tg, eh=sh) ----
    f32x4 num[2] = {};
    #pragma unroll
    for (int kk = 0; kk < 2; kk++) {
        const int sA2 = kk * 32 + (lane >> 4) * 8;
        bf16x8 aPh = *(const bf16x8*)&S[8192  + tA * 72 + sA2];
        bf16x8 aPl = *(const bf16x8*)&S[12800 + tA * 72 + sA2];
        #pragma unroll
        for (int j = 0; j < 2; j++) {
            const int e2 = sh * 32 + j * 16 + (lane & 15);
            const int tB = (kk * 32 + (lane >> 4) * 8) ^ ((e2 & 7) << 3);
            bf16x8 bTh = *(const bf16x8*)&S[24576 + e2 * 64 + tB];
            bf16x8 bTl = *(const bf16x8*)&S[28672 + e2 * 64 + tB];
            num[j] = MF(aPh, bTh, num[j]);
            num[j] = MF(aPh, bTl, num[j]);
            num[j] = MF(aPl, bTh, num[j]);
        }
    }

    // ---- output: h = o * num / den -> split bf16 ----
    #pragma unroll
    for (int j = 0; j < 2; j++) {
        const int e = sh * 32 + j * 16 + (lane & 15);
        #pragma unroll
        for (int r = 0; r < 4; r++) {
            const int t = tbase + r;
            const float den = fmaxf(fabsf(denF[t] + denF[64 + t]), 1.f);
            const float o = Ot[t * 64 + e];
            const float hval = o * num[j][r] / den;
            unsigned short hi, lo; fsplit(hval, hi, lo);
            const size_t oidx = (size_t)(b * TT + t) * HIDN + hh * DH + e;
            hoh[oidx] = hi; hol[oidx] = lo;
        }
    }
}

// ---------------------------------------------------------------------------
// LayerNorm over 256 (+optional fused i/f gate projection for the NEXT layer).
// src split pair -> dst split pair. 4 waves = 4 rows per block.
// ---------------------------------------------------------------------------
__global__ __launch_bounds__(256) void layernorm_gate(
    const unsigned short* __restrict__ sh_, const unsigned short* __restrict__ sl_,
    unsigned short* __restrict__ dh_, unsigned short* __restrict__ dl_,
    const float* __restrict__ g, const float* __restrict__ bta,
    const float* __restrict__ wi, const float* __restrict__ wf,
    const float* __restrict__ bi, const float* __restrict__ bf,
    float* __restrict__ iout, float* __restrict__ fout)
{
    const int w    = threadIdx.x >> 6;
    const int lane = threadIdx.x & 63;
    const int row  = blockIdx.x * 4 + w;
    ushort4 a4 = *(const ushort4*)(sh_ + (size_t)row * HIDN + lane * 4);
    ushort4 l4 = *(const ushort4*)(sl_ + (size_t)row * HIDN + lane * 4);
    float x0 = b2f(a4.x) + b2f(l4.x);
    float x1 = b2f(a4.y) + b2f(l4.y);
    float x2 = b2f(a4.z) + b2f(l4.z);
    float x3 = b2f(a4.w) + b2f(l4.w);
    float s = x0 + x1 + x2 + x3;
    #pragma unroll
    for (int off = 32; off; off >>= 1) s += __shfl_xor(s, off);
    const float mu = s * (1.f / 256.f);
    const float d0 = x0 - mu, d1 = x1 - mu, d2 = x2 - mu, d3 = x3 - mu;
    float vs = d0*d0 + d1*d1 + d2*d2 + d3*d3;
    #pragma unroll
    for (int off = 32; off; off >>= 1) vs += __shfl_xor(vs, off);
    const float rstd = rsqrtf(vs * (1.f / 256.f) + EPS);
    const float4 gv = *(const float4*)(g + lane * 4);
    const float4 bv = *(const float4*)(bta + lane * 4);
    float yv[4];
    yv[0] = d0 * rstd * gv.x + bv.x;
    yv[1] = d1 * rstd * gv.y + bv.y;
    yv[2] = d2 * rstd * gv.z + bv.z;
    yv[3] = d3 * rstd * gv.w + bv.w;
    ushort4 h4, o4;
    fsplit(yv[0], h4.x, o4.x); fsplit(yv[1], h4.y, o4.y);
    fsplit(yv[2], h4.z, o4.z); fsplit(yv[3], h4.w, o4.w);
    *(ushort4*)(dh_ + (size_t)row * HIDN + lane * 4) = h4;
    *(ushort4*)(dl_ + (size_t)row * HIDN + lane * 4) = o4;

    if (wi) {   // fused gate projection for the next layer
        float g8[8] = {0.f,0.f,0.f,0.f,0.f,0.f,0.f,0.f};
        #pragma unroll
        for (int j = 0; j < 4; j++) {
            const float4 wiv = *(const float4*)(wi + (size_t)(lane * 4 + j) * 4);
            const float4 wfv = *(const float4*)(wf + (size_t)(lane * 4 + j) * 4);
            g8[0] += yv[j] * wiv.x; g8[1] += yv[j] * wiv.y;
            g8[2] += yv[j] * wiv.z; g8[3] += yv[j] * wiv.w;
            g8[4] += yv[j] * wfv.x; g8[5] += yv[j] * wfv.y;
            g8[6] += yv[j] * wfv.z; g8[7] += yv[j] * wfv.w;
        }
        #pragma unroll
        for (int o = 0; o < 8; o++)
            #pragma unroll
            for (int off = 32; off; off >>= 1) g8[o] += __shfl_xor(g8[o], off);
        if (lane < 4)      iout[(size_t)row * NH + lane] = g8[lane] + bi[lane];
        else if (lane < 8) fout[(size_t)row * NH + lane - 4] = g8[lane] + bf[lane - 4];
    }
}

// ---------------------------------------------------------------------------
// Final head: z = h[:, T-1, :]; out = relu(z@W1 + b1) @ W2 + b2
// ---------------------------------------------------------------------------
__global__ __launch_bounds__(128) void head_mlp(
    const unsigned short* __restrict__ hbh, const unsigned short* __restrict__ hbl,
    const float* __restrict__ W1, const float* __restrict__ b1,
    const float* __restrict__ W2, const float* __restrict__ b2,
    float* __restrict__ out)
{
    const int b = blockIdx.x;
    const int j = threadIdx.x;
    __shared__ float z[HIDN];
    __shared__ float a[128];
    const size_t rb = ((size_t)b * TT + (TT - 1)) * HIDN;
    z[j]       = b2f(hbh[rb + j])       + b2f(hbl[rb + j]);
    z[j + 128] = b2f(hbh[rb + j + 128]) + b2f(hbl[rb + j + 128]);
    __syncthreads();
    float acc = b1[j];
    #pragma unroll 4
    for (int c = 0; c < HIDN; c++) acc += z[c] * W1[c * 128 + j];
    a[j] = fmaxf(acc, 0.f);
    __syncthreads();
    if (j < 2) {
        float s = b2[j];
        for (int c = 0; c < 128; c++) s += a[c] * W2[c * 2 + j];
        out[b * 2 + j] = s;
    }
}

// ---------------------------------------------------------------------------
extern "C" void kernel_launch(void* const* d_in, const int* in_sizes, int n_in,
                              void* d_out, int out_size, void* d_ws, size_t ws_size,
                              hipStream_t stream)
{
    const float* x   = (const float*)d_in[0];
    const float* Wp  = (const float*)d_in[1];
    const float* bp  = (const float*)d_in[2];
    const float* Wq  = (const float*)d_in[3];
    const float* Wk  = (const float*)d_in[4];
    const float* Wv  = (const float*)d_in[5];
    const float* Wo  = (const float*)d_in[6];
    const float* bo  = (const float*)d_in[7];
    const float* wi  = (const float*)d_in[8];
    const float* bi  = (const float*)d_in[9];
    const float* wf  = (const float*)d_in[10];
    const float* bf  = (const float*)d_in[11];
    const float* lng = (const float*)d_in[12];
    const float* lnb = (const float*)d_in[13];
    const float* W1  = (const float*)d_in[14];
    const float* b1  = (const float*)d_in[15];
    const float* W2  = (const float*)d_in[16];
    const float* b2  = (const float*)d_in[17];
    float* out = (float*)d_out;

    // workspace layout (~37 MB)
    unsigned short* hbh = (unsigned short*)d_ws;            // [ROWS][256]
    unsigned short* hbl = hbh + (size_t)ROWS * HIDN;
    unsigned short* h2h = hbl + (size_t)ROWS * HIDN;        // fused-layer output
    unsigned short* h2l = h2h + (size_t)ROWS * HIDN;
    float*          ir  = (float*)(h2l + (size_t)ROWS * HIDN);
    float*          fr  = ir + (size_t)ROWS * NH;
    unsigned short* WpTh = (unsigned short*)(fr + (size_t)ROWS * NH);
    unsigned short* WpTl = WpTh + (size_t)HIDN * KPAD;
    unsigned short* Wth  = WpTl + (size_t)HIDN * KPAD;
    unsigned short* Wtl  = Wth + (size_t)2 * 1024 * 256;
    // pack_x outputs alias h2h/h2l (dead until first fused layer writes them)
    unsigned short* xh = h2h;
    unsigned short* xl = h2l;

    pack_x<<<(ROWS * KPAD + 255) / 256, 256, 0, stream>>>(x, xh, xl);
    pack_w2<<<140, 256, 0, stream>>>(Wp, Wq, Wk, Wv, Wo, WpTh, WpTl, Wth, Wtl);

    // input projection: hb = x @ Wp + bp (split); grid transposed (m = x)
    gemm_mfma3<<<dim3(128, 2), 256, 0, stream>>>(
        xh, xl, WpTh, WpTl, bp, hbh, hbl, ROWS, HIDN, KPAD);

    // layer-0 gates
    ifproj<<<ROWS / 4, 256, 0, stream>>>(hbh, hbl, wi, wf, bi, bf, ir, fr);

    // layer 0
    fused_layer<<<BATCH * NH, 512, 81920, stream>>>(
        hbh, hbl, Wth, Wtl, bo, ir, fr, h2h, h2l);
    // LN + layer-1 gates
    layernorm_gate<<<ROWS / 4, 256, 0, stream>>>(
        h2h, h2l, hbh, hbl, lng, lnb,
        wi + (size_t)HIDN * NH, wf + (size_t)HIDN * NH, bi + NH, bf + NH, ir, fr);

    // layer 1
    fused_layer<<<BATCH * NH, 512, 81920, stream>>>(
        hbh, hbl, Wth + (size_t)1024 * 256, Wtl + (size_t)1024 * 256,
        bo + HIDN, ir, fr, h2h, h2l);
    // final LN (no gates)
    layernorm_gate<<<ROWS / 4, 256, 0, stream>>>(
        h2h, h2l, hbh, hbl, lng + HIDN, lnb + HIDN,
        nullptr, nullptr, nullptr, nullptr, nullptr, nullptr);

    head_mlp<<<BATCH, 128, 0, stream>>>(hbh, hbl, W1, b1, W2, b2, out);
}